// Round 1
// baseline (2200.521 us; speedup 1.0000x reference)
//
#include <hip/hip_runtime.h>
#include <stdint.h>

// ---------------- geometry ----------------
// B=8, C=256, H=W=128, HW=16384, 4 heads of d_k=64
// idx: HS=WS=2<<idx, S=HS*WS, OH=OW=64>>idx, NSP=OH*OW, D=64*NSP
// gather:  q[s=(i,j)][d=(c,ohi,owi)] = Q[lo+c][ohi*HS+i][owi*WS+j]
// scatter: Y[lo+c][i*OH+ohi][j*OW+owi] = y[s][d]   (transposed vs gather!)

#define DEVI static __device__ __forceinline__

typedef short bf8 __attribute__((ext_vector_type(8)));   // 8 bf16 (4 VGPRs)
typedef float f32x4 __attribute__((ext_vector_type(4)));

DEVI unsigned short f2bf(float f) {
  unsigned u = __builtin_bit_cast(unsigned, f);
  u = (u + 0x7fffu + ((u >> 16) & 1u)) >> 16;
  return (unsigned short)u;
}
DEVI float bf2f(unsigned short h) {
  unsigned u = ((unsigned)h) << 16;
  return __builtin_bit_cast(float, u);
}

// ---------------- ws layout (bytes) ----------------
static const size_t WB_OFF  = 0;                       // bf16 [3][256][256]
static const size_t WOB_OFF = 393216;                  // bf16 [256][2304] k=(e*256+c)
static const size_t QB_OFF  = 1572864;                 // bf16 [8][256][16384]
static const size_t KB_OFF  = QB_OFF + 67108864;
static const size_t VB_OFF  = KB_OFF + 67108864;
static const size_t YB_OFF  = VB_OFF + 67108864;
static const size_t SC_OFF  = YB_OFF + 67108864;       // f32 scores (559232 floats)
static const size_t PR_OFF  = SC_OFF + 2236928;        // f32 probs
static const size_t BNP_OFF = PR_OFF + 2236928;        // f32 [2048][256][2]
static const size_t BNS_OFF = BNP_OFF + 4194304;       // f32 [2][256]
static const size_t WS_NEED = BNS_OFF + 2048;

// scores float offsets per idx: sizes 8*S^2
DEVI int sc_base(int idx) { return idx == 0 ? 0 : idx == 1 ? 128 : idx == 2 ? 2176 : 34944; }

// ---------------- prep: convert weights to bf16 (wo reordered) ----------------
__global__ void k_prep(const float* __restrict__ wq, const float* __restrict__ wk,
                       const float* __restrict__ wv, const float* __restrict__ wo,
                       unsigned short* __restrict__ Wb, unsigned short* __restrict__ Wob) {
  int i = blockIdx.x * 256 + threadIdx.x;        // grid covers 786432 exactly
  if (i < 196608) {
    int z = i >> 16, r = i & 65535;
    const float* w = (z == 0) ? wq : (z == 1) ? wk : wv;
    Wb[i] = f2bf(w[r]);
  } else {
    int j = i - 196608;
    int o = j / 2304, k = j - o * 2304;
    int e = k >> 8, c = k & 255;
    Wob[j] = f2bf(wo[(o * 256 + c) * 9 + e]);    // Wob[o][e*256+c] = wo[o][c][e]
  }
}

__global__ void k_zero(float* __restrict__ p, int n) {
  int i = blockIdx.x * 256 + threadIdx.x;
  for (; i < n; i += gridDim.x * 256) p[i] = 0.f;
}

// ---------------- QKV projection: MFMA GEMM [256x256]x[256x64-tile] ----------------
__global__ __launch_bounds__(256) void k_qkv(
    const float* __restrict__ x, const unsigned short* __restrict__ Wb,
    const float* __restrict__ bq, const float* __restrict__ bk, const float* __restrict__ bv,
    unsigned short* __restrict__ Qb, unsigned short* __restrict__ Kb,
    unsigned short* __restrict__ Vb) {
  const int pt = blockIdx.x, b = blockIdx.y, z = blockIdx.z;
  const int p0 = pt * 64;
  const int tid = threadIdx.x;
  const float* bias = (z == 0) ? bq : (z == 1) ? bk : bv;
  unsigned short* Out = (z == 0) ? Qb : (z == 1) ? Kb : Vb;
  const unsigned short* Wz = Wb + (size_t)z * 65536;

  __shared__ __align__(16) unsigned short xt[64 * 256];  // [p][c] XOR-swizzled, 32KB

  const float* xb = x + (size_t)b * 256 * 16384;
  {
    int pl = tid & 63, c0 = tid >> 6;
    for (int it = 0; it < 64; ++it) {
      int c = c0 + it * 4;
      float v = xb[(size_t)c * 16384 + p0 + pl];
      xt[pl * 256 + (c ^ ((pl & 7) << 3))] = f2bf(v);
    }
  }
  __syncthreads();

  const int wave = tid >> 6, lane = tid & 63;
  const int lr = lane & 15, lk = lane >> 4;
  const int obase = wave * 64;

  f32x4 acc[4][4];
  for (int m = 0; m < 4; ++m)
    for (int n = 0; n < 4; ++n)
      for (int r = 0; r < 4; ++r) acc[m][n][r] = 0.f;

  for (int ks = 0; ks < 8; ++ks) {
    int c0 = ks * 32 + lk * 8;
    bf8 a[4], bb[4];
#pragma unroll
    for (int m = 0; m < 4; ++m)
      a[m] = *(const bf8*)(Wz + (size_t)(obase + m * 16 + lr) * 256 + c0);
#pragma unroll
    for (int n = 0; n < 4; ++n) {
      int p = n * 16 + lr;
      bb[n] = *(const bf8*)(&xt[p * 256 + (c0 ^ ((p & 7) << 3))]);
    }
#pragma unroll
    for (int m = 0; m < 4; ++m)
#pragma unroll
      for (int n = 0; n < 4; ++n)
        acc[m][n] = __builtin_amdgcn_mfma_f32_16x16x32_bf16(a[m], bb[n], acc[m][n], 0, 0, 0);
  }

  unsigned short* ob = Out + (size_t)b * 256 * 16384;
#pragma unroll
  for (int m = 0; m < 4; ++m) {
#pragma unroll
    for (int r = 0; r < 4; ++r) {
      int o = obase + m * 16 + lk * 4 + r;
      float bv_ = bias[o];
#pragma unroll
      for (int n = 0; n < 4; ++n)
        ob[(size_t)o * 16384 + p0 + n * 16 + lr] = f2bf(acc[m][n][r] + bv_);
    }
  }
}

// ---------------- Gram (scores) kernels ----------------
// idx0: S=4, NSP=4096
__global__ __launch_bounds__(256) void k_gram0(
    const unsigned short* __restrict__ Qb, const unsigned short* __restrict__ Kb,
    float* __restrict__ scores) {
  const int c = blockIdx.x, b = blockIdx.y;
  const int tid = threadIdx.x;
  __shared__ unsigned short ql[4 * 2048];   // [s][sp-half] 16KB
  __shared__ unsigned short kl[4 * 2048];
  const size_t plane = ((size_t)b * 256 + c) * 16384;

  float acc[16];
  for (int i = 0; i < 16; ++i) acc[i] = 0.f;

  for (int half = 0; half < 2; ++half) {
    __syncthreads();
    for (int k = 0; k < 32; ++k) {
      int px = tid + k * 256;              // 0..8191
      int h = (half << 6) | (px >> 7), w = px & 127;
      int s = (h & 1) * 2 + (w & 1);
      int spl = ((h & 63) >> 1) * 64 + (w >> 1);
      ql[s * 2048 + spl] = Qb[plane + (size_t)h * 128 + w];
      kl[s * 2048 + spl] = Kb[plane + (size_t)h * 128 + w];
    }
    __syncthreads();
    for (int k = 0; k < 8; ++k) {
      int sp = tid + k * 256;
      float qv[4], kv[4];
#pragma unroll
      for (int i = 0; i < 4; ++i) { qv[i] = bf2f(ql[i * 2048 + sp]); kv[i] = bf2f(kl[i * 2048 + sp]); }
#pragma unroll
      for (int i = 0; i < 4; ++i)
#pragma unroll
        for (int j = 0; j < 4; ++j) acc[i * 4 + j] += qv[i] * kv[j];
    }
  }
  __syncthreads();
  float* red = (float*)ql;                 // reuse 16KB
  for (int i = 0; i < 16; ++i) red[tid * 16 + i] = acc[i];
  __syncthreads();
  if (tid < 16) {
    float s = 0.f;
    for (int t = 0; t < 256; ++t) s += red[t * 16 + tid];
    atomicAdd(scores + (size_t)b * 16 + tid, s);
  }
}

// idx 1 (S=16) and idx 2 (S=64)
template <int IDX>
__global__ __launch_bounds__(256) void k_gram12(
    const unsigned short* __restrict__ Qb, const unsigned short* __restrict__ Kb,
    float* __restrict__ scores) {
  constexpr int HS = 2 << IDX, S = HS * HS, OH = 64 >> IDX, NSP = OH * OH, SPH = NSP / 2;
  constexpr int CPB = (IDX == 2) ? 2 : 1;
  constexpr int SB = (IDX == 2) ? 4 : 1;
  constexpr int TB = (IDX == 2) ? 4 : 1;
  const int cg = blockIdx.x, b = blockIdx.y;
  const int tid = threadIdx.x;
  __shared__ unsigned short ql[S * SPH];   // 16KB
  __shared__ unsigned short kl[S * SPH];
  const int sg = tid >> 4, tg = tid & 15;
  const int s0 = sg * SB, t0 = tg * TB;

  float acc[SB][TB];
  for (int i = 0; i < SB; ++i) for (int j = 0; j < TB; ++j) acc[i][j] = 0.f;

  for (int cc = 0; cc < CPB; ++cc) {
    int c = cg * CPB + cc;
    const size_t plane = ((size_t)b * 256 + IDX * 64 + c) * 16384;
    for (int half = 0; half < 2; ++half) {
      __syncthreads();
      for (int k = 0; k < 32; ++k) {
        int px = tid + k * 256;
        int h = (half << 6) | (px >> 7), w = px & 127;
        int i = h & (HS - 1), j = w & (HS - 1);
        int ohl = (h & 63) >> (1 + IDX), owi = w >> (1 + IDX);
        int s = i * HS + j, spl = ohl * OH + owi;
        ql[s * SPH + spl] = Qb[plane + (size_t)h * 128 + w];
        kl[s * SPH + spl] = Kb[plane + (size_t)h * 128 + w];
      }
      __syncthreads();
      for (int ss = 0; ss < SPH; ++ss) {
        int sp = (ss + tid) & (SPH - 1);
        float qv[SB], kv[TB];
#pragma unroll
        for (int i = 0; i < SB; ++i) qv[i] = bf2f(ql[(s0 + i) * SPH + sp]);
#pragma unroll
        for (int j = 0; j < TB; ++j) kv[j] = bf2f(kl[(t0 + j) * SPH + sp]);
#pragma unroll
        for (int i = 0; i < SB; ++i)
#pragma unroll
          for (int j = 0; j < TB; ++j) acc[i][j] += qv[i] * kv[j];
      }
    }
  }
  float* sc = scores + ((IDX == 1) ? 128 : 2176) + (size_t)b * S * S;
  for (int i = 0; i < SB; ++i)
    for (int j = 0; j < TB; ++j) atomicAdd(sc + (s0 + i) * S + (t0 + j), acc[i][j]);
}

// idx3: S=256, NSP=64; grid (16 cgroups, 8 b, 2 s-halves)
__global__ __launch_bounds__(256) void k_gram3(
    const unsigned short* __restrict__ Qb, const unsigned short* __restrict__ Kb,
    float* __restrict__ scores) {
  const int cg = blockIdx.x, b = blockIdx.y, sh = blockIdx.z;
  const int tid = threadIdx.x;
  __shared__ unsigned short ql[128 * 64];  // [s_local][sp] 16KB
  __shared__ unsigned short kl[256 * 64];  // 32KB
  const int sg = tid >> 5, tg = tid & 31;
  const int s0l = sg * 16, t0 = tg * 8;
  const int i0 = sh * 8;

  float acc[16][8];
  for (int i = 0; i < 16; ++i) for (int j = 0; j < 8; ++j) acc[i][j] = 0.f;

  for (int cc = 0; cc < 4; ++cc) {
    int c = cg * 4 + cc;
    const size_t plane = ((size_t)b * 256 + 192 + c) * 16384;
    __syncthreads();
    for (int k = 0; k < 64; ++k) {       // K full plane
      int px = tid + k * 256;
      int h = px >> 7, w = px & 127;
      int t = (h & 15) * 16 + (w & 15);
      int sp = (h >> 4) * 8 + (w >> 4);
      kl[t * 64 + sp] = Kb[plane + px];
    }
    for (int k = 0; k < 32; ++k) {       // Q half plane (i in [i0,i0+8))
      int px = tid + k * 256;            // 0..8191
      int hr = px >> 7, w = px & 127;    // hr: (ohi 8)x(il 8)
      int il = hr & 7, ohi = hr >> 3;
      int h = ohi * 16 + i0 + il;
      int s_local = il * 16 + (w & 15);
      int sp = ohi * 8 + (w >> 4);
      ql[s_local * 64 + sp] = Qb[plane + (size_t)h * 128 + w];
    }
    __syncthreads();
    for (int ss = 0; ss < 64; ++ss) {
      int sp = (ss + tid) & 63;
      float qv[16], kv[8];
#pragma unroll
      for (int i = 0; i < 16; ++i) qv[i] = bf2f(ql[(s0l + i) * 64 + sp]);
#pragma unroll
      for (int j = 0; j < 8; ++j) kv[j] = bf2f(kl[(t0 + j) * 64 + sp]);
#pragma unroll
      for (int i = 0; i < 16; ++i)
#pragma unroll
        for (int j = 0; j < 8; ++j) acc[i][j] += qv[i] * kv[j];
    }
  }
  float* sc = scores + 34944 + (size_t)b * 65536;
  const int s0 = sh * 128 + s0l;
  for (int i = 0; i < 16; ++i)
    for (int j = 0; j < 8; ++j) atomicAdd(sc + (s0 + i) * 256 + (t0 + j), acc[i][j]);
}

// ---------------- softmax ----------------
__global__ __launch_bounds__(256) void k_softmax(const float* __restrict__ scores,
                                                 float* __restrict__ probs) {
  const int idx = blockIdx.x, b = blockIdx.y;
  const int S = 4 << (2 * idx);
  const int off = (idx == 0 ? 0 : idx == 1 ? 128 : idx == 2 ? 2176 : 34944) + b * S * S;
  const int s = threadIdx.x;
  if (s >= S) return;
  const float scale = rsqrtf(64.0f * (float)(4096 >> (2 * idx)));
  const float* row = scores + off + s * S;
  float m = -1e30f;
  for (int t = 0; t < S; ++t) m = fmaxf(m, row[t] * scale);
  float sum = 0.f;
  for (int t = 0; t < S; ++t) sum += __expf(row[t] * scale - m);
  float inv = 1.0f / sum;
  float* prow = probs + off + s * S;
  for (int t = 0; t < S; ++t) prow[t] = __expf(row[t] * scale - m) * inv;
}

// ---------------- PV: small S (idx 0,1,2) ----------------
template <int IDX>
__global__ __launch_bounds__(256) void k_pv_small(
    const unsigned short* __restrict__ Vb, const float* __restrict__ probs,
    unsigned short* __restrict__ Yb) {
  constexpr int HS = 2 << IDX, S = HS * HS, OH = 64 >> IDX, NSP = OH * OH;
  constexpr int SPT = NSP / 256;
  const int c = blockIdx.x, b = blockIdx.y;
  const int tid = threadIdx.x;
  __shared__ __align__(16) float pl[S * S];
  const float* pr = probs + (IDX == 0 ? 0 : IDX == 1 ? 128 : 2176) + (size_t)b * S * S;
  for (int i = tid; i < S * S; i += 256) pl[i] = pr[i];
  __syncthreads();
  const size_t plane = ((size_t)b * 256 + IDX * 64 + c) * 16384;
  const unsigned short* vp = Vb + plane;
  unsigned short* yp = Yb + plane;
  for (int k = 0; k < SPT; ++k) {
    int sp = tid + k * 256;
    int ohi = sp >> (6 - IDX), owi = sp & (OH - 1);
    float v[S];
#pragma unroll
    for (int t = 0; t < S; ++t) {
      int i = t / HS, j = t % HS;
      v[t] = bf2f(vp[(size_t)(ohi * HS + i) * 128 + owi * HS + j]);
    }
    for (int s = 0; s < S; ++s) {
      float a = 0.f;
      const float4* p4 = (const float4*)(pl + s * S);
#pragma unroll
      for (int t4 = 0; t4 < S / 4; ++t4) {
        float4 pp = p4[t4];
        a += pp.x * v[t4 * 4] + pp.y * v[t4 * 4 + 1] + pp.z * v[t4 * 4 + 2] + pp.w * v[t4 * 4 + 3];
      }
      int i = s / HS, j = s % HS;
      yp[(size_t)(i * OH + ohi) * 128 + j * OH + owi] = f2bf(a);  // transposed scatter
    }
  }
}

// ---------------- PV: idx3 (S=256) ----------------
__global__ __launch_bounds__(256) void k_pv3(
    const unsigned short* __restrict__ Vb, const float* __restrict__ probs,
    unsigned short* __restrict__ Yb) {
  const int c = blockIdx.x, b = blockIdx.y;
  const int tid = threadIdx.x;
  __shared__ unsigned short vpl[256 * 64];  // [t][sp] 32KB
  __shared__ __align__(16) unsigned short ppl[32 * 256];  // [tt][s] 16KB
  const size_t plane = ((size_t)b * 256 + 192 + c) * 16384;
  for (int k = 0; k < 64; ++k) {
    int px = tid + k * 256;
    int h = px >> 7, w = px & 127;
    vpl[((h & 15) * 16 + (w & 15)) * 64 + ((h >> 4) * 8 + (w >> 4))] = Vb[plane + px];
  }
  const int sp = tid & 63, sg = tid >> 6;
  const int s0 = sg * 64;
  float acc[64];
  for (int i = 0; i < 64; ++i) acc[i] = 0.f;
  const float* pr = probs + 34944 + (size_t)b * 65536;
  for (int tc = 0; tc < 8; ++tc) {
    __syncthreads();
    {
      int tt = tid & 31, sb = tid >> 5;
      for (int ss = 0; ss < 32; ++ss) {
        int s = sb + ss * 8;
        ppl[tt * 256 + s] = f2bf(pr[s * 256 + tc * 32 + tt]);
      }
    }
    __syncthreads();
    for (int tt = 0; tt < 32; ++tt) {
      float v = bf2f(vpl[(tc * 32 + tt) * 64 + sp]);
      const ushort2* pp2 = (const ushort2*)(ppl + tt * 256 + s0);
#pragma unroll
      for (int s2 = 0; s2 < 32; ++s2) {
        ushort2 pp = pp2[s2];
        acc[s2 * 2] += bf2f(pp.x) * v;
        acc[s2 * 2 + 1] += bf2f(pp.y) * v;
      }
    }
  }
  unsigned short* yp = Yb + plane;
  const int ohi = sp >> 3, owi = sp & 7;
#pragma unroll
  for (int s2 = 0; s2 < 64; ++s2) {
    int s = s0 + s2;
    int i = s >> 4, j = s & 15;
    yp[(size_t)(i * 8 + ohi) * 128 + j * 8 + owi] = f2bf(acc[s2]);
  }
}

// ---------------- 3x3 conv (MFMA) + BN partials ----------------
__global__ __launch_bounds__(256) void k_conv(
    const unsigned short* __restrict__ Yb, const unsigned short* __restrict__ Wob,
    const float* __restrict__ bo, float* __restrict__ out, float* __restrict__ bnp) {
  const int tile = blockIdx.x, b = blockIdx.y;
  const int ty0 = (tile >> 4) * 8, tx0 = (tile & 15) * 8;
  const int tid = threadIdx.x;

  __shared__ __align__(16) unsigned short yl[100 * 256];  // [sp'][c] swizzled, 51.2KB

  {
    const unsigned short* yb = Yb + (size_t)b * 256 * 16384;
    int wl = tid & 15, cl = tid >> 4;
    for (int cc = 0; cc < 16; ++cc) {
      int c = cc * 16 + cl;
      for (int hh = 0; hh < 10; ++hh) {
        if (wl < 10) {
          int h = ty0 - 1 + hh, w = tx0 - 1 + wl;
          unsigned short v = 0;
          if (h >= 0 && h < 128 && w >= 0 && w < 128)
            v = yb[(size_t)c * 16384 + h * 128 + w];
          int sp = hh * 10 + wl;
          yl[sp * 256 + (c ^ ((sp & 7) << 3))] = v;
        }
      }
    }
  }
  __syncthreads();

  const int wave = tid >> 6, lane = tid & 63;
  const int lr = lane & 15, lk = lane >> 4;
  const int obase = wave * 64;

  f32x4 acc[4][4];
  for (int m = 0; m < 4; ++m)
    for (int n = 0; n < 4; ++n)
      for (int r = 0; r < 4; ++r) acc[m][n][r] = 0.f;

  int ty[4], tx[4];
#pragma unroll
  for (int n = 0; n < 4; ++n) { int pl = n * 16 + lr; ty[n] = pl >> 3; tx[n] = pl & 7; }

#pragma unroll
  for (int e = 0; e < 9; ++e) {
    const int dy = e / 3, dx = e % 3;
    for (int k8 = 0; k8 < 8; ++k8) {
      int c0 = k8 * 32 + lk * 8;
      bf8 a[4], bb[4];
#pragma unroll
      for (int m = 0; m < 4; ++m)
        a[m] = *(const bf8*)(Wob + (size_t)(obase + m * 16 + lr) * 2304 + e * 256 + c0);
#pragma unroll
      for (int n = 0; n < 4; ++n) {
        int sp = (ty[n] + dy) * 10 + tx[n] + dx;
        bb[n] = *(const bf8*)(&yl[sp * 256 + (c0 ^ ((sp & 7) << 3))]);
      }
#pragma unroll
      for (int m = 0; m < 4; ++m)
#pragma unroll
        for (int n = 0; n < 4; ++n)
          acc[m][n] = __builtin_amdgcn_mfma_f32_16x16x32_bf16(a[m], bb[n], acc[m][n], 0, 0, 0);
    }
  }

  float* ob = out + (size_t)b * 256 * 16384;
#pragma unroll
  for (int m = 0; m < 4; ++m) {
#pragma unroll
    for (int r = 0; r < 4; ++r) {
      int o = obase + m * 16 + lk * 4 + r;
      float bv_ = bo[o];
      float s1 = 0.f, s2 = 0.f;
#pragma unroll
      for (int n = 0; n < 4; ++n) {
        float v = acc[m][n][r] + bv_;
        ob[(size_t)o * 16384 + (ty0 + ty[n]) * 128 + tx0 + tx[n]] = v;
        s1 += v;
        s2 += v * v;
      }
      for (int off = 1; off < 16; off <<= 1) {
        s1 += __shfl_xor(s1, off, 64);
        s2 += __shfl_xor(s2, off, 64);
      }
      if (lr == 0) {
        int gb = b * 256 + tile;
        bnp[((size_t)gb * 256 + o) * 2 + 0] = s1;
        bnp[((size_t)gb * 256 + o) * 2 + 1] = s2;
      }
    }
  }
}

// ---------------- BN reduce + apply ----------------
__global__ __launch_bounds__(256) void k_bnred(
    const float* __restrict__ bnp, const float* __restrict__ gamma,
    const float* __restrict__ beta, float* __restrict__ bns) {
  const int o = blockIdx.x;
  const int tid = threadIdx.x;
  float s1 = 0.f, s2 = 0.f;
  for (int k = tid; k < 2048; k += 256) {
    s1 += bnp[((size_t)k * 256 + o) * 2 + 0];
    s2 += bnp[((size_t)k * 256 + o) * 2 + 1];
  }
  __shared__ float r1[256], r2[256];
  r1[tid] = s1; r2[tid] = s2;
  __syncthreads();
  for (int off = 128; off > 0; off >>= 1) {
    if (tid < off) { r1[tid] += r1[tid + off]; r2[tid] += r2[tid + off]; }
    __syncthreads();
  }
  if (tid == 0) {
    const float cnt = 8.0f * 16384.0f;
    float mean = r1[0] / cnt;
    float var = r2[0] / cnt - mean * mean;
    float sc = gamma[o] * rsqrtf(var + 1e-5f);
    bns[o] = sc;
    bns[256 + o] = beta[o] - mean * sc;
  }
}

__global__ void k_bnapply(float* __restrict__ out, const float* __restrict__ bns) {
  size_t i = ((size_t)blockIdx.x * 256 + threadIdx.x) * 4;
  const size_t total = 33554432;
  const size_t stride = (size_t)gridDim.x * 256 * 4;
  for (; i < total; i += stride) {
    float4 v = *(float4*)(out + i);
    int o = (int)((i >> 14) & 255);
    float sc = bns[o], shv = bns[256 + o];
    v.x = v.x * sc + shv; v.x = v.x > 0.f ? v.x : 0.2f * v.x;
    v.y = v.y * sc + shv; v.y = v.y > 0.f ? v.y : 0.2f * v.y;
    v.z = v.z * sc + shv; v.z = v.z > 0.f ? v.z : 0.2f * v.z;
    v.w = v.w * sc + shv; v.w = v.w > 0.f ? v.w : 0.2f * v.w;
    *(float4*)(out + i) = v;
  }
}

// ---------------- launcher ----------------
extern "C" void kernel_launch(void* const* d_in, const int* in_sizes, int n_in,
                              void* d_out, int out_size, void* d_ws, size_t ws_size,
                              hipStream_t stream) {
  if (ws_size < WS_NEED) return;  // fail cleanly rather than corrupt

  const float* x     = (const float*)d_in[0];
  const float* wq    = (const float*)d_in[1];
  const float* bq    = (const float*)d_in[2];
  const float* wk    = (const float*)d_in[3];
  const float* bk    = (const float*)d_in[4];
  const float* wv    = (const float*)d_in[5];
  const float* bv    = (const float*)d_in[6];
  const float* wo    = (const float*)d_in[7];
  const float* bo    = (const float*)d_in[8];
  const float* gamma = (const float*)d_in[9];
  const float* beta  = (const float*)d_in[10];
  float* out = (float*)d_out;
  char* ws = (char*)d_ws;

  unsigned short* Wb  = (unsigned short*)(ws + WB_OFF);
  unsigned short* Wob = (unsigned short*)(ws + WOB_OFF);
  unsigned short* Qb  = (unsigned short*)(ws + QB_OFF);
  unsigned short* Kb  = (unsigned short*)(ws + KB_OFF);
  unsigned short* Vb  = (unsigned short*)(ws + VB_OFF);
  unsigned short* Yb  = (unsigned short*)(ws + YB_OFF);
  float* scores = (float*)(ws + SC_OFF);
  float* probs  = (float*)(ws + PR_OFF);
  float* bnp    = (float*)(ws + BNP_OFF);
  float* bns    = (float*)(ws + BNS_OFF);

  k_prep<<<dim3(3072), dim3(256), 0, stream>>>(wq, wk, wv, wo, Wb, Wob);
  k_zero<<<dim3(547), dim3(256), 0, stream>>>(scores, 559232);
  k_qkv<<<dim3(256, 8, 3), dim3(256), 0, stream>>>(x, Wb, bq, bk, bv, Qb, Kb, Vb);
  k_gram0<<<dim3(64, 8), dim3(256), 0, stream>>>(Qb, Kb, scores);
  k_gram12<1><<<dim3(64, 8), dim3(256), 0, stream>>>(Qb, Kb, scores);
  k_gram12<2><<<dim3(32, 8), dim3(256), 0, stream>>>(Qb, Kb, scores);
  k_gram3<<<dim3(16, 8, 2), dim3(256), 0, stream>>>(Qb, Kb, scores);
  k_softmax<<<dim3(4, 8), dim3(256), 0, stream>>>(scores, probs);
  k_pv_small<0><<<dim3(64, 8), dim3(256), 0, stream>>>(Vb, probs, Yb);
  k_pv_small<1><<<dim3(64, 8), dim3(256), 0, stream>>>(Vb, probs, Yb);
  k_pv_small<2><<<dim3(64, 8), dim3(256), 0, stream>>>(Vb, probs, Yb);
  k_pv3<<<dim3(64, 8), dim3(256), 0, stream>>>(Vb, probs, Yb);
  k_conv<<<dim3(256, 8), dim3(256), 0, stream>>>(Yb, Wob, bo, out, bnp);
  k_bnred<<<dim3(256), dim3(256), 0, stream>>>(bnp, gamma, beta, bns);
  k_bnapply<<<dim3(4096), dim3(256), 0, stream>>>(out, bns);
}

// Round 2
// 1513.794 us; speedup vs baseline: 1.4536x; 1.4536x over previous
//
#include <hip/hip_runtime.h>
#include <stdint.h>

// ---------------- geometry ----------------
// B=8, C=256, H=W=128, HW=16384, 4 heads of d_k=64
// idx: HS=WS=2<<idx, S=HS*WS, OH=OW=64>>idx, NSP=OH*OW
// gather:  q[s=(i,j)][d=(c,ohi,owi)] = Q[lo+c][ohi*HS+i][owi*WS+j]
// scatter: Y[lo+c][i*OH+ohi][j*OW+owi] = y[s][d]   (transposed vs gather!)
// NHWC buffers (Vn, Yn): element (p, c) stored at [p*256 + (c ^ ((p&7)<<3))]
// (granule-XOR swizzle baked into global layout so global_load_lds staging
//  is linear and LDS b128 reads are bank-spread; 64-aligned c-blocks are
//  closed under the XOR so per-head 128B segments stay contiguous)

#define DEVI static __device__ __forceinline__

typedef short bf8 __attribute__((ext_vector_type(8)));   // 8 bf16 (4 VGPRs)
typedef float f32x4 __attribute__((ext_vector_type(4)));

DEVI unsigned short f2bf(float f) {
  unsigned u = __builtin_bit_cast(unsigned, f);
  u = (u + 0x7fffu + ((u >> 16) & 1u)) >> 16;
  return (unsigned short)u;
}
DEVI float bf2f(unsigned short h) {
  unsigned u = ((unsigned)h) << 16;
  return __builtin_bit_cast(float, u);
}

DEVI void gload16(const void* g, void* l) {
  __builtin_amdgcn_global_load_lds(
      (const __attribute__((address_space(1))) unsigned int*)g,
      (__attribute__((address_space(3))) unsigned int*)l, 16, 0, 0);
}

// ---------------- ws layout (bytes) ----------------
static const size_t WB_OFF  = 0;                        // bf16 [3][256][256]
static const size_t WOB_OFF = 393216;                   // bf16 [256][2304] k=(e*256+c)
static const size_t QB_OFF  = 1572864;                  // bf16 planar [8][256][16384]
static const size_t KB_OFF  = QB_OFF + 67108864;
static const size_t VN_OFF  = KB_OFF + 67108864;        // bf16 NHWC-swz [8][16384][256]
static const size_t YN_OFF  = VN_OFF + 67108864;        // bf16 NHWC-swz
static const size_t SC_OFF  = YN_OFF + 67108864;        // f32 scores (559232 floats)
static const size_t PRB_OFF = SC_OFF + 2236928;         // bf16 probs (559232)
static const size_t BNP_OFF = PRB_OFF + 1118464;        // f32 [2048][256][2]
static const size_t BNS_OFF = BNP_OFF + 4194304;        // f32 [2][256]
static const size_t WS_NEED = BNS_OFF + 2048;

// ---------------- prep: convert weights to bf16 (wo reordered) ----------------
__global__ void k_prep(const float* __restrict__ wq, const float* __restrict__ wk,
                       const float* __restrict__ wv, const float* __restrict__ wo,
                       unsigned short* __restrict__ Wb, unsigned short* __restrict__ Wob) {
  int i = blockIdx.x * 256 + threadIdx.x;        // grid covers 786432 exactly
  if (i < 196608) {
    int z = i >> 16, r = i & 65535;
    const float* w = (z == 0) ? wq : (z == 1) ? wk : wv;
    Wb[i] = f2bf(w[r]);
  } else {
    int j = i - 196608;
    int o = j / 2304, k = j - o * 2304;
    int e = k >> 8, c = k & 255;
    Wob[j] = f2bf(wo[(o * 256 + c) * 9 + e]);    // Wob[o][e*256+c] = wo[o][c][e]
  }
}

__global__ void k_zero(float* __restrict__ p, int n) {
  int i = blockIdx.x * 256 + threadIdx.x;
  for (; i < n; i += gridDim.x * 256) p[i] = 0.f;
}

// ---------------- fused QKV projection ----------------
__global__ __launch_bounds__(256) void k_qkv(
    const float* __restrict__ x, const unsigned short* __restrict__ Wb,
    const float* __restrict__ bq, const float* __restrict__ bk, const float* __restrict__ bv,
    unsigned short* __restrict__ Qb, unsigned short* __restrict__ Kb,
    unsigned short* __restrict__ Vn) {
  const int pt = blockIdx.x, b = blockIdx.y;
  const int p0 = pt * 64;
  const int tid = threadIdx.x;

  __shared__ __align__(16) unsigned short xt[64 * 256];  // [p][c'] swizzled, 32KB

  const float* xb = x + (size_t)b * 256 * 16384;
  for (int k = 0; k < 16; ++k) {
    int i = tid + k * 256;
    int c = i >> 4, p4 = (i & 15) * 4;
    float4 v = *(const float4*)(xb + (size_t)c * 16384 + p0 + p4);
    xt[(p4 + 0) * 256 + (c ^ (((p4 + 0) & 7) << 3))] = f2bf(v.x);
    xt[(p4 + 1) * 256 + (c ^ (((p4 + 1) & 7) << 3))] = f2bf(v.y);
    xt[(p4 + 2) * 256 + (c ^ (((p4 + 2) & 7) << 3))] = f2bf(v.z);
    xt[(p4 + 3) * 256 + (c ^ (((p4 + 3) & 7) << 3))] = f2bf(v.w);
  }
  __syncthreads();

  const int wave = tid >> 6, lane = tid & 63;
  const int lr = lane & 15, lk = lane >> 4;
  const int obase = wave * 64;

  for (int z = 0; z < 3; ++z) {
    const unsigned short* Wz = Wb + (size_t)z * 65536;
    f32x4 acc[4][4];
    for (int m = 0; m < 4; ++m)
      for (int n = 0; n < 4; ++n)
        for (int r = 0; r < 4; ++r) acc[m][n][r] = 0.f;

    for (int ks = 0; ks < 8; ++ks) {
      int c0 = ks * 32 + lk * 8;
      bf8 a[4], bb[4];
#pragma unroll
      for (int m = 0; m < 4; ++m)
        a[m] = *(const bf8*)(Wz + (size_t)(obase + m * 16 + lr) * 256 + c0);
#pragma unroll
      for (int n = 0; n < 4; ++n) {
        int p = n * 16 + lr;
        bb[n] = *(const bf8*)(&xt[p * 256 + (c0 ^ ((p & 7) << 3))]);
      }
#pragma unroll
      for (int m = 0; m < 4; ++m)
#pragma unroll
        for (int n = 0; n < 4; ++n)
          acc[m][n] = __builtin_amdgcn_mfma_f32_16x16x32_bf16(a[m], bb[n], acc[m][n], 0, 0, 0);
    }

    if (z < 2) {
      unsigned short* ob = ((z == 0) ? Qb : Kb) + (size_t)b * 256 * 16384;
      const float* bias = (z == 0) ? bq : bk;
#pragma unroll
      for (int m = 0; m < 4; ++m) {
#pragma unroll
        for (int r = 0; r < 4; ++r) {
          int o = obase + m * 16 + lk * 4 + r;
          float bvv = bias[o];
#pragma unroll
          for (int n = 0; n < 4; ++n)
            ob[(size_t)o * 16384 + p0 + n * 16 + lr] = f2bf(acc[m][n][r] + bvv);
        }
      }
    } else {
      // V: transpose to NHWC-swizzled via LDS (xt is dead now)
      __syncthreads();
#pragma unroll
      for (int m = 0; m < 4; ++m) {
        int ob4 = obase + m * 16 + lk * 4;
        float4 b4 = *(const float4*)(bv + ob4);
#pragma unroll
        for (int n = 0; n < 4; ++n) {
          int p = n * 16 + lr;
          ushort4 v4;
          v4.x = f2bf(acc[m][n][0] + b4.x);
          v4.y = f2bf(acc[m][n][1] + b4.y);
          v4.z = f2bf(acc[m][n][2] + b4.z);
          v4.w = f2bf(acc[m][n][3] + b4.w);
          *(ushort4*)(&xt[p * 256 + (ob4 ^ ((p & 7) << 3))]) = v4;
        }
      }
      __syncthreads();
      unsigned short* vb = Vn + ((size_t)b * 16384 + p0) * 256;
#pragma unroll
      for (int i = 0; i < 8; ++i) {
        int ch = tid + i * 256;
        *(uint4*)(vb + ch * 8) = *(const uint4*)(&xt[ch * 8]);
      }
    }
  }
}

// ---------------- Gram (scores) kernels (planar Q/K, unchanged) ----------------
__global__ __launch_bounds__(256) void k_gram0(
    const unsigned short* __restrict__ Qb, const unsigned short* __restrict__ Kb,
    float* __restrict__ scores) {
  const int c = blockIdx.x, b = blockIdx.y;
  const int tid = threadIdx.x;
  __shared__ unsigned short ql[4 * 2048];
  __shared__ unsigned short kl[4 * 2048];
  const size_t plane = ((size_t)b * 256 + c) * 16384;

  float acc[16];
  for (int i = 0; i < 16; ++i) acc[i] = 0.f;

  for (int half = 0; half < 2; ++half) {
    __syncthreads();
    for (int k = 0; k < 32; ++k) {
      int px = tid + k * 256;
      int h = (half << 6) | (px >> 7), w = px & 127;
      int s = (h & 1) * 2 + (w & 1);
      int spl = ((h & 63) >> 1) * 64 + (w >> 1);
      ql[s * 2048 + spl] = Qb[plane + (size_t)h * 128 + w];
      kl[s * 2048 + spl] = Kb[plane + (size_t)h * 128 + w];
    }
    __syncthreads();
    for (int k = 0; k < 8; ++k) {
      int sp = tid + k * 256;
      float qv[4], kv[4];
#pragma unroll
      for (int i = 0; i < 4; ++i) { qv[i] = bf2f(ql[i * 2048 + sp]); kv[i] = bf2f(kl[i * 2048 + sp]); }
#pragma unroll
      for (int i = 0; i < 4; ++i)
#pragma unroll
        for (int j = 0; j < 4; ++j) acc[i * 4 + j] += qv[i] * kv[j];
    }
  }
  __syncthreads();
  float* red = (float*)ql;
  for (int i = 0; i < 16; ++i) red[tid * 16 + i] = acc[i];
  __syncthreads();
  if (tid < 16) {
    float s = 0.f;
    for (int t = 0; t < 256; ++t) s += red[t * 16 + tid];
    atomicAdd(scores + (size_t)b * 16 + tid, s);
  }
}

template <int IDX>
__global__ __launch_bounds__(256) void k_gram12(
    const unsigned short* __restrict__ Qb, const unsigned short* __restrict__ Kb,
    float* __restrict__ scores) {
  constexpr int HS = 2 << IDX, S = HS * HS, OH = 64 >> IDX, NSP = OH * OH, SPH = NSP / 2;
  constexpr int CPB = (IDX == 2) ? 2 : 1;
  constexpr int SB = (IDX == 2) ? 4 : 1;
  constexpr int TB = (IDX == 2) ? 4 : 1;
  const int cg = blockIdx.x, b = blockIdx.y;
  const int tid = threadIdx.x;
  __shared__ unsigned short ql[S * SPH];
  __shared__ unsigned short kl[S * SPH];
  const int sg = tid >> 4, tg = tid & 15;
  const int s0 = sg * SB, t0 = tg * TB;

  float acc[SB][TB];
  for (int i = 0; i < SB; ++i) for (int j = 0; j < TB; ++j) acc[i][j] = 0.f;

  for (int cc = 0; cc < CPB; ++cc) {
    int c = cg * CPB + cc;
    const size_t plane = ((size_t)b * 256 + IDX * 64 + c) * 16384;
    for (int half = 0; half < 2; ++half) {
      __syncthreads();
      for (int k = 0; k < 32; ++k) {
        int px = tid + k * 256;
        int h = (half << 6) | (px >> 7), w = px & 127;
        int i = h & (HS - 1), j = w & (HS - 1);
        int ohl = (h & 63) >> (1 + IDX), owi = w >> (1 + IDX);
        int s = i * HS + j, spl = ohl * OH + owi;
        ql[s * SPH + spl] = Qb[plane + (size_t)h * 128 + w];
        kl[s * SPH + spl] = Kb[plane + (size_t)h * 128 + w];
      }
      __syncthreads();
      for (int ss = 0; ss < SPH; ++ss) {
        int sp = (ss + tid) & (SPH - 1);
        float qv[SB], kv[TB];
#pragma unroll
        for (int i = 0; i < SB; ++i) qv[i] = bf2f(ql[(s0 + i) * SPH + sp]);
#pragma unroll
        for (int j = 0; j < TB; ++j) kv[j] = bf2f(kl[(t0 + j) * SPH + sp]);
#pragma unroll
        for (int i = 0; i < SB; ++i)
#pragma unroll
          for (int j = 0; j < TB; ++j) acc[i][j] += qv[i] * kv[j];
      }
    }
  }
  float* sc = scores + ((IDX == 1) ? 128 : 2176) + (size_t)b * S * S;
  for (int i = 0; i < SB; ++i)
    for (int j = 0; j < TB; ++j) atomicAdd(sc + (s0 + i) * S + (t0 + j), acc[i][j]);
}

__global__ __launch_bounds__(256) void k_gram3(
    const unsigned short* __restrict__ Qb, const unsigned short* __restrict__ Kb,
    float* __restrict__ scores) {
  const int cg = blockIdx.x, b = blockIdx.y, sh = blockIdx.z;
  const int tid = threadIdx.x;
  __shared__ unsigned short ql[128 * 64];
  __shared__ unsigned short kl[256 * 64];
  const int sg = tid >> 5, tg = tid & 31;
  const int s0l = sg * 16, t0 = tg * 8;
  const int i0 = sh * 8;

  float acc[16][8];
  for (int i = 0; i < 16; ++i) for (int j = 0; j < 8; ++j) acc[i][j] = 0.f;

  for (int cc = 0; cc < 4; ++cc) {
    int c = cg * 4 + cc;
    const size_t plane = ((size_t)b * 256 + 192 + c) * 16384;
    __syncthreads();
    for (int k = 0; k < 64; ++k) {
      int px = tid + k * 256;
      int h = px >> 7, w = px & 127;
      int t = (h & 15) * 16 + (w & 15);
      int sp = (h >> 4) * 8 + (w >> 4);
      kl[t * 64 + sp] = Kb[plane + px];
    }
    for (int k = 0; k < 32; ++k) {
      int px = tid + k * 256;
      int hr = px >> 7, w = px & 127;
      int il = hr & 7, ohi = hr >> 3;
      int h = ohi * 16 + i0 + il;
      int s_local = il * 16 + (w & 15);
      int sp = ohi * 8 + (w >> 4);
      ql[s_local * 64 + sp] = Qb[plane + (size_t)h * 128 + w];
    }
    __syncthreads();
    for (int ss = 0; ss < 64; ++ss) {
      int sp = (ss + tid) & 63;
      float qv[16], kv[8];
#pragma unroll
      for (int i = 0; i < 16; ++i) qv[i] = bf2f(ql[(s0l + i) * 64 + sp]);
#pragma unroll
      for (int j = 0; j < 8; ++j) kv[j] = bf2f(kl[(t0 + j) * 64 + sp]);
#pragma unroll
      for (int i = 0; i < 16; ++i)
#pragma unroll
        for (int j = 0; j < 8; ++j) acc[i][j] += qv[i] * kv[j];
    }
  }
  float* sc = scores + 34944 + (size_t)b * 65536;
  const int s0 = sh * 128 + s0l;
  for (int i = 0; i < 16; ++i)
    for (int j = 0; j < 8; ++j) atomicAdd(sc + (s0 + i) * 256 + (t0 + j), acc[i][j]);
}

// ---------------- softmax (fp32 scores -> bf16 probs) ----------------
__global__ __launch_bounds__(256) void k_softmax(const float* __restrict__ scores,
                                                 unsigned short* __restrict__ prb) {
  const int idx = blockIdx.x, b = blockIdx.y;
  const int S = 4 << (2 * idx);
  const int off = (idx == 0 ? 0 : idx == 1 ? 128 : idx == 2 ? 2176 : 34944) + b * S * S;
  const int s = threadIdx.x;
  if (s >= S) return;
  const float scale = rsqrtf(64.0f * (float)(4096 >> (2 * idx)));
  const float* row = scores + off + s * S;
  float m = -1e30f;
  for (int t = 0; t < S; ++t) m = fmaxf(m, row[t]);
  m *= scale;
  float sum = 0.f;
  for (int t = 0; t < S; ++t) sum += __expf(row[t] * scale - m);
  float inv = 1.0f / sum;
  unsigned short* prow = prb + off + s * S;
  for (int t = 0; t < S; ++t) prow[t] = f2bf(__expf(row[t] * scale - m) * inv);
}

// ---------------- PV small S (idx 0,1,2): per-head, NHWC in/out ----------------
template <int IDX>
__global__ __launch_bounds__(256) void k_pv(
    const unsigned short* __restrict__ Vn, const unsigned short* __restrict__ prb,
    unsigned short* __restrict__ Yn) {
  constexpr int HS = 2 << IDX, S = HS * HS, OH = 64 >> IDX;
  constexpr int IT = (IDX == 0) ? 8 : (IDX == 1) ? 4 : 1;
  constexpr int POFF = (IDX == 0) ? 0 : (IDX == 1) ? 128 : 2176;
  const int bx = blockIdx.x, b = blockIdx.y;
  const int c = threadIdx.x & 63, spg = threadIdx.x >> 6;
  __shared__ __align__(16) float pl[S * S];
  const unsigned short* pr = prb + POFF + (size_t)b * S * S;
  for (int i = threadIdx.x; i < S * S; i += 256) pl[i] = bf2f(pr[i]);
  __syncthreads();
  const int hc = IDX * 64;
  const unsigned short* vb = Vn + (size_t)b * 16384 * 256;
  unsigned short* yb = Yn + (size_t)b * 16384 * 256;
  for (int it = 0; it < IT; ++it) {
    int sp = bx * (4 * IT) + it * 4 + spg;
    int ohi = sp >> (6 - IDX), owi = sp & (OH - 1);
    float v[S];
#pragma unroll
    for (int t = 0; t < S; ++t) {
      int po = (ohi * HS + t / HS) * 128 + owi * HS + (t % HS);
      v[t] = bf2f(vb[(size_t)po * 256 + ((hc + c) ^ ((po & 7) << 3))]);
    }
    for (int s = 0; s < S; ++s) {
      const float4* p4 = (const float4*)(pl + s * S);
      float a = 0.f;
#pragma unroll
      for (int t4 = 0; t4 < S / 4; ++t4) {
        float4 pp = p4[t4];
        a += pp.x * v[t4 * 4] + pp.y * v[t4 * 4 + 1] + pp.z * v[t4 * 4 + 2] + pp.w * v[t4 * 4 + 3];
      }
      int po = ((s >> (IDX + 1)) * OH + ohi) * 128 + (s & (HS - 1)) * OH + owi;
      yb[(size_t)po * 256 + ((hc + c) ^ ((po & 7) << 3))] = f2bf(a);
    }
  }
}

// ---------------- PV idx3 (S=256): MFMA GEMM per (b, sp) ----------------
__global__ __launch_bounds__(256) void k_pv3(
    const unsigned short* __restrict__ Vn, const unsigned short* __restrict__ prb,
    unsigned short* __restrict__ Yn) {
  const int sp = blockIdx.x, b = blockIdx.y;   // grid (64, 8)
  const int ohi = sp >> 3, owi = sp & 7;
  const int tid = threadIdx.x;
  __shared__ __align__(16) unsigned short vl[64 * 256];  // [c][t'] swizzled, 32KB
  const unsigned short* vb = Vn + (size_t)b * 16384 * 256;
  {
    int t = tid;  // pixel index t = ti*16+tj
    int po = (ohi * 16 + (t >> 4)) * 128 + owi * 16 + (t & 15);
    const unsigned short* src = vb + (size_t)po * 256;
    int xv = (po & 7) << 3;
#pragma unroll
    for (int g = 0; g < 8; ++g) {
      ushort4 lo = *(const ushort4*)(src + ((192 + g * 8) ^ xv));
      ushort4 hi = *(const ushort4*)(src + ((192 + g * 8) ^ xv) + 4);
      unsigned short vv[8] = {lo.x, lo.y, lo.z, lo.w, hi.x, hi.y, hi.z, hi.w};
#pragma unroll
      for (int e = 0; e < 8; ++e) {
        int cc = g * 8 + e;
        vl[cc * 256 + (t ^ ((cc & 7) << 3))] = vv[e];
      }
    }
  }
  __syncthreads();

  const int wave = tid >> 6, lane = tid & 63;
  const int lr = lane & 15, lk = lane >> 4;
  const int sb = wave * 64;
  const unsigned short* pr = prb + 34944 + (size_t)b * 65536;

  f32x4 acc[4][4];
  for (int m = 0; m < 4; ++m)
    for (int n = 0; n < 4; ++n)
      for (int r = 0; r < 4; ++r) acc[m][n][r] = 0.f;

  for (int kk = 0; kk < 8; ++kk) {
    int t0 = kk * 32 + lk * 8;
    bf8 a[4], bb[4];
#pragma unroll
    for (int m = 0; m < 4; ++m)
      a[m] = *(const bf8*)(pr + (size_t)(sb + m * 16 + lr) * 256 + t0);
#pragma unroll
    for (int n = 0; n < 4; ++n) {
      int cc = n * 16 + lr;
      bb[n] = *(const bf8*)(&vl[cc * 256 + (t0 ^ ((cc & 7) << 3))]);
    }
#pragma unroll
    for (int m = 0; m < 4; ++m)
#pragma unroll
      for (int n = 0; n < 4; ++n)
        acc[m][n] = __builtin_amdgcn_mfma_f32_16x16x32_bf16(a[m], bb[n], acc[m][n], 0, 0, 0);
  }

  unsigned short* yb = Yn + (size_t)b * 16384 * 256;
#pragma unroll
  for (int m = 0; m < 4; ++m) {
#pragma unroll
    for (int r = 0; r < 4; ++r) {
      int s = sb + m * 16 + lk * 4 + r;
      int si = s >> 4, sj = s & 15;
      int po = (si * 8 + ohi) * 128 + sj * 8 + owi;
#pragma unroll
      for (int n = 0; n < 4; ++n) {
        int cc = 192 + n * 16 + lr;
        yb[(size_t)po * 256 + (cc ^ (owi << 3))] = f2bf(acc[m][n][r]);
      }
    }
  }
}

// ---------------- 3x3 conv (MFMA, NHWC-swz in) + BN partials ----------------
__global__ __launch_bounds__(256) void k_conv(
    const unsigned short* __restrict__ Yn, const unsigned short* __restrict__ Wob,
    const float* __restrict__ bo, float* __restrict__ out, float* __restrict__ bnp) {
  const int tile = blockIdx.x, b = blockIdx.y;
  const int ty0 = (tile >> 4) * 8, tx0 = (tile & 15) * 8;
  const int tid = threadIdx.x;

  __shared__ __align__(16) unsigned short yl[100 * 256];  // [hh*10+ww][c'], 51.2KB

  const unsigned short* yb = Yn + (size_t)b * 16384 * 256;
  const int wave = tid >> 6, lane = tid & 63;

  // stage: 10 rows x 5 KB; linear copy (swizzle lives in the global layout)
  for (int i = wave; i < 50; i += 4) {
    int hh = i / 5, ck = i % 5;
    int h = ty0 - 1 + hh;
    unsigned short* ldst = yl + hh * 2560 + ck * 512;   // wave-uniform base
    if (h >= 0 && h < 128) {
      const unsigned short* g = yb + (h * 128 + tx0 - 1) * 256 + ck * 512 + lane * 8;
      gload16(g, ldst);
    } else {
      uint4 z4 = {0u, 0u, 0u, 0u};
      *(uint4*)(ldst + lane * 8) = z4;
    }
  }
  __syncthreads();
  // zero invalid w-edge columns (ww=0 at left edge, ww=9 at right edge)
  if (tx0 == 0) {
    for (int i = tid; i < 320; i += 256) {
      int hh = i >> 5, ch = i & 31;
      uint4 z4 = {0u, 0u, 0u, 0u};
      *(uint4*)(yl + hh * 2560 + ch * 8) = z4;
    }
  }
  if (tx0 == 120) {
    for (int i = tid; i < 320; i += 256) {
      int hh = i >> 5, ch = i & 31;
      uint4 z4 = {0u, 0u, 0u, 0u};
      *(uint4*)(yl + hh * 2560 + 9 * 256 + ch * 8) = z4;
    }
  }
  __syncthreads();

  const int lr = lane & 15, lk = lane >> 4;
  const int obase = wave * 64;
  const int pty = lr >> 3, ptx = lr & 7;   // n*16+lr -> p in 0..63; ty=p>>3=(n*2)+(lr>>3), tx=p&7=lr&7
  // note: p = n*16 + lr => ty = 2*n + (lr>>3), tx = lr&7

  f32x4 acc[4][4];
  for (int m = 0; m < 4; ++m)
    for (int n = 0; n < 4; ++n)
      for (int r = 0; r < 4; ++r) acc[m][n][r] = 0.f;

  int dy = 0, dx = 0;
  for (int e = 0; e < 9; ++e) {
    int spn[4], gxn[4];
#pragma unroll
    for (int n = 0; n < 4; ++n) {
      int ty = 2 * n + pty, tx = ptx;
      spn[n] = (ty + dy) * 10 + tx + dx;
      gxn[n] = (tx + dx + 7) & 7;
    }
#pragma unroll
    for (int k8 = 0; k8 < 8; ++k8) {
      bf8 a[4], bb[4];
#pragma unroll
      for (int m = 0; m < 4; ++m)
        a[m] = *(const bf8*)(Wob + (size_t)(obase + m * 16 + lr) * 2304 + e * 256 + k8 * 32 + lk * 8);
#pragma unroll
      for (int n = 0; n < 4; ++n)
        bb[n] = *(const bf8*)(yl + spn[n] * 256 + (((k8 * 4 + lk) ^ gxn[n]) << 3));
#pragma unroll
      for (int m = 0; m < 4; ++m)
#pragma unroll
        for (int n = 0; n < 4; ++n)
          acc[m][n] = __builtin_amdgcn_mfma_f32_16x16x32_bf16(a[m], bb[n], acc[m][n], 0, 0, 0);
    }
    if (++dx == 3) { dx = 0; ++dy; }
  }

  float* ob = out + (size_t)b * 256 * 16384;
#pragma unroll
  for (int m = 0; m < 4; ++m) {
#pragma unroll
    for (int r = 0; r < 4; ++r) {
      int o = obase + m * 16 + lk * 4 + r;
      float bv_ = bo[o];
      float s1 = 0.f, s2 = 0.f;
#pragma unroll
      for (int n = 0; n < 4; ++n) {
        int ty = 2 * n + pty, tx = ptx;
        float v = acc[m][n][r] + bv_;
        ob[(size_t)o * 16384 + (ty0 + ty) * 128 + tx0 + tx] = v;
        s1 += v;
        s2 += v * v;
      }
      for (int off = 1; off < 16; off <<= 1) {
        s1 += __shfl_xor(s1, off, 64);
        s2 += __shfl_xor(s2, off, 64);
      }
      if (lr == 0) {
        int gb = b * 256 + tile;
        bnp[((size_t)gb * 256 + o) * 2 + 0] = s1;
        bnp[((size_t)gb * 256 + o) * 2 + 1] = s2;
      }
    }
  }
}

// ---------------- BN reduce + apply ----------------
__global__ __launch_bounds__(256) void k_bnred(
    const float* __restrict__ bnp, const float* __restrict__ gamma,
    const float* __restrict__ beta, float* __restrict__ bns) {
  const int o = blockIdx.x;
  const int tid = threadIdx.x;
  float s1 = 0.f, s2 = 0.f;
  for (int k = tid; k < 2048; k += 256) {
    s1 += bnp[((size_t)k * 256 + o) * 2 + 0];
    s2 += bnp[((size_t)k * 256 + o) * 2 + 1];
  }
  __shared__ float r1[256], r2[256];
  r1[tid] = s1; r2[tid] = s2;
  __syncthreads();
  for (int off = 128; off > 0; off >>= 1) {
    if (tid < off) { r1[tid] += r1[tid + off]; r2[tid] += r2[tid + off]; }
    __syncthreads();
  }
  if (tid == 0) {
    const float cnt = 8.0f * 16384.0f;
    float mean = r1[0] / cnt;
    float var = r2[0] / cnt - mean * mean;
    float sc = gamma[o] * rsqrtf(var + 1e-5f);
    bns[o] = sc;
    bns[256 + o] = beta[o] - mean * sc;
  }
}

__global__ void k_bnapply(float* __restrict__ out, const float* __restrict__ bns) {
  size_t i = ((size_t)blockIdx.x * 256 + threadIdx.x) * 4;
  const size_t total = 33554432;
  const size_t stride = (size_t)gridDim.x * 256 * 4;
  for (; i < total; i += stride) {
    float4 v = *(float4*)(out + i);
    int o = (int)((i >> 14) & 255);
    float sc = bns[o], shv = bns[256 + o];
    v.x = v.x * sc + shv; v.x = v.x > 0.f ? v.x : 0.2f * v.x;
    v.y = v.y * sc + shv; v.y = v.y > 0.f ? v.y : 0.2f * v.y;
    v.z = v.z * sc + shv; v.z = v.z > 0.f ? v.z : 0.2f * v.z;
    v.w = v.w * sc + shv; v.w = v.w > 0.f ? v.w : 0.2f * v.w;
    *(float4*)(out + i) = v;
  }
}

// ---------------- launcher ----------------
extern "C" void kernel_launch(void* const* d_in, const int* in_sizes, int n_in,
                              void* d_out, int out_size, void* d_ws, size_t ws_size,
                              hipStream_t stream) {
  if (ws_size < WS_NEED) return;

  const float* x     = (const float*)d_in[0];
  const float* wq    = (const float*)d_in[1];
  const float* bq    = (const float*)d_in[2];
  const float* wk    = (const float*)d_in[3];
  const float* bk    = (const float*)d_in[4];
  const float* wv    = (const float*)d_in[5];
  const float* bv    = (const float*)d_in[6];
  const float* wo    = (const float*)d_in[7];
  const float* bo    = (const float*)d_in[8];
  const float* gamma = (const float*)d_in[9];
  const float* beta  = (const float*)d_in[10];
  float* out = (float*)d_out;
  char* ws = (char*)d_ws;

  unsigned short* Wb  = (unsigned short*)(ws + WB_OFF);
  unsigned short* Wob = (unsigned short*)(ws + WOB_OFF);
  unsigned short* Qb  = (unsigned short*)(ws + QB_OFF);
  unsigned short* Kb  = (unsigned short*)(ws + KB_OFF);
  unsigned short* Vn  = (unsigned short*)(ws + VN_OFF);
  unsigned short* Yn  = (unsigned short*)(ws + YN_OFF);
  float* scores = (float*)(ws + SC_OFF);
  unsigned short* prb = (unsigned short*)(ws + PRB_OFF);
  float* bnp    = (float*)(ws + BNP_OFF);
  float* bns    = (float*)(ws + BNS_OFF);

  k_prep<<<dim3(3072), dim3(256), 0, stream>>>(wq, wk, wv, wo, Wb, Wob);
  k_zero<<<dim3(547), dim3(256), 0, stream>>>(scores, 559232);
  k_qkv<<<dim3(256, 8), dim3(256), 0, stream>>>(x, Wb, bq, bk, bv, Qb, Kb, Vn);
  k_gram0<<<dim3(64, 8), dim3(256), 0, stream>>>(Qb, Kb, scores);
  k_gram12<1><<<dim3(64, 8), dim3(256), 0, stream>>>(Qb, Kb, scores);
  k_gram12<2><<<dim3(32, 8), dim3(256), 0, stream>>>(Qb, Kb, scores);
  k_gram3<<<dim3(16, 8, 2), dim3(256), 0, stream>>>(Qb, Kb, scores);
  k_softmax<<<dim3(4, 8), dim3(256), 0, stream>>>(scores, prb);
  k_pv<0><<<dim3(128, 8), dim3(256), 0, stream>>>(Vn, prb, Yn);
  k_pv<1><<<dim3(64, 8), dim3(256), 0, stream>>>(Vn, prb, Yn);
  k_pv<2><<<dim3(64, 8), dim3(256), 0, stream>>>(Vn, prb, Yn);
  k_pv3<<<dim3(64, 8), dim3(256), 0, stream>>>(Vn, prb, Yn);
  k_conv<<<dim3(256, 8), dim3(256), 0, stream>>>(Yn, Wob, bo, out, bnp);
  k_bnred<<<dim3(256), dim3(256), 0, stream>>>(bnp, gamma, beta, bns);
  k_bnapply<<<dim3(4096), dim3(256), 0, stream>>>(out, bns);
}

// Round 3
// 763.380 us; speedup vs baseline: 2.8826x; 1.9830x over previous
//
#include <hip/hip_runtime.h>
#include <stdint.h>

// ---------------- geometry ----------------
// B=8, C=256, H=W=128, HW=16384, 4 heads of d_k=64
// idx: HS=WS=2<<idx, S=HS*HS, OH=OW=64>>idx, NSP=OH*OW
// gather:  q[s=(i,j)][d=(c,ohi,owi)] = Q[lo+c][ohi*HS+i][owi*WS+j], s=i*WS+j
// scatter: Y[lo+c][i*OH+ohi][j*OW+owi] = y[s][d]   (transposed vs gather!)
// NHWC buffers (Qn,Kn,Vn,Yn): element (p, c) at [p*256 + (c ^ ((p&7)<<3))]
// granule rule: 8-ch granule cg of pixel p sits at granule (cg ^ (p&7)), order kept.

#define DEVI static __device__ __forceinline__

typedef short bf8 __attribute__((ext_vector_type(8)));   // 8 bf16 (4 VGPRs)
typedef float f32x4 __attribute__((ext_vector_type(4)));

DEVI unsigned short f2bf(float f) {
  unsigned u = __builtin_bit_cast(unsigned, f);
  u = (u + 0x7fffu + ((u >> 16) & 1u)) >> 16;
  return (unsigned short)u;
}
DEVI float bf2f(unsigned short h) {
  unsigned u = ((unsigned)h) << 16;
  return __builtin_bit_cast(float, u);
}

DEVI void gload16(const void* g, void* l) {
  __builtin_amdgcn_global_load_lds(
      (const __attribute__((address_space(1))) unsigned int*)g,
      (__attribute__((address_space(3))) unsigned int*)l, 16, 0, 0);
}

// ---------------- ws layout (bytes) ----------------
static const size_t WB_OFF  = 0;                        // bf16 [3][256][256]
static const size_t WOB_OFF = 393216;                   // bf16 [256][2304] k=(e*256+c)
static const size_t QN_OFF  = 1572864;                  // bf16 NHWC-swz [8][16384][256]
static const size_t KN_OFF  = QN_OFF + 67108864;
static const size_t VN_OFF  = KN_OFF + 67108864;
static const size_t YN_OFF  = VN_OFF + 67108864;        // bf16 NHWC-swz (also part3 overlay)
static const size_t SC_OFF  = YN_OFF + 67108864;        // f32 scores idx0-2 (34944 floats used)
static const size_t PRB_OFF = SC_OFF + 2236928;         // bf16 probs (559232)
static const size_t BNP_OFF = PRB_OFF + 1118464;        // f32 [2048][256][2]
static const size_t BNS_OFF = BNP_OFF + 4194304;        // f32 [2][256]
static const size_t WS_NEED = BNS_OFF + 2048;

// ---------------- prep: convert weights to bf16 (wo reordered) ----------------
__global__ void k_prep(const float* __restrict__ wq, const float* __restrict__ wk,
                       const float* __restrict__ wv, const float* __restrict__ wo,
                       unsigned short* __restrict__ Wb, unsigned short* __restrict__ Wob) {
  int i = blockIdx.x * 256 + threadIdx.x;        // grid covers 786432 exactly
  if (i < 196608) {
    int z = i >> 16, r = i & 65535;
    const float* w = (z == 0) ? wq : (z == 1) ? wk : wv;
    Wb[i] = f2bf(w[r]);
  } else {
    int j = i - 196608;
    int o = j / 2304, k = j - o * 2304;
    int e = k >> 8, c = k & 255;
    Wob[j] = f2bf(wo[(o * 256 + c) * 9 + e]);    // Wob[o][e*256+c] = wo[o][c][e]
  }
}

__global__ void k_zero(float* __restrict__ p, int n) {
  int i = blockIdx.x * 256 + threadIdx.x;
  for (; i < n; i += gridDim.x * 256) p[i] = 0.f;
}

// ---------------- fused QKV projection, all outputs NHWC-swizzled ----------------
__global__ __launch_bounds__(256) void k_qkv(
    const float* __restrict__ x, const unsigned short* __restrict__ Wb,
    const float* __restrict__ bq, const float* __restrict__ bk, const float* __restrict__ bv,
    unsigned short* __restrict__ Qn, unsigned short* __restrict__ Kn,
    unsigned short* __restrict__ Vn) {
  const int pt = blockIdx.x, b = blockIdx.y;
  const int p0 = pt * 64;
  const int tid = threadIdx.x;

  __shared__ __align__(16) unsigned short xt[64 * 256];  // input tile [p][c'] swizzled
  __shared__ __align__(16) unsigned short ot[64 * 256];  // output transpose buffer

  const float* xb = x + (size_t)b * 256 * 16384;
  for (int k = 0; k < 16; ++k) {
    int i = tid + k * 256;
    int c = i >> 4, p4 = (i & 15) * 4;
    float4 v = *(const float4*)(xb + (size_t)c * 16384 + p0 + p4);
    xt[(p4 + 0) * 256 + (c ^ (((p4 + 0) & 7) << 3))] = f2bf(v.x);
    xt[(p4 + 1) * 256 + (c ^ (((p4 + 1) & 7) << 3))] = f2bf(v.y);
    xt[(p4 + 2) * 256 + (c ^ (((p4 + 2) & 7) << 3))] = f2bf(v.z);
    xt[(p4 + 3) * 256 + (c ^ (((p4 + 3) & 7) << 3))] = f2bf(v.w);
  }
  __syncthreads();

  const int wave = tid >> 6, lane = tid & 63;
  const int lr = lane & 15, lk = lane >> 4;
  const int obase = wave * 64;

  for (int z = 0; z < 3; ++z) {
    const unsigned short* Wz = Wb + (size_t)z * 65536;
    f32x4 acc[4][4];
    for (int m = 0; m < 4; ++m)
      for (int n = 0; n < 4; ++n)
        for (int r = 0; r < 4; ++r) acc[m][n][r] = 0.f;

    for (int ks = 0; ks < 8; ++ks) {
      int c0 = ks * 32 + lk * 8;
      bf8 a[4], bb[4];
#pragma unroll
      for (int m = 0; m < 4; ++m)
        a[m] = *(const bf8*)(Wz + (size_t)(obase + m * 16 + lr) * 256 + c0);
#pragma unroll
      for (int n = 0; n < 4; ++n) {
        int p = n * 16 + lr;
        bb[n] = *(const bf8*)(&xt[p * 256 + (c0 ^ ((p & 7) << 3))]);
      }
#pragma unroll
      for (int m = 0; m < 4; ++m)
#pragma unroll
        for (int n = 0; n < 4; ++n)
          acc[m][n] = __builtin_amdgcn_mfma_f32_16x16x32_bf16(a[m], bb[n], acc[m][n], 0, 0, 0);
    }

    const float* bias = (z == 0) ? bq : (z == 1) ? bk : bv;
    unsigned short* On = (z == 0) ? Qn : (z == 1) ? Kn : Vn;
    __syncthreads();   // prior ot consumers done
#pragma unroll
    for (int m = 0; m < 4; ++m) {
      int ob4 = obase + m * 16 + lk * 4;
      float4 b4 = *(const float4*)(bias + ob4);
#pragma unroll
      for (int n = 0; n < 4; ++n) {
        int p = n * 16 + lr;
        ushort4 v4;
        v4.x = f2bf(acc[m][n][0] + b4.x);
        v4.y = f2bf(acc[m][n][1] + b4.y);
        v4.z = f2bf(acc[m][n][2] + b4.z);
        v4.w = f2bf(acc[m][n][3] + b4.w);
        *(ushort4*)(&ot[p * 256 + (ob4 ^ ((p & 7) << 3))]) = v4;
      }
    }
    __syncthreads();
    unsigned short* gb = On + ((size_t)b * 16384 + p0) * 256;
#pragma unroll
    for (int i = 0; i < 8; ++i) {
      int ch = tid + i * 256;
      *(uint4*)(gb + ch * 8) = *(const uint4*)(&ot[ch * 8]);
    }
  }
}

// ---------------- Gram via MFMA, idx 0..2 ----------------
// grid (32 chunks, 8 b); block 256 = 4 waves.
template <int IDX>
__global__ __launch_bounds__(256) void k_gram(
    const unsigned short* __restrict__ Qn, const unsigned short* __restrict__ Kn,
    float* __restrict__ scores) {
  constexpr int HS = 2 << IDX, S = HS * HS, OH = 64 >> IDX, NSP = OH * OH;
  constexpr int SPW = (IDX == 2) ? 2 : 8;      // sp per stage
  constexpr int DSUB = SPW * 64;               // k-elems per stage
  constexpr int SPB = NSP / 32;                // sp per block
  constexpr int STEPS = SPB / SPW;
  constexpr int ROWS = (S < 16) ? S : S;       // 4 / 16 / 64
  constexpr int TPT = S * SPW * 8 / 256;       // granule tasks per thread
  constexpr int SCOFF = (IDX == 0) ? 0 : (IDX == 1) ? 128 : 2176;
  constexpr int HC = IDX * 64;
  constexpr int MT = (IDX == 2) ? 4 : 1;

  const int chk = blockIdx.x, b = blockIdx.y;
  const int tid = threadIdx.x;
  const int wave = tid >> 6, lane = tid & 63, lr = lane & 15, lk = lane >> 4;

  __shared__ __align__(16) unsigned short qg[ROWS * DSUB];
  __shared__ __align__(16) unsigned short kg[ROWS * DSUB];
  __shared__ float red[S * S];

  const size_t base = (size_t)b * 16384 * 256;

  f32x4 acc[MT][MT];
  for (int m = 0; m < MT; ++m)
    for (int n = 0; n < MT; ++n)
      for (int r = 0; r < 4; ++r) acc[m][n][r] = 0.f;

  for (int st = 0; st < STEPS; ++st) {
    const int sp0 = chk * SPB + st * SPW;
    __syncthreads();
#pragma unroll
    for (int r = 0; r < TPT; ++r) {
      int task = tid + r * 256;
      int cg = task & 7, pl = task >> 3;
      int spl = pl >> (2 * (IDX + 1)), s = pl & (S - 1);
      int sp = sp0 + spl;
      int ohi = sp >> (6 - IDX), owi = sp & (OH - 1);
      int ii = s >> (IDX + 1), jj = s & (HS - 1);
      int p = (ohi * HS + ii) * 128 + owi * HS + jj;
      size_t gaddr = base + (size_t)p * 256 + HC + ((cg ^ (p & 7)) << 3);
      int laddr = s * DSUB + (((spl * 8 + cg) ^ (s & 7)) << 3);
      *(uint4*)(qg + laddr) = *(const uint4*)(Qn + gaddr);
      *(uint4*)(kg + laddr) = *(const uint4*)(Kn + gaddr);
    }
    __syncthreads();
    if (IDX == 2) {
      int kgid = wave * 4 + lk;                // wave owns k-chunk = wave
      bf8 a[4], bb[4];
#pragma unroll
      for (int m = 0; m < 4; ++m) {
        int row = m * 16 + lr;
        int off = row * DSUB + ((kgid ^ (row & 7)) << 3);
        a[m] = *(const bf8*)(qg + off);
        bb[m] = *(const bf8*)(kg + off);
      }
#pragma unroll
      for (int m = 0; m < 4; ++m)
#pragma unroll
        for (int n = 0; n < 4; ++n)
          acc[m][n] = __builtin_amdgcn_mfma_f32_16x16x32_bf16(a[m], bb[n], acc[m][n], 0, 0, 0);
    } else {
      int row = lr & (ROWS - 1);
#pragma unroll
      for (int kk = 0; kk < 4; ++kk) {
        int kgid = (wave * 4 + kk) * 4 + lk;   // waves split the 16 k-chunks
        int off = row * DSUB + ((kgid ^ (row & 7)) << 3);
        bf8 a = *(const bf8*)(qg + off);
        bf8 bb = *(const bf8*)(kg + off);
        acc[0][0] = __builtin_amdgcn_mfma_f32_16x16x32_bf16(a, bb, acc[0][0], 0, 0, 0);
      }
    }
  }

  __syncthreads();
  for (int i2 = tid; i2 < S * S; i2 += 256) red[i2] = 0.f;
  __syncthreads();
  if (IDX == 2) {
#pragma unroll
    for (int m = 0; m < 4; ++m)
#pragma unroll
      for (int n = 0; n < 4; ++n)
#pragma unroll
        for (int r = 0; r < 4; ++r)
          atomicAdd(&red[(m * 16 + lk * 4 + r) * 64 + n * 16 + lr], acc[m][n][r]);
  } else if (IDX == 1) {
#pragma unroll
    for (int r = 0; r < 4; ++r)
      atomicAdd(&red[(lk * 4 + r) * 16 + lr], acc[0][0][r]);
  } else {
    if (lk == 0 && lr < 4) {
#pragma unroll
      for (int r = 0; r < 4; ++r)
        atomicAdd(&red[r * 4 + lr], acc[0][0][r]);
    }
  }
  __syncthreads();
  float* sc = scores + SCOFF + (size_t)b * S * S;
  for (int i2 = tid; i2 < S * S; i2 += 256) atomicAdd(sc + i2, red[i2]);
}

// ---------------- Gram idx3: 256x256x4096 GEMM, partials ----------------
// grid (8 k-chunks, 4 t-quadrants, 8 b); partials -> part3[chunk][b][256][256]
__global__ __launch_bounds__(256) void k_gram3(
    const unsigned short* __restrict__ Qn, const unsigned short* __restrict__ Kn,
    float* __restrict__ part3) {
  const int qc = blockIdx.x, tq = blockIdx.y, b = blockIdx.z;
  const int tid = threadIdx.x;
  const int wave = tid >> 6, lane = tid & 63, lr = lane & 15, lk = lane >> 4;

  __shared__ __align__(16) unsigned short qg[256 * 64];  // 32KB [s][c']
  __shared__ __align__(16) unsigned short kg[64 * 64];   // 8KB  [tl][c']

  const size_t base = (size_t)b * 16384 * 256;

  f32x4 acc[4][4];
  for (int m = 0; m < 4; ++m)
    for (int n = 0; n < 4; ++n)
      for (int r = 0; r < 4; ++r) acc[m][n][r] = 0.f;

  for (int st = 0; st < 8; ++st) {
    int sp = qc * 8 + st;
    int ohi = sp >> 3, owi = sp & 7;
    __syncthreads();
#pragma unroll
    for (int r = 0; r < 8; ++r) {            // Q: all 256 s at this sp
      int task = tid + r * 256;
      int cg = task & 7, s = task >> 3;
      int p = (ohi * 16 + (s >> 4)) * 128 + owi * 16 + (s & 15);
      uint4 v = *(const uint4*)(Qn + base + (size_t)p * 256 + 192 + ((cg ^ (p & 7)) << 3));
      *(uint4*)(qg + s * 64 + ((cg ^ (s & 7)) << 3)) = v;
    }
#pragma unroll
    for (int r = 0; r < 2; ++r) {            // K: t-quadrant rows
      int task = tid + r * 256;
      int cg = task & 7, tl = task >> 3;
      int p = (ohi * 16 + tq * 4 + (tl >> 4)) * 128 + owi * 16 + (tl & 15);
      uint4 v = *(const uint4*)(Kn + base + (size_t)p * 256 + 192 + ((cg ^ (p & 7)) << 3));
      *(uint4*)(kg + tl * 64 + ((cg ^ (tl & 7)) << 3)) = v;
    }
    __syncthreads();
#pragma unroll
    for (int kk = 0; kk < 2; ++kk) {
      int kgid = kk * 4 + lk;
      bf8 a[4], bb[4];
#pragma unroll
      for (int m = 0; m < 4; ++m) {
        int row = wave * 64 + m * 16 + lr;
        a[m] = *(const bf8*)(qg + row * 64 + ((kgid ^ (row & 7)) << 3));
      }
#pragma unroll
      for (int n = 0; n < 4; ++n) {
        int rowb = n * 16 + lr;
        bb[n] = *(const bf8*)(kg + rowb * 64 + ((kgid ^ (rowb & 7)) << 3));
      }
#pragma unroll
      for (int m = 0; m < 4; ++m)
#pragma unroll
        for (int n = 0; n < 4; ++n)
          acc[m][n] = __builtin_amdgcn_mfma_f32_16x16x32_bf16(a[m], bb[n], acc[m][n], 0, 0, 0);
    }
  }

  float* pb = part3 + (((size_t)qc * 8 + b) * 65536);
#pragma unroll
  for (int m = 0; m < 4; ++m)
#pragma unroll
    for (int r = 0; r < 4; ++r) {
      int srow = wave * 64 + m * 16 + lk * 4 + r;
#pragma unroll
      for (int n = 0; n < 4; ++n)
        pb[srow * 256 + tq * 64 + n * 16 + lr] = acc[m][n][r];
    }
}

// ---------------- softmax idx0-2 (fp32 scores -> bf16 probs) ----------------
__global__ __launch_bounds__(256) void k_softmax(const float* __restrict__ scores,
                                                 unsigned short* __restrict__ prb) {
  const int idx = blockIdx.x, b = blockIdx.y;
  const int S = 4 << (2 * idx);
  const int off = (idx == 0 ? 0 : idx == 1 ? 128 : 2176) + b * S * S;
  const int s = threadIdx.x;
  if (s >= S) return;
  const float scale = rsqrtf(64.0f * (float)(4096 >> (2 * idx)));
  const float* row = scores + off + s * S;
  float m = -1e30f;
  for (int t = 0; t < S; ++t) m = fmaxf(m, row[t]);
  m *= scale;
  float sum = 0.f;
  for (int t = 0; t < S; ++t) sum += __expf(row[t] * scale - m);
  float inv = 1.0f / sum;
  unsigned short* prow = prb + off + s * S;
  for (int t = 0; t < S; ++t) prow[t] = f2bf(__expf(row[t] * scale - m) * inv);
}

// ---------------- softmax idx3: sum 8 partials + softmax ----------------
// grid (8 s-chunks, 8 b); thread = (row = tid>>3, t-range = (tid&7)*32)
__global__ __launch_bounds__(256) void k_softmax3(const float* __restrict__ part3,
                                                  unsigned short* __restrict__ prb) {
  const int sc_ = blockIdx.x, b = blockIdx.y;
  const int tid = threadIdx.x;
  const int s = sc_ * 32 + (tid >> 3);
  const int t0 = (tid & 7) * 32;
  float v[32];
#pragma unroll
  for (int k = 0; k < 32; ++k) v[k] = 0.f;
  for (int q = 0; q < 8; ++q) {
    const float4* pp = (const float4*)(part3 + (((size_t)q * 8 + b) * 256 + s) * 256 + t0);
#pragma unroll
    for (int k = 0; k < 8; ++k) {
      float4 u = pp[k];
      v[k * 4 + 0] += u.x; v[k * 4 + 1] += u.y; v[k * 4 + 2] += u.z; v[k * 4 + 3] += u.w;
    }
  }
  const float scale = 1.0f / 64.0f;   // rsqrt(64*64)
  float m = -1e30f;
#pragma unroll
  for (int k = 0; k < 32; ++k) { v[k] *= scale; m = fmaxf(m, v[k]); }
  m = fmaxf(m, __shfl_xor(m, 1));
  m = fmaxf(m, __shfl_xor(m, 2));
  m = fmaxf(m, __shfl_xor(m, 4));
  float sum = 0.f;
#pragma unroll
  for (int k = 0; k < 32; ++k) { v[k] = __expf(v[k] - m); sum += v[k]; }
  sum += __shfl_xor(sum, 1);
  sum += __shfl_xor(sum, 2);
  sum += __shfl_xor(sum, 4);
  float inv = 1.0f / sum;
  unsigned short* prw = prb + 34944 + (size_t)b * 65536 + s * 256 + t0;
#pragma unroll
  for (int k8 = 0; k8 < 4; ++k8) {
    unsigned short tmp[8];
#pragma unroll
    for (int e = 0; e < 8; ++e) tmp[e] = f2bf(v[k8 * 8 + e] * inv);
    *(uint4*)(prw + k8 * 8) = *(const uint4*)tmp;
  }
}

// ---------------- PV small S (idx 0,1,2): per-head, NHWC in/out ----------------
template <int IDX>
__global__ __launch_bounds__(256) void k_pv(
    const unsigned short* __restrict__ Vn, const unsigned short* __restrict__ prb,
    unsigned short* __restrict__ Yn) {
  constexpr int HS = 2 << IDX, S = HS * HS, OH = 64 >> IDX;
  constexpr int IT = (IDX == 0) ? 8 : (IDX == 1) ? 4 : 1;
  constexpr int POFF = (IDX == 0) ? 0 : (IDX == 1) ? 128 : 2176;
  const int bx = blockIdx.x, b = blockIdx.y;
  const int c = threadIdx.x & 63, spg = threadIdx.x >> 6;
  __shared__ __align__(16) float pl[S * S];
  const unsigned short* pr = prb + POFF + (size_t)b * S * S;
  for (int i = threadIdx.x; i < S * S; i += 256) pl[i] = bf2f(pr[i]);
  __syncthreads();
  const int hc = IDX * 64;
  const unsigned short* vb = Vn + (size_t)b * 16384 * 256;
  unsigned short* yb = Yn + (size_t)b * 16384 * 256;
  for (int it = 0; it < IT; ++it) {
    int sp = bx * (4 * IT) + it * 4 + spg;
    int ohi = sp >> (6 - IDX), owi = sp & (OH - 1);
    float v[S];
#pragma unroll
    for (int t = 0; t < S; ++t) {
      int po = (ohi * HS + t / HS) * 128 + owi * HS + (t % HS);
      v[t] = bf2f(vb[(size_t)po * 256 + ((hc + c) ^ ((po & 7) << 3))]);
    }
    for (int s = 0; s < S; ++s) {
      const float4* p4 = (const float4*)(pl + s * S);
      float a = 0.f;
#pragma unroll
      for (int t4 = 0; t4 < S / 4; ++t4) {
        float4 pp = p4[t4];
        a += pp.x * v[t4 * 4] + pp.y * v[t4 * 4 + 1] + pp.z * v[t4 * 4 + 2] + pp.w * v[t4 * 4 + 3];
      }
      int po = ((s >> (IDX + 1)) * OH + ohi) * 128 + (s & (HS - 1)) * OH + owi;
      yb[(size_t)po * 256 + ((hc + c) ^ ((po & 7) << 3))] = f2bf(a);
    }
  }
}

// ---------------- PV idx3 (S=256): MFMA GEMM per (b, sp) ----------------
__global__ __launch_bounds__(256) void k_pv3(
    const unsigned short* __restrict__ Vn, const unsigned short* __restrict__ prb,
    unsigned short* __restrict__ Yn) {
  const int sp = blockIdx.x, b = blockIdx.y;   // grid (64, 8)
  const int ohi = sp >> 3, owi = sp & 7;
  const int tid = threadIdx.x;
  __shared__ __align__(16) unsigned short vl[64 * 256];  // [c][t'] swizzled, 32KB
  const unsigned short* vb = Vn + (size_t)b * 16384 * 256;
  {
    int t = tid;  // pixel index t = ti*16+tj
    int po = (ohi * 16 + (t >> 4)) * 128 + owi * 16 + (t & 15);
    const unsigned short* src = vb + (size_t)po * 256;
    int xv = (po & 7) << 3;
#pragma unroll
    for (int g = 0; g < 8; ++g) {
      ushort4 lo = *(const ushort4*)(src + ((192 + g * 8) ^ xv));
      ushort4 hi = *(const ushort4*)(src + ((192 + g * 8) ^ xv) + 4);
      unsigned short vv[8] = {lo.x, lo.y, lo.z, lo.w, hi.x, hi.y, hi.z, hi.w};
#pragma unroll
      for (int e = 0; e < 8; ++e) {
        int cc = g * 8 + e;
        vl[cc * 256 + (t ^ ((cc & 7) << 3))] = vv[e];
      }
    }
  }
  __syncthreads();

  const int wave = tid >> 6, lane = tid & 63;
  const int lr = lane & 15, lk = lane >> 4;
  const int sb = wave * 64;
  const unsigned short* pr = prb + 34944 + (size_t)b * 65536;

  f32x4 acc[4][4];
  for (int m = 0; m < 4; ++m)
    for (int n = 0; n < 4; ++n)
      for (int r = 0; r < 4; ++r) acc[m][n][r] = 0.f;

  for (int kk = 0; kk < 8; ++kk) {
    int t0 = kk * 32 + lk * 8;
    bf8 a[4], bb[4];
#pragma unroll
    for (int m = 0; m < 4; ++m)
      a[m] = *(const bf8*)(pr + (size_t)(sb + m * 16 + lr) * 256 + t0);
#pragma unroll
    for (int n = 0; n < 4; ++n) {
      int cc = n * 16 + lr;
      bb[n] = *(const bf8*)(&vl[cc * 256 + (t0 ^ ((cc & 7) << 3))]);
    }
#pragma unroll
    for (int m = 0; m < 4; ++m)
#pragma unroll
      for (int n = 0; n < 4; ++n)
        acc[m][n] = __builtin_amdgcn_mfma_f32_16x16x32_bf16(a[m], bb[n], acc[m][n], 0, 0, 0);
  }

  unsigned short* yb = Yn + (size_t)b * 16384 * 256;
#pragma unroll
  for (int m = 0; m < 4; ++m) {
#pragma unroll
    for (int r = 0; r < 4; ++r) {
      int s = sb + m * 16 + lk * 4 + r;
      int si = s >> 4, sj = s & 15;
      int po = (si * 8 + ohi) * 128 + sj * 8 + owi;
#pragma unroll
      for (int n = 0; n < 4; ++n) {
        int cc = 192 + n * 16 + lr;
        yb[(size_t)po * 256 + (cc ^ (owi << 3))] = f2bf(acc[m][n][r]);
      }
    }
  }
}

// ---------------- 3x3 conv (MFMA, NHWC-swz in) + BN partials ----------------
__global__ __launch_bounds__(256) void k_conv(
    const unsigned short* __restrict__ Yn, const unsigned short* __restrict__ Wob,
    const float* __restrict__ bo, float* __restrict__ out, float* __restrict__ bnp) {
  const int tile = blockIdx.x, b = blockIdx.y;
  const int ty0 = (tile >> 4) * 8, tx0 = (tile & 15) * 8;
  const int tid = threadIdx.x;

  __shared__ __align__(16) unsigned short yl[100 * 256];  // [hh*10+ww][c'], 51.2KB

  const unsigned short* yb = Yn + (size_t)b * 16384 * 256;
  const int wave = tid >> 6, lane = tid & 63;

  for (int i = wave; i < 50; i += 4) {
    int hh = i / 5, ck = i % 5;
    int h = ty0 - 1 + hh;
    unsigned short* ldst = yl + hh * 2560 + ck * 512;
    if (h >= 0 && h < 128) {
      const unsigned short* g = yb + (h * 128 + tx0 - 1) * 256 + ck * 512 + lane * 8;
      gload16(g, ldst);
    } else {
      uint4 z4 = {0u, 0u, 0u, 0u};
      *(uint4*)(ldst + lane * 8) = z4;
    }
  }
  __syncthreads();
  if (tx0 == 0) {
    for (int i = tid; i < 320; i += 256) {
      int hh = i >> 5, chh = i & 31;
      uint4 z4 = {0u, 0u, 0u, 0u};
      *(uint4*)(yl + hh * 2560 + chh * 8) = z4;
    }
  }
  if (tx0 == 120) {
    for (int i = tid; i < 320; i += 256) {
      int hh = i >> 5, chh = i & 31;
      uint4 z4 = {0u, 0u, 0u, 0u};
      *(uint4*)(yl + hh * 2560 + 9 * 256 + chh * 8) = z4;
    }
  }
  __syncthreads();

  const int lr = lane & 15, lk = lane >> 4;
  const int obase = wave * 64;
  const int pty = lr >> 3, ptx = lr & 7;

  f32x4 acc[4][4];
  for (int m = 0; m < 4; ++m)
    for (int n = 0; n < 4; ++n)
      for (int r = 0; r < 4; ++r) acc[m][n][r] = 0.f;

  int dy = 0, dx = 0;
  for (int e = 0; e < 9; ++e) {
    int spn[4], gxn[4];
#pragma unroll
    for (int n = 0; n < 4; ++n) {
      int ty = 2 * n + pty, tx = ptx;
      spn[n] = (ty + dy) * 10 + tx + dx;
      gxn[n] = (tx + dx + 7) & 7;
    }
#pragma unroll
    for (int k8 = 0; k8 < 8; ++k8) {
      bf8 a[4], bb[4];
#pragma unroll
      for (int m = 0; m < 4; ++m)
        a[m] = *(const bf8*)(Wob + (size_t)(obase + m * 16 + lr) * 2304 + e * 256 + k8 * 32 + lk * 8);
#pragma unroll
      for (int n = 0; n < 4; ++n)
        bb[n] = *(const bf8*)(yl + spn[n] * 256 + (((k8 * 4 + lk) ^ gxn[n]) << 3));
#pragma unroll
      for (int m = 0; m < 4; ++m)
#pragma unroll
        for (int n = 0; n < 4; ++n)
          acc[m][n] = __builtin_amdgcn_mfma_f32_16x16x32_bf16(a[m], bb[n], acc[m][n], 0, 0, 0);
    }
    if (++dx == 3) { dx = 0; ++dy; }
  }

  float* ob = out + (size_t)b * 256 * 16384;
#pragma unroll
  for (int m = 0; m < 4; ++m) {
#pragma unroll
    for (int r = 0; r < 4; ++r) {
      int o = obase + m * 16 + lk * 4 + r;
      float bv_ = bo[o];
      float s1 = 0.f, s2 = 0.f;
#pragma unroll
      for (int n = 0; n < 4; ++n) {
        int ty = 2 * n + pty, tx = ptx;
        float v = acc[m][n][r] + bv_;
        ob[(size_t)o * 16384 + (ty0 + ty) * 128 + tx0 + tx] = v;
        s1 += v;
        s2 += v * v;
      }
      for (int off = 1; off < 16; off <<= 1) {
        s1 += __shfl_xor(s1, off, 64);
        s2 += __shfl_xor(s2, off, 64);
      }
      if (lr == 0) {
        int gb = b * 256 + tile;
        bnp[((size_t)gb * 256 + o) * 2 + 0] = s1;
        bnp[((size_t)gb * 256 + o) * 2 + 1] = s2;
      }
    }
  }
}

// ---------------- BN reduce + apply ----------------
__global__ __launch_bounds__(256) void k_bnred(
    const float* __restrict__ bnp, const float* __restrict__ gamma,
    const float* __restrict__ beta, float* __restrict__ bns) {
  const int o = blockIdx.x;
  const int tid = threadIdx.x;
  float s1 = 0.f, s2 = 0.f;
  for (int k = tid; k < 2048; k += 256) {
    s1 += bnp[((size_t)k * 256 + o) * 2 + 0];
    s2 += bnp[((size_t)k * 256 + o) * 2 + 1];
  }
  __shared__ float r1[256], r2[256];
  r1[tid] = s1; r2[tid] = s2;
  __syncthreads();
  for (int off = 128; off > 0; off >>= 1) {
    if (tid < off) { r1[tid] += r1[tid + off]; r2[tid] += r2[tid + off]; }
    __syncthreads();
  }
  if (tid == 0) {
    const float cnt = 8.0f * 16384.0f;
    float mean = r1[0] / cnt;
    float var = r2[0] / cnt - mean * mean;
    float sc = gamma[o] * rsqrtf(var + 1e-5f);
    bns[o] = sc;
    bns[256 + o] = beta[o] - mean * sc;
  }
}

__global__ void k_bnapply(float* __restrict__ out, const float* __restrict__ bns) {
  size_t i = ((size_t)blockIdx.x * 256 + threadIdx.x) * 4;
  const size_t total = 33554432;
  const size_t stride = (size_t)gridDim.x * 256 * 4;
  for (; i < total; i += stride) {
    float4 v = *(float4*)(out + i);
    int o = (int)((i >> 14) & 255);
    float sc = bns[o], shv = bns[256 + o];
    v.x = v.x * sc + shv; v.x = v.x > 0.f ? v.x : 0.2f * v.x;
    v.y = v.y * sc + shv; v.y = v.y > 0.f ? v.y : 0.2f * v.y;
    v.z = v.z * sc + shv; v.z = v.z > 0.f ? v.z : 0.2f * v.z;
    v.w = v.w * sc + shv; v.w = v.w > 0.f ? v.w : 0.2f * v.w;
    *(float4*)(out + i) = v;
  }
}

// ---------------- launcher ----------------
extern "C" void kernel_launch(void* const* d_in, const int* in_sizes, int n_in,
                              void* d_out, int out_size, void* d_ws, size_t ws_size,
                              hipStream_t stream) {
  if (ws_size < WS_NEED) return;

  const float* x     = (const float*)d_in[0];
  const float* wq    = (const float*)d_in[1];
  const float* bq    = (const float*)d_in[2];
  const float* wk    = (const float*)d_in[3];
  const float* bk    = (const float*)d_in[4];
  const float* wv    = (const float*)d_in[5];
  const float* bv    = (const float*)d_in[6];
  const float* wo    = (const float*)d_in[7];
  const float* bo    = (const float*)d_in[8];
  const float* gamma = (const float*)d_in[9];
  const float* beta  = (const float*)d_in[10];
  float* out = (float*)d_out;
  char* ws = (char*)d_ws;

  unsigned short* Wb  = (unsigned short*)(ws + WB_OFF);
  unsigned short* Wob = (unsigned short*)(ws + WOB_OFF);
  unsigned short* Qn  = (unsigned short*)(ws + QN_OFF);
  unsigned short* Kn  = (unsigned short*)(ws + KN_OFF);
  unsigned short* Vn  = (unsigned short*)(ws + VN_OFF);
  unsigned short* Yn  = (unsigned short*)(ws + YN_OFF);
  float* part3 = (float*)(ws + YN_OFF);          // overlay: used before Yn is written
  float* scores = (float*)(ws + SC_OFF);
  unsigned short* prb = (unsigned short*)(ws + PRB_OFF);
  float* bnp    = (float*)(ws + BNP_OFF);
  float* bns    = (float*)(ws + BNS_OFF);

  k_prep<<<dim3(3072), dim3(256), 0, stream>>>(wq, wk, wv, wo, Wb, Wob);
  k_zero<<<dim3(137), dim3(256), 0, stream>>>(scores, 34944);
  k_qkv<<<dim3(256, 8), dim3(256), 0, stream>>>(x, Wb, bq, bk, bv, Qn, Kn, Vn);
  k_gram<0><<<dim3(32, 8), dim3(256), 0, stream>>>(Qn, Kn, scores);
  k_gram<1><<<dim3(32, 8), dim3(256), 0, stream>>>(Qn, Kn, scores);
  k_gram<2><<<dim3(32, 8), dim3(256), 0, stream>>>(Qn, Kn, scores);
  k_gram3<<<dim3(8, 4, 8), dim3(256), 0, stream>>>(Qn, Kn, part3);
  k_softmax<<<dim3(3, 8), dim3(256), 0, stream>>>(scores, prb);
  k_softmax3<<<dim3(8, 8), dim3(256), 0, stream>>>(part3, prb);
  k_pv<0><<<dim3(128, 8), dim3(256), 0, stream>>>(Vn, prb, Yn);
  k_pv<1><<<dim3(64, 8), dim3(256), 0, stream>>>(Vn, prb, Yn);
  k_pv<2><<<dim3(64, 8), dim3(256), 0, stream>>>(Vn, prb, Yn);
  k_pv3<<<dim3(64, 8), dim3(256), 0, stream>>>(Vn, prb, Yn);
  k_conv<<<dim3(256, 8), dim3(256), 0, stream>>>(Yn, Wob, bo, out, bnp);
  k_bnred<<<dim3(256), dim3(256), 0, stream>>>(bnp, gamma, beta, bns);
  k_bnapply<<<dim3(4096), dim3(256), 0, stream>>>(out, bns);
}

// Round 4
// 613.331 us; speedup vs baseline: 3.5878x; 1.2446x over previous
//
#include <hip/hip_runtime.h>
#include <stdint.h>

// ---------------- geometry ----------------
// B=8, C=256, H=W=128, HW=16384, 4 heads of d_k=64
// idx: HS=WS=2<<idx, S=HS*HS, OH=OW=64>>idx, NSP=OH*OW
// gather:  q[s=(i,j)][d=(c,ohi,owi)] = Q[lo+c][ohi*HS+i][owi*WS+j], s=i*WS+j
// scatter: Y[lo+c][i*OH+ohi][j*OW+owi] = y[s][d]   (transposed vs gather!)
// NHWC buffers (Qn,Kn,Vn,Yn): element (p, c) at [p*256 + (c ^ ((p&7)<<3))]
// granule rule: 8-ch granule g of pixel p sits at granule slot (g ^ (p&7)).

#define DEVI static __device__ __forceinline__

typedef short bf8 __attribute__((ext_vector_type(8)));   // 8 bf16 (4 VGPRs)
typedef float f32x4 __attribute__((ext_vector_type(4)));

DEVI unsigned short f2bf(float f) {
  unsigned u = __builtin_bit_cast(unsigned, f);
  u = (u + 0x7fffu + ((u >> 16) & 1u)) >> 16;
  return (unsigned short)u;
}
DEVI float bf2f(unsigned short h) {
  unsigned u = ((unsigned)h) << 16;
  return __builtin_bit_cast(float, u);
}

DEVI void gload16(const void* g, void* l) {
  __builtin_amdgcn_global_load_lds(
      (const __attribute__((address_space(1))) unsigned int*)g,
      (__attribute__((address_space(3))) unsigned int*)l, 16, 0, 0);
}

// ---------------- ws layout (bytes) ----------------
static const size_t WB_OFF  = 0;                        // bf16 [3][256][256]
static const size_t WOB_OFF = 393216;                   // bf16 [256][2304] k=(e*256+c)
static const size_t QN_OFF  = 1572864;                  // bf16 NHWC-swz [8][16384][256]
static const size_t KN_OFF  = QN_OFF + 67108864;
static const size_t VN_OFF  = KN_OFF + 67108864;
static const size_t YN_OFF  = VN_OFF + 67108864;        // bf16 NHWC-swz (also part3 overlay)
static const size_t SC_OFF  = YN_OFF + 67108864;        // f32 scores idx0-2 (34944 floats used)
static const size_t PRB_OFF = SC_OFF + 2236928;         // bf16 probs (559232)
static const size_t BNP_OFF = PRB_OFF + 1118464;        // f32 [512][256][2]
static const size_t BNS_OFF = BNP_OFF + 4194304;        // f32 [2][256]
static const size_t ZP_OFF  = BNS_OFF + 2048;           // 256B zero page for OOB gloads
static const size_t WS_NEED = ZP_OFF + 256;

// ---------------- prep: convert weights to bf16 (wo reordered) ----------------
__global__ void k_prep(const float* __restrict__ wq, const float* __restrict__ wk,
                       const float* __restrict__ wv, const float* __restrict__ wo,
                       unsigned short* __restrict__ Wb, unsigned short* __restrict__ Wob) {
  int i = blockIdx.x * 256 + threadIdx.x;        // grid covers 786432 exactly
  if (i < 196608) {
    int z = i >> 16, r = i & 65535;
    const float* w = (z == 0) ? wq : (z == 1) ? wk : wv;
    Wb[i] = f2bf(w[r]);
  } else {
    int j = i - 196608;
    int o = j / 2304, k = j - o * 2304;
    int e = k >> 8, c = k & 255;
    Wob[j] = f2bf(wo[(o * 256 + c) * 9 + e]);    // Wob[o][e*256+c] = wo[o][c][e]
  }
}

__global__ void k_zero(float* __restrict__ p, int n) {
  int i = blockIdx.x * 256 + threadIdx.x;
  for (; i < n; i += gridDim.x * 256) p[i] = 0.f;
}

// ---------------- fused QKV projection, all outputs NHWC-swizzled ----------------
__global__ __launch_bounds__(256) void k_qkv(
    const float* __restrict__ x, const unsigned short* __restrict__ Wb,
    const float* __restrict__ bq, const float* __restrict__ bk, const float* __restrict__ bv,
    unsigned short* __restrict__ Qn, unsigned short* __restrict__ Kn,
    unsigned short* __restrict__ Vn) {
  const int pt = blockIdx.x, b = blockIdx.y;
  const int p0 = pt * 64;
  const int tid = threadIdx.x;

  __shared__ __align__(16) unsigned short xt[64 * 256];  // input tile [p][c'] swizzled
  __shared__ __align__(16) unsigned short ot[64 * 256];  // output transpose buffer

  const float* xb = x + (size_t)b * 256 * 16384;
  for (int k = 0; k < 16; ++k) {
    int i = tid + k * 256;
    int c = i >> 4, p4 = (i & 15) * 4;
    float4 v = *(const float4*)(xb + (size_t)c * 16384 + p0 + p4);
    xt[(p4 + 0) * 256 + (c ^ (((p4 + 0) & 7) << 3))] = f2bf(v.x);
    xt[(p4 + 1) * 256 + (c ^ (((p4 + 1) & 7) << 3))] = f2bf(v.y);
    xt[(p4 + 2) * 256 + (c ^ (((p4 + 2) & 7) << 3))] = f2bf(v.z);
    xt[(p4 + 3) * 256 + (c ^ (((p4 + 3) & 7) << 3))] = f2bf(v.w);
  }
  __syncthreads();

  const int wave = tid >> 6, lane = tid & 63;
  const int lr = lane & 15, lk = lane >> 4;
  const int obase = wave * 64;

  for (int z = 0; z < 3; ++z) {
    const unsigned short* Wz = Wb + (size_t)z * 65536;
    f32x4 acc[4][4];
    for (int m = 0; m < 4; ++m)
      for (int n = 0; n < 4; ++n)
        for (int r = 0; r < 4; ++r) acc[m][n][r] = 0.f;

    for (int ks = 0; ks < 8; ++ks) {
      int c0 = ks * 32 + lk * 8;
      bf8 a[4], bb[4];
#pragma unroll
      for (int m = 0; m < 4; ++m)
        a[m] = *(const bf8*)(Wz + (size_t)(obase + m * 16 + lr) * 256 + c0);
#pragma unroll
      for (int n = 0; n < 4; ++n) {
        int p = n * 16 + lr;
        bb[n] = *(const bf8*)(&xt[p * 256 + (c0 ^ ((p & 7) << 3))]);
      }
#pragma unroll
      for (int m = 0; m < 4; ++m)
#pragma unroll
        for (int n = 0; n < 4; ++n)
          acc[m][n] = __builtin_amdgcn_mfma_f32_16x16x32_bf16(a[m], bb[n], acc[m][n], 0, 0, 0);
    }

    const float* bias = (z == 0) ? bq : (z == 1) ? bk : bv;
    unsigned short* On = (z == 0) ? Qn : (z == 1) ? Kn : Vn;
    __syncthreads();   // prior ot consumers done
#pragma unroll
    for (int m = 0; m < 4; ++m) {
      int ob4 = obase + m * 16 + lk * 4;
      float4 b4 = *(const float4*)(bias + ob4);
#pragma unroll
      for (int n = 0; n < 4; ++n) {
        int p = n * 16 + lr;
        ushort4 v4;
        v4.x = f2bf(acc[m][n][0] + b4.x);
        v4.y = f2bf(acc[m][n][1] + b4.y);
        v4.z = f2bf(acc[m][n][2] + b4.z);
        v4.w = f2bf(acc[m][n][3] + b4.w);
        *(ushort4*)(&ot[p * 256 + (ob4 ^ ((p & 7) << 3))]) = v4;
      }
    }
    __syncthreads();
    unsigned short* gb = On + ((size_t)b * 16384 + p0) * 256;
#pragma unroll
    for (int i = 0; i < 8; ++i) {
      int ch = tid + i * 256;
      *(uint4*)(gb + ch * 8) = *(const uint4*)(&ot[ch * 8]);
    }
  }
}

// ---------------- Gram via MFMA, idx 0..2 ----------------
template <int IDX>
__global__ __launch_bounds__(256) void k_gram(
    const unsigned short* __restrict__ Qn, const unsigned short* __restrict__ Kn,
    float* __restrict__ scores) {
  constexpr int HS = 2 << IDX, S = HS * HS, OH = 64 >> IDX, NSP = OH * OH;
  constexpr int SPW = (IDX == 2) ? 2 : 8;
  constexpr int DSUB = SPW * 64;
  constexpr int SPB = NSP / 32;
  constexpr int STEPS = SPB / SPW;
  constexpr int ROWS = S;
  constexpr int TPT = S * SPW * 8 / 256;
  constexpr int SCOFF = (IDX == 0) ? 0 : (IDX == 1) ? 128 : 2176;
  constexpr int HC = IDX * 64;
  constexpr int MT = (IDX == 2) ? 4 : 1;

  const int chk = blockIdx.x, b = blockIdx.y;
  const int tid = threadIdx.x;
  const int wave = tid >> 6, lane = tid & 63, lr = lane & 15, lk = lane >> 4;

  __shared__ __align__(16) unsigned short qg[ROWS * DSUB];
  __shared__ __align__(16) unsigned short kg[ROWS * DSUB];
  __shared__ float red[S * S];

  const size_t base = (size_t)b * 16384 * 256;

  f32x4 acc[MT][MT];
  for (int m = 0; m < MT; ++m)
    for (int n = 0; n < MT; ++n)
      for (int r = 0; r < 4; ++r) acc[m][n][r] = 0.f;

  for (int st = 0; st < STEPS; ++st) {
    const int sp0 = chk * SPB + st * SPW;
    __syncthreads();
#pragma unroll
    for (int r = 0; r < TPT; ++r) {
      int task = tid + r * 256;
      int cg = task & 7, pl = task >> 3;
      int spl = pl >> (2 * (IDX + 1)), s = pl & (S - 1);
      int sp = sp0 + spl;
      int ohi = sp >> (6 - IDX), owi = sp & (OH - 1);
      int ii = s >> (IDX + 1), jj = s & (HS - 1);
      int p = (ohi * HS + ii) * 128 + owi * HS + jj;
      size_t gaddr = base + (size_t)p * 256 + HC + ((cg ^ (p & 7)) << 3);
      int laddr = s * DSUB + (((spl * 8 + cg) ^ (s & 7)) << 3);
      *(uint4*)(qg + laddr) = *(const uint4*)(Qn + gaddr);
      *(uint4*)(kg + laddr) = *(const uint4*)(Kn + gaddr);
    }
    __syncthreads();
    if (IDX == 2) {
      int kgid = wave * 4 + lk;
      bf8 a[4], bb[4];
#pragma unroll
      for (int m = 0; m < 4; ++m) {
        int row = m * 16 + lr;
        int off = row * DSUB + ((kgid ^ (row & 7)) << 3);
        a[m] = *(const bf8*)(qg + off);
        bb[m] = *(const bf8*)(kg + off);
      }
#pragma unroll
      for (int m = 0; m < 4; ++m)
#pragma unroll
        for (int n = 0; n < 4; ++n)
          acc[m][n] = __builtin_amdgcn_mfma_f32_16x16x32_bf16(a[m], bb[n], acc[m][n], 0, 0, 0);
    } else {
      int row = lr & (ROWS - 1);
#pragma unroll
      for (int kk = 0; kk < 4; ++kk) {
        int kgid = (wave * 4 + kk) * 4 + lk;
        int off = row * DSUB + ((kgid ^ (row & 7)) << 3);
        bf8 a = *(const bf8*)(qg + off);
        bf8 bb = *(const bf8*)(kg + off);
        acc[0][0] = __builtin_amdgcn_mfma_f32_16x16x32_bf16(a, bb, acc[0][0], 0, 0, 0);
      }
    }
  }

  __syncthreads();
  for (int i2 = tid; i2 < S * S; i2 += 256) red[i2] = 0.f;
  __syncthreads();
  if (IDX == 2) {
#pragma unroll
    for (int m = 0; m < 4; ++m)
#pragma unroll
      for (int n = 0; n < 4; ++n)
#pragma unroll
        for (int r = 0; r < 4; ++r)
          atomicAdd(&red[(m * 16 + lk * 4 + r) * 64 + n * 16 + lr], acc[m][n][r]);
  } else if (IDX == 1) {
#pragma unroll
    for (int r = 0; r < 4; ++r)
      atomicAdd(&red[(lk * 4 + r) * 16 + lr], acc[0][0][r]);
  } else {
    if (lk == 0 && lr < 4) {
#pragma unroll
      for (int r = 0; r < 4; ++r)
        atomicAdd(&red[r * 4 + lr], acc[0][0][r]);
    }
  }
  __syncthreads();
  float* sc = scores + SCOFF + (size_t)b * S * S;
  for (int i2 = tid; i2 < S * S; i2 += 256) atomicAdd(sc + i2, red[i2]);
}

// ---------------- Gram idx3: 256x256x4096 GEMM, partials ----------------
__global__ __launch_bounds__(256) void k_gram3(
    const unsigned short* __restrict__ Qn, const unsigned short* __restrict__ Kn,
    float* __restrict__ part3) {
  const int qc = blockIdx.x, tq = blockIdx.y, b = blockIdx.z;
  const int tid = threadIdx.x;
  const int wave = tid >> 6, lane = tid & 63, lr = lane & 15, lk = lane >> 4;

  __shared__ __align__(16) unsigned short qg[256 * 64];
  __shared__ __align__(16) unsigned short kg[64 * 64];

  const size_t base = (size_t)b * 16384 * 256;

  f32x4 acc[4][4];
  for (int m = 0; m < 4; ++m)
    for (int n = 0; n < 4; ++n)
      for (int r = 0; r < 4; ++r) acc[m][n][r] = 0.f;

  for (int st = 0; st < 8; ++st) {
    int sp = qc * 8 + st;
    int ohi = sp >> 3, owi = sp & 7;
    __syncthreads();
#pragma unroll
    for (int r = 0; r < 8; ++r) {
      int task = tid + r * 256;
      int cg = task & 7, s = task >> 3;
      int p = (ohi * 16 + (s >> 4)) * 128 + owi * 16 + (s & 15);
      uint4 v = *(const uint4*)(Qn + base + (size_t)p * 256 + 192 + ((cg ^ (p & 7)) << 3));
      *(uint4*)(qg + s * 64 + ((cg ^ (s & 7)) << 3)) = v;
    }
#pragma unroll
    for (int r = 0; r < 2; ++r) {
      int task = tid + r * 256;
      int cg = task & 7, tl = task >> 3;
      int p = (ohi * 16 + tq * 4 + (tl >> 4)) * 128 + owi * 16 + (tl & 15);
      uint4 v = *(const uint4*)(Kn + base + (size_t)p * 256 + 192 + ((cg ^ (p & 7)) << 3));
      *(uint4*)(kg + tl * 64 + ((cg ^ (tl & 7)) << 3)) = v;
    }
    __syncthreads();
#pragma unroll
    for (int kk = 0; kk < 2; ++kk) {
      int kgid = kk * 4 + lk;
      bf8 a[4], bb[4];
#pragma unroll
      for (int m = 0; m < 4; ++m) {
        int row = wave * 64 + m * 16 + lr;
        a[m] = *(const bf8*)(qg + row * 64 + ((kgid ^ (row & 7)) << 3));
      }
#pragma unroll
      for (int n = 0; n < 4; ++n) {
        int rowb = n * 16 + lr;
        bb[n] = *(const bf8*)(kg + rowb * 64 + ((kgid ^ (rowb & 7)) << 3));
      }
#pragma unroll
      for (int m = 0; m < 4; ++m)
#pragma unroll
        for (int n = 0; n < 4; ++n)
          acc[m][n] = __builtin_amdgcn_mfma_f32_16x16x32_bf16(a[m], bb[n], acc[m][n], 0, 0, 0);
    }
  }

  float* pb = part3 + (((size_t)qc * 8 + b) * 65536);
#pragma unroll
  for (int m = 0; m < 4; ++m)
#pragma unroll
    for (int r = 0; r < 4; ++r) {
      int srow = wave * 64 + m * 16 + lk * 4 + r;
#pragma unroll
      for (int n = 0; n < 4; ++n)
        pb[srow * 256 + tq * 64 + n * 16 + lr] = acc[m][n][r];
    }
}

// ---------------- softmax idx0-2 (fp32 scores -> bf16 probs) ----------------
__global__ __launch_bounds__(256) void k_softmax(const float* __restrict__ scores,
                                                 unsigned short* __restrict__ prb) {
  const int idx = blockIdx.x, b = blockIdx.y;
  const int S = 4 << (2 * idx);
  const int off = (idx == 0 ? 0 : idx == 1 ? 128 : 2176) + b * S * S;
  const int s = threadIdx.x;
  if (s >= S) return;
  const float scale = rsqrtf(64.0f * (float)(4096 >> (2 * idx)));
  const float* row = scores + off + s * S;
  float m = -1e30f;
  for (int t = 0; t < S; ++t) m = fmaxf(m, row[t]);
  m *= scale;
  float sum = 0.f;
  for (int t = 0; t < S; ++t) sum += __expf(row[t] * scale - m);
  float inv = 1.0f / sum;
  unsigned short* prow = prb + off + s * S;
  for (int t = 0; t < S; ++t) prow[t] = f2bf(__expf(row[t] * scale - m) * inv);
}

// ---------------- softmax idx3: sum 8 partials + softmax ----------------
__global__ __launch_bounds__(256) void k_softmax3(const float* __restrict__ part3,
                                                  unsigned short* __restrict__ prb) {
  const int sc_ = blockIdx.x, b = blockIdx.y;
  const int tid = threadIdx.x;
  const int s = sc_ * 32 + (tid >> 3);
  const int t0 = (tid & 7) * 32;
  float v[32];
#pragma unroll
  for (int k = 0; k < 32; ++k) v[k] = 0.f;
  for (int q = 0; q < 8; ++q) {
    const float4* pp = (const float4*)(part3 + (((size_t)q * 8 + b) * 256 + s) * 256 + t0);
#pragma unroll
    for (int k = 0; k < 8; ++k) {
      float4 u = pp[k];
      v[k * 4 + 0] += u.x; v[k * 4 + 1] += u.y; v[k * 4 + 2] += u.z; v[k * 4 + 3] += u.w;
    }
  }
  const float scale = 1.0f / 64.0f;
  float m = -1e30f;
#pragma unroll
  for (int k = 0; k < 32; ++k) { v[k] *= scale; m = fmaxf(m, v[k]); }
  m = fmaxf(m, __shfl_xor(m, 1));
  m = fmaxf(m, __shfl_xor(m, 2));
  m = fmaxf(m, __shfl_xor(m, 4));
  float sum = 0.f;
#pragma unroll
  for (int k = 0; k < 32; ++k) { v[k] = __expf(v[k] - m); sum += v[k]; }
  sum += __shfl_xor(sum, 1);
  sum += __shfl_xor(sum, 2);
  sum += __shfl_xor(sum, 4);
  float inv = 1.0f / sum;
  unsigned short* prw = prb + 34944 + (size_t)b * 65536 + s * 256 + t0;
#pragma unroll
  for (int k8 = 0; k8 < 4; ++k8) {
    unsigned short tmp[8];
#pragma unroll
    for (int e = 0; e < 8; ++e) tmp[e] = f2bf(v[k8 * 8 + e] * inv);
    *(uint4*)(prw + k8 * 8) = *(const uint4*)tmp;
  }
}

// ---------------- PV small S (idx 0,1,2): per-head, NHWC in/out ----------------
template <int IDX>
__global__ __launch_bounds__(256) void k_pv(
    const unsigned short* __restrict__ Vn, const unsigned short* __restrict__ prb,
    unsigned short* __restrict__ Yn) {
  constexpr int HS = 2 << IDX, S = HS * HS, OH = 64 >> IDX;
  constexpr int IT = (IDX == 0) ? 8 : (IDX == 1) ? 4 : 1;
  constexpr int POFF = (IDX == 0) ? 0 : (IDX == 1) ? 128 : 2176;
  const int bx = blockIdx.x, b = blockIdx.y;
  const int c = threadIdx.x & 63, spg = threadIdx.x >> 6;
  __shared__ __align__(16) float pl[S * S];
  const unsigned short* pr = prb + POFF + (size_t)b * S * S;
  for (int i = threadIdx.x; i < S * S; i += 256) pl[i] = bf2f(pr[i]);
  __syncthreads();
  const int hc = IDX * 64;
  const unsigned short* vb = Vn + (size_t)b * 16384 * 256;
  unsigned short* yb = Yn + (size_t)b * 16384 * 256;
  for (int it = 0; it < IT; ++it) {
    int sp = bx * (4 * IT) + it * 4 + spg;
    int ohi = sp >> (6 - IDX), owi = sp & (OH - 1);
    float v[S];
#pragma unroll
    for (int t = 0; t < S; ++t) {
      int po = (ohi * HS + t / HS) * 128 + owi * HS + (t % HS);
      v[t] = bf2f(vb[(size_t)po * 256 + ((hc + c) ^ ((po & 7) << 3))]);
    }
    for (int s = 0; s < S; ++s) {
      const float4* p4 = (const float4*)(pl + s * S);
      float a = 0.f;
#pragma unroll
      for (int t4 = 0; t4 < S / 4; ++t4) {
        float4 pp = p4[t4];
        a += pp.x * v[t4 * 4] + pp.y * v[t4 * 4 + 1] + pp.z * v[t4 * 4 + 2] + pp.w * v[t4 * 4 + 3];
      }
      int po = ((s >> (IDX + 1)) * OH + ohi) * 128 + (s & (HS - 1)) * OH + owi;
      yb[(size_t)po * 256 + ((hc + c) ^ ((po & 7) << 3))] = f2bf(a);
    }
  }
}

// ---------------- PV idx3 (S=256): MFMA GEMM per (b, sp) ----------------
__global__ __launch_bounds__(256) void k_pv3(
    const unsigned short* __restrict__ Vn, const unsigned short* __restrict__ prb,
    unsigned short* __restrict__ Yn) {
  const int sp = blockIdx.x, b = blockIdx.y;
  const int ohi = sp >> 3, owi = sp & 7;
  const int tid = threadIdx.x;
  __shared__ __align__(16) unsigned short vl[64 * 256];
  const unsigned short* vb = Vn + (size_t)b * 16384 * 256;
  {
    int t = tid;
    int po = (ohi * 16 + (t >> 4)) * 128 + owi * 16 + (t & 15);
    const unsigned short* src = vb + (size_t)po * 256;
    int xv = (po & 7) << 3;
#pragma unroll
    for (int g = 0; g < 8; ++g) {
      ushort4 lo = *(const ushort4*)(src + ((192 + g * 8) ^ xv));
      ushort4 hi = *(const ushort4*)(src + ((192 + g * 8) ^ xv) + 4);
      unsigned short vv[8] = {lo.x, lo.y, lo.z, lo.w, hi.x, hi.y, hi.z, hi.w};
#pragma unroll
      for (int e = 0; e < 8; ++e) {
        int cc = g * 8 + e;
        vl[cc * 256 + (t ^ ((cc & 7) << 3))] = vv[e];
      }
    }
  }
  __syncthreads();

  const int wave = tid >> 6, lane = tid & 63;
  const int lr = lane & 15, lk = lane >> 4;
  const int sb = wave * 64;
  const unsigned short* pr = prb + 34944 + (size_t)b * 65536;

  f32x4 acc[4][4];
  for (int m = 0; m < 4; ++m)
    for (int n = 0; n < 4; ++n)
      for (int r = 0; r < 4; ++r) acc[m][n][r] = 0.f;

  for (int kk = 0; kk < 8; ++kk) {
    int t0 = kk * 32 + lk * 8;
    bf8 a[4], bb[4];
#pragma unroll
    for (int m = 0; m < 4; ++m)
      a[m] = *(const bf8*)(pr + (size_t)(sb + m * 16 + lr) * 256 + t0);
#pragma unroll
    for (int n = 0; n < 4; ++n) {
      int cc = n * 16 + lr;
      bb[n] = *(const bf8*)(&vl[cc * 256 + (t0 ^ ((cc & 7) << 3))]);
    }
#pragma unroll
    for (int m = 0; m < 4; ++m)
#pragma unroll
      for (int n = 0; n < 4; ++n)
        acc[m][n] = __builtin_amdgcn_mfma_f32_16x16x32_bf16(a[m], bb[n], acc[m][n], 0, 0, 0);
  }

  unsigned short* yb = Yn + (size_t)b * 16384 * 256;
#pragma unroll
  for (int m = 0; m < 4; ++m) {
#pragma unroll
    for (int r = 0; r < 4; ++r) {
      int s = sb + m * 16 + lk * 4 + r;
      int si = s >> 4, sj = s & 15;
      int po = (si * 8 + ohi) * 128 + sj * 8 + owi;
#pragma unroll
      for (int n = 0; n < 4; ++n) {
        int cc = 192 + n * 16 + lr;
        yb[(size_t)po * 256 + (cc ^ (owi << 3))] = f2bf(acc[m][n][r]);
      }
    }
  }
}

// ---------------- 3x3 conv as 256x256x2304 GEMM (double-buffered, counted vmcnt) ----------------
// grid 512 = (b, 16x16 pixel tile); 512 threads = 8 waves (2M x 4N)
__global__ __launch_bounds__(512, 2) void k_conv(
    const unsigned short* __restrict__ Yn, const unsigned short* __restrict__ Wob,
    const float* __restrict__ bo, const unsigned short* __restrict__ zp,
    float* __restrict__ out, float* __restrict__ bnp) {
  __shared__ __align__(16) unsigned short ldsA[2][16384];  // [buf][o][64c]  64KB
  __shared__ __align__(16) unsigned short ldsB[2][16384];  // [buf][n][64c]  64KB

  const int bid = blockIdx.x;
  const int swz = (bid & 7) * 64 + (bid >> 3);   // XCD-chunked, bijective (512=8*64)
  const int b = swz >> 6, tile = swz & 63;
  const int y0 = (tile >> 3) * 16, x0 = (tile & 7) * 16;
  const int tid = threadIdx.x;
  const int wave = tid >> 6, lane = tid & 63;
  const int lr = lane & 15, lk = lane >> 4;
  const int wm = wave >> 2, wn = wave & 3;

  const unsigned short* yb = Yn + (size_t)b * 16384 * 256;

  auto STAGE = [&](int buf, int st) {
    int e = st >> 2;
    int dy = e / 3 - 1, dx = e % 3 - 1;
    int c0 = (st & 3) * 64, g0 = (st & 3) * 8;
#pragma unroll
    for (int i = 0; i < 4; ++i) {
      int task = (wave * 4 + i) * 64 + lane;
      int o = task >> 3, cg = task & 7;
      const unsigned short* sa = Wob + o * 2304 + e * 256 + c0 + ((cg ^ (o & 7)) << 3);
      gload16(sa, &ldsA[buf][(wave * 4 + i) * 512]);
      int py = o >> 4, px = o & 15;            // n == o decomposition for B
      int h = y0 + py + dy, w = x0 + px + dx;
      const unsigned short* sb;
      if (h >= 0 && h < 128 && w >= 0 && w < 128) {
        int pp = h * 128 + w;
        int gl = (cg ^ (o & 7)) ^ (pp & 7);
        sb = yb + (size_t)pp * 256 + ((g0 + gl) << 3);
      } else {
        sb = zp;
      }
      gload16(sb, &ldsB[buf][(wave * 4 + i) * 512]);
    }
  };

  f32x4 acc[8][4];
#pragma unroll
  for (int m = 0; m < 8; ++m)
#pragma unroll
    for (int n = 0; n < 4; ++n)
#pragma unroll
      for (int r = 0; r < 4; ++r) acc[m][n][r] = 0.f;

  int cur = 0;
  STAGE(0, 0);
  for (int t = 0; t < 36; ++t) {
    if (t < 35) {
      STAGE(cur ^ 1, t + 1);
      asm volatile("s_waitcnt vmcnt(8)" ::: "memory");
    } else {
      asm volatile("s_waitcnt vmcnt(0)" ::: "memory");
    }
    __builtin_amdgcn_s_barrier();
    asm volatile("" ::: "memory");
#pragma unroll
    for (int kk = 0; kk < 2; ++kk) {
      int kg = kk * 4 + lk;
      bf8 a[8], bf[4];
#pragma unroll
      for (int m = 0; m < 8; ++m) {
        int row = wm * 128 + m * 16 + lr;
        a[m] = *(const bf8*)(&ldsA[cur][row * 64 + ((kg ^ (row & 7)) << 3)]);
      }
#pragma unroll
      for (int n = 0; n < 4; ++n) {
        int rn = wn * 64 + n * 16 + lr;
        bf[n] = *(const bf8*)(&ldsB[cur][rn * 64 + ((kg ^ (rn & 7)) << 3)]);
      }
#pragma unroll
      for (int m = 0; m < 8; ++m)
#pragma unroll
        for (int n = 0; n < 4; ++n)
          acc[m][n] = __builtin_amdgcn_mfma_f32_16x16x32_bf16(a[m], bf[n], acc[m][n], 0, 0, 0);
    }
    asm volatile("" ::: "memory");
    __builtin_amdgcn_s_barrier();
    cur ^= 1;
  }

  // epilogue: bias + out write (planar f32) + BN partials
  float* ob = out + (size_t)b * 256 * 16384;
  float* red1 = (float*)&ldsA[0][0];     // [8][128]
  float* red2 = red1 + 1024;
#pragma unroll
  for (int m = 0; m < 8; ++m) {
#pragma unroll
    for (int r = 0; r < 4; ++r) {
      int o = wm * 128 + m * 16 + lk * 4 + r;
      float bvv = bo[o];
      float s1 = 0.f, s2 = 0.f;
#pragma unroll
      for (int n = 0; n < 4; ++n) {
        int pix = wn * 64 + n * 16 + lr;
        int py = pix >> 4, px = pix & 15;
        float v = acc[m][n][r] + bvv;
        ob[(size_t)o * 16384 + (y0 + py) * 128 + x0 + px] = v;
        s1 += v;
        s2 += v * v;
      }
      for (int off = 1; off < 16; off <<= 1) {
        s1 += __shfl_xor(s1, off, 64);
        s2 += __shfl_xor(s2, off, 64);
      }
      if (lr == 0) {
        int ol = m * 16 + lk * 4 + r;
        red1[wave * 128 + ol] = s1;
        red2[wave * 128 + ol] = s2;
      }
    }
  }
  __syncthreads();
  {
    int o = tid & 255, stat = tid >> 8;
    int wm2 = o >> 7, ol = o & 127;
    const float* rd = stat ? red2 : red1;
    float s = rd[(wm2 * 4 + 0) * 128 + ol] + rd[(wm2 * 4 + 1) * 128 + ol] +
              rd[(wm2 * 4 + 2) * 128 + ol] + rd[(wm2 * 4 + 3) * 128 + ol];
    bnp[((size_t)(b * 64 + tile) * 256 + o) * 2 + stat] = s;
  }
}

// ---------------- BN reduce + apply ----------------
__global__ __launch_bounds__(256) void k_bnred(
    const float* __restrict__ bnp, const float* __restrict__ gamma,
    const float* __restrict__ beta, float* __restrict__ bns) {
  const int o = blockIdx.x;
  const int tid = threadIdx.x;
  float s1 = 0.f, s2 = 0.f;
  for (int k = tid; k < 512; k += 256) {
    s1 += bnp[((size_t)k * 256 + o) * 2 + 0];
    s2 += bnp[((size_t)k * 256 + o) * 2 + 1];
  }
  __shared__ float r1[256], r2[256];
  r1[tid] = s1; r2[tid] = s2;
  __syncthreads();
  for (int off = 128; off > 0; off >>= 1) {
    if (tid < off) { r1[tid] += r1[tid + off]; r2[tid] += r2[tid + off]; }
    __syncthreads();
  }
  if (tid == 0) {
    const float cnt = 8.0f * 16384.0f;
    float mean = r1[0] / cnt;
    float var = r2[0] / cnt - mean * mean;
    float sc = gamma[o] * rsqrtf(var + 1e-5f);
    bns[o] = sc;
    bns[256 + o] = beta[o] - mean * sc;
  }
}

__global__ void k_bnapply(float* __restrict__ out, const float* __restrict__ bns) {
  size_t i = ((size_t)blockIdx.x * 256 + threadIdx.x) * 4;
  const size_t total = 33554432;
  const size_t stride = (size_t)gridDim.x * 256 * 4;
  for (; i < total; i += stride) {
    float4 v = *(float4*)(out + i);
    int o = (int)((i >> 14) & 255);
    float sc = bns[o], shv = bns[256 + o];
    v.x = v.x * sc + shv; v.x = v.x > 0.f ? v.x : 0.2f * v.x;
    v.y = v.y * sc + shv; v.y = v.y > 0.f ? v.y : 0.2f * v.y;
    v.z = v.z * sc + shv; v.z = v.z > 0.f ? v.z : 0.2f * v.z;
    v.w = v.w * sc + shv; v.w = v.w > 0.f ? v.w : 0.2f * v.w;
    *(float4*)(out + i) = v;
  }
}

// ---------------- launcher ----------------
extern "C" void kernel_launch(void* const* d_in, const int* in_sizes, int n_in,
                              void* d_out, int out_size, void* d_ws, size_t ws_size,
                              hipStream_t stream) {
  if (ws_size < WS_NEED) return;

  const float* x     = (const float*)d_in[0];
  const float* wq    = (const float*)d_in[1];
  const float* bq    = (const float*)d_in[2];
  const float* wk    = (const float*)d_in[3];
  const float* bk    = (const float*)d_in[4];
  const float* wv    = (const float*)d_in[5];
  const float* bv    = (const float*)d_in[6];
  const float* wo    = (const float*)d_in[7];
  const float* bo    = (const float*)d_in[8];
  const float* gamma = (const float*)d_in[9];
  const float* beta  = (const float*)d_in[10];
  float* out = (float*)d_out;
  char* ws = (char*)d_ws;

  unsigned short* Wb  = (unsigned short*)(ws + WB_OFF);
  unsigned short* Wob = (unsigned short*)(ws + WOB_OFF);
  unsigned short* Qn  = (unsigned short*)(ws + QN_OFF);
  unsigned short* Kn  = (unsigned short*)(ws + KN_OFF);
  unsigned short* Vn  = (unsigned short*)(ws + VN_OFF);
  unsigned short* Yn  = (unsigned short*)(ws + YN_OFF);
  float* part3 = (float*)(ws + YN_OFF);          // overlay: used before Yn is written
  float* scores = (float*)(ws + SC_OFF);
  unsigned short* prb = (unsigned short*)(ws + PRB_OFF);
  float* bnp    = (float*)(ws + BNP_OFF);
  float* bns    = (float*)(ws + BNS_OFF);
  unsigned short* zp = (unsigned short*)(ws + ZP_OFF);

  k_prep<<<dim3(3072), dim3(256), 0, stream>>>(wq, wk, wv, wo, Wb, Wob);
  k_zero<<<dim3(137), dim3(256), 0, stream>>>(scores, 34944);
  k_zero<<<dim3(1), dim3(64), 0, stream>>>((float*)zp, 64);
  k_qkv<<<dim3(256, 8), dim3(256), 0, stream>>>(x, Wb, bq, bk, bv, Qn, Kn, Vn);
  k_gram<0><<<dim3(32, 8), dim3(256), 0, stream>>>(Qn, Kn, scores);
  k_gram<1><<<dim3(32, 8), dim3(256), 0, stream>>>(Qn, Kn, scores);
  k_gram<2><<<dim3(32, 8), dim3(256), 0, stream>>>(Qn, Kn, scores);
  k_gram3<<<dim3(8, 4, 8), dim3(256), 0, stream>>>(Qn, Kn, part3);
  k_softmax<<<dim3(3, 8), dim3(256), 0, stream>>>(scores, prb);
  k_softmax3<<<dim3(8, 8), dim3(256), 0, stream>>>(part3, prb);
  k_pv<0><<<dim3(128, 8), dim3(256), 0, stream>>>(Vn, prb, Yn);
  k_pv<1><<<dim3(64, 8), dim3(256), 0, stream>>>(Vn, prb, Yn);
  k_pv<2><<<dim3(64, 8), dim3(256), 0, stream>>>(Vn, prb, Yn);
  k_pv3<<<dim3(64, 8), dim3(256), 0, stream>>>(Vn, prb, Yn);
  k_conv<<<dim3(512), dim3(512), 0, stream>>>(Yn, Wob, bo, zp, out, bnp);
  k_bnred<<<dim3(256), dim3(256), 0, stream>>>(bnp, gamma, beta, bns);
  k_bnapply<<<dim3(4096), dim3(256), 0, stream>>>(out, bns);
}

// Round 5
// 591.700 us; speedup vs baseline: 3.7190x; 1.0366x over previous
//
#include <hip/hip_runtime.h>
#include <stdint.h>

// ---------------- geometry ----------------
// B=8, C=256, H=W=128, HW=16384, 4 heads of d_k=64
// idx: HS=WS=2<<idx, S=HS*HS, OH=OW=64>>idx, NSP=OH*OW
// gather:  q[s=(i,j)][d=(c,ohi,owi)] = Q[lo+c][ohi*HS+i][owi*WS+j], s=i*WS+j
// scatter: Y[lo+c][i*OH+ohi][j*OW+owi] = y[s][d]   (transposed vs gather!)
// NHWC buffers (Qn,Kn,Vn,Yn): element (p, c) at [p*256 + (c ^ ((p&7)<<3))]
// granule rule: 8-ch granule g of pixel p sits at granule slot (g ^ (p&7)).

#define DEVI static __device__ __forceinline__

typedef short bf8 __attribute__((ext_vector_type(8)));   // 8 bf16 (4 VGPRs)
typedef float f32x4 __attribute__((ext_vector_type(4)));

DEVI unsigned short f2bf(float f) {
  unsigned u = __builtin_bit_cast(unsigned, f);
  u = (u + 0x7fffu + ((u >> 16) & 1u)) >> 16;
  return (unsigned short)u;
}
DEVI float bf2f(unsigned short h) {
  unsigned u = ((unsigned)h) << 16;
  return __builtin_bit_cast(float, u);
}

DEVI void gload16(const void* g, void* l) {
  __builtin_amdgcn_global_load_lds(
      (const __attribute__((address_space(1))) unsigned int*)g,
      (__attribute__((address_space(3))) unsigned int*)l, 16, 0, 0);
}

// ---------------- ws layout (bytes) ----------------
static const size_t WB_OFF  = 0;                        // bf16 [3][256][256]
static const size_t WOB_OFF = 393216;                   // bf16 [256][2304] k=(e*256+c)
static const size_t QN_OFF  = 1572864;                  // bf16 NHWC-swz [8][16384][256]
static const size_t KN_OFF  = QN_OFF + 67108864;
static const size_t VN_OFF  = KN_OFF + 67108864;
static const size_t YN_OFF  = VN_OFF + 67108864;        // bf16 NHWC-swz (also part3 overlay)
static const size_t SC_OFF  = YN_OFF + 67108864;        // f32 scores idx0-2 (34944 floats used)
static const size_t PRB_OFF = SC_OFF + 2236928;         // bf16 probs (559232)
static const size_t BNP_OFF = PRB_OFF + 1118464;        // f32 [512][256][2]
static const size_t BNS_OFF = BNP_OFF + 4194304;        // f32 [2][256]
static const size_t ZP_OFF  = BNS_OFF + 2048;           // 256B zero page for OOB gloads
static const size_t WS_NEED = ZP_OFF + 256;

// ---------------- prep: convert weights to bf16 (wo reordered) ----------------
__global__ void k_prep(const float* __restrict__ wq, const float* __restrict__ wk,
                       const float* __restrict__ wv, const float* __restrict__ wo,
                       unsigned short* __restrict__ Wb, unsigned short* __restrict__ Wob) {
  int i = blockIdx.x * 256 + threadIdx.x;        // grid covers 786432 exactly
  if (i < 196608) {
    int z = i >> 16, r = i & 65535;
    const float* w = (z == 0) ? wq : (z == 1) ? wk : wv;
    Wb[i] = f2bf(w[r]);
  } else {
    int j = i - 196608;
    int o = j / 2304, k = j - o * 2304;
    int e = k >> 8, c = k & 255;
    Wob[j] = f2bf(wo[(o * 256 + c) * 9 + e]);    // Wob[o][e*256+c] = wo[o][c][e]
  }
}

__global__ void k_zero(float* __restrict__ p, int n) {
  int i = blockIdx.x * 256 + threadIdx.x;
  for (; i < n; i += gridDim.x * 256) p[i] = 0.f;
}

// ---------------- fused QKV projection, all outputs NHWC-swizzled ----------------
__global__ __launch_bounds__(256) void k_qkv(
    const float* __restrict__ x, const unsigned short* __restrict__ Wb,
    const float* __restrict__ bq, const float* __restrict__ bk, const float* __restrict__ bv,
    unsigned short* __restrict__ Qn, unsigned short* __restrict__ Kn,
    unsigned short* __restrict__ Vn) {
  const int pt = blockIdx.x, b = blockIdx.y;
  const int p0 = pt * 64;
  const int tid = threadIdx.x;

  __shared__ __align__(16) unsigned short xt[64 * 256];  // input tile [p][c'] swizzled
  __shared__ __align__(16) unsigned short ot[64 * 256];  // output transpose buffer

  const float* xb = x + (size_t)b * 256 * 16384;
  for (int k = 0; k < 16; ++k) {
    int i = tid + k * 256;
    int c = i >> 4, p4 = (i & 15) * 4;
    float4 v = *(const float4*)(xb + (size_t)c * 16384 + p0 + p4);
    xt[(p4 + 0) * 256 + (c ^ (((p4 + 0) & 7) << 3))] = f2bf(v.x);
    xt[(p4 + 1) * 256 + (c ^ (((p4 + 1) & 7) << 3))] = f2bf(v.y);
    xt[(p4 + 2) * 256 + (c ^ (((p4 + 2) & 7) << 3))] = f2bf(v.z);
    xt[(p4 + 3) * 256 + (c ^ (((p4 + 3) & 7) << 3))] = f2bf(v.w);
  }
  __syncthreads();

  const int wave = tid >> 6, lane = tid & 63;
  const int lr = lane & 15, lk = lane >> 4;
  const int obase = wave * 64;

  for (int z = 0; z < 3; ++z) {
    const unsigned short* Wz = Wb + (size_t)z * 65536;
    f32x4 acc[4][4];
    for (int m = 0; m < 4; ++m)
      for (int n = 0; n < 4; ++n)
        for (int r = 0; r < 4; ++r) acc[m][n][r] = 0.f;

    for (int ks = 0; ks < 8; ++ks) {
      int c0 = ks * 32 + lk * 8;
      bf8 a[4], bb[4];
#pragma unroll
      for (int m = 0; m < 4; ++m)
        a[m] = *(const bf8*)(Wz + (size_t)(obase + m * 16 + lr) * 256 + c0);
#pragma unroll
      for (int n = 0; n < 4; ++n) {
        int p = n * 16 + lr;
        bb[n] = *(const bf8*)(&xt[p * 256 + (c0 ^ ((p & 7) << 3))]);
      }
#pragma unroll
      for (int m = 0; m < 4; ++m)
#pragma unroll
        for (int n = 0; n < 4; ++n)
          acc[m][n] = __builtin_amdgcn_mfma_f32_16x16x32_bf16(a[m], bb[n], acc[m][n], 0, 0, 0);
    }

    const float* bias = (z == 0) ? bq : (z == 1) ? bk : bv;
    unsigned short* On = (z == 0) ? Qn : (z == 1) ? Kn : Vn;
    __syncthreads();   // prior ot consumers done
#pragma unroll
    for (int m = 0; m < 4; ++m) {
      int ob4 = obase + m * 16 + lk * 4;
      float4 b4 = *(const float4*)(bias + ob4);
#pragma unroll
      for (int n = 0; n < 4; ++n) {
        int p = n * 16 + lr;
        ushort4 v4;
        v4.x = f2bf(acc[m][n][0] + b4.x);
        v4.y = f2bf(acc[m][n][1] + b4.y);
        v4.z = f2bf(acc[m][n][2] + b4.z);
        v4.w = f2bf(acc[m][n][3] + b4.w);
        *(ushort4*)(&ot[p * 256 + (ob4 ^ ((p & 7) << 3))]) = v4;
      }
    }
    __syncthreads();
    unsigned short* gb = On + ((size_t)b * 16384 + p0) * 256;
#pragma unroll
    for (int i = 0; i < 8; ++i) {
      int ch = tid + i * 256;
      *(uint4*)(gb + ch * 8) = *(const uint4*)(&ot[ch * 8]);
    }
  }
}

// ---------------- Gram via MFMA, idx 0..2 ----------------
template <int IDX>
__global__ __launch_bounds__(256) void k_gram(
    const unsigned short* __restrict__ Qn, const unsigned short* __restrict__ Kn,
    float* __restrict__ scores) {
  constexpr int HS = 2 << IDX, S = HS * HS, OH = 64 >> IDX, NSP = OH * OH;
  constexpr int SPW = (IDX == 2) ? 2 : 8;
  constexpr int DSUB = SPW * 64;
  constexpr int SPB = NSP / 32;
  constexpr int STEPS = SPB / SPW;
  constexpr int ROWS = S;
  constexpr int TPT = S * SPW * 8 / 256;
  constexpr int SCOFF = (IDX == 0) ? 0 : (IDX == 1) ? 128 : 2176;
  constexpr int HC = IDX * 64;
  constexpr int MT = (IDX == 2) ? 4 : 1;

  const int chk = blockIdx.x, b = blockIdx.y;
  const int tid = threadIdx.x;
  const int wave = tid >> 6, lane = tid & 63, lr = lane & 15, lk = lane >> 4;

  __shared__ __align__(16) unsigned short qg[ROWS * DSUB];
  __shared__ __align__(16) unsigned short kg[ROWS * DSUB];
  __shared__ float red[S * S];

  const size_t base = (size_t)b * 16384 * 256;

  f32x4 acc[MT][MT];
  for (int m = 0; m < MT; ++m)
    for (int n = 0; n < MT; ++n)
      for (int r = 0; r < 4; ++r) acc[m][n][r] = 0.f;

  for (int st = 0; st < STEPS; ++st) {
    const int sp0 = chk * SPB + st * SPW;
    __syncthreads();
#pragma unroll
    for (int r = 0; r < TPT; ++r) {
      int task = tid + r * 256;
      int cg = task & 7, pl = task >> 3;
      int spl = pl >> (2 * (IDX + 1)), s = pl & (S - 1);
      int sp = sp0 + spl;
      int ohi = sp >> (6 - IDX), owi = sp & (OH - 1);
      int ii = s >> (IDX + 1), jj = s & (HS - 1);
      int p = (ohi * HS + ii) * 128 + owi * HS + jj;
      size_t gaddr = base + (size_t)p * 256 + HC + ((cg ^ (p & 7)) << 3);
      int laddr = s * DSUB + (((spl * 8 + cg) ^ (s & 7)) << 3);
      *(uint4*)(qg + laddr) = *(const uint4*)(Qn + gaddr);
      *(uint4*)(kg + laddr) = *(const uint4*)(Kn + gaddr);
    }
    __syncthreads();
    if (IDX == 2) {
      int kgid = wave * 4 + lk;
      bf8 a[4], bb[4];
#pragma unroll
      for (int m = 0; m < 4; ++m) {
        int row = m * 16 + lr;
        int off = row * DSUB + ((kgid ^ (row & 7)) << 3);
        a[m] = *(const bf8*)(qg + off);
        bb[m] = *(const bf8*)(kg + off);
      }
#pragma unroll
      for (int m = 0; m < 4; ++m)
#pragma unroll
        for (int n = 0; n < 4; ++n)
          acc[m][n] = __builtin_amdgcn_mfma_f32_16x16x32_bf16(a[m], bb[n], acc[m][n], 0, 0, 0);
    } else {
      int row = lr & (ROWS - 1);
#pragma unroll
      for (int kk = 0; kk < 4; ++kk) {
        int kgid = (wave * 4 + kk) * 4 + lk;
        int off = row * DSUB + ((kgid ^ (row & 7)) << 3);
        bf8 a = *(const bf8*)(qg + off);
        bf8 bb = *(const bf8*)(kg + off);
        acc[0][0] = __builtin_amdgcn_mfma_f32_16x16x32_bf16(a, bb, acc[0][0], 0, 0, 0);
      }
    }
  }

  __syncthreads();
  for (int i2 = tid; i2 < S * S; i2 += 256) red[i2] = 0.f;
  __syncthreads();
  if (IDX == 2) {
#pragma unroll
    for (int m = 0; m < 4; ++m)
#pragma unroll
      for (int n = 0; n < 4; ++n)
#pragma unroll
        for (int r = 0; r < 4; ++r)
          atomicAdd(&red[(m * 16 + lk * 4 + r) * 64 + n * 16 + lr], acc[m][n][r]);
  } else if (IDX == 1) {
#pragma unroll
    for (int r = 0; r < 4; ++r)
      atomicAdd(&red[(lk * 4 + r) * 16 + lr], acc[0][0][r]);
  } else {
    if (lk == 0 && lr < 4) {
#pragma unroll
      for (int r = 0; r < 4; ++r)
        atomicAdd(&red[r * 4 + lr], acc[0][0][r]);
    }
  }
  __syncthreads();
  float* sc = scores + SCOFF + (size_t)b * S * S;
  for (int i2 = tid; i2 < S * S; i2 += 256) atomicAdd(sc + i2, red[i2]);
}

// ---------------- Gram idx3: 256x256x4096 GEMM, partials ----------------
__global__ __launch_bounds__(256) void k_gram3(
    const unsigned short* __restrict__ Qn, const unsigned short* __restrict__ Kn,
    float* __restrict__ part3) {
  const int qc = blockIdx.x, tq = blockIdx.y, b = blockIdx.z;
  const int tid = threadIdx.x;
  const int wave = tid >> 6, lane = tid & 63, lr = lane & 15, lk = lane >> 4;

  __shared__ __align__(16) unsigned short qg[256 * 64];
  __shared__ __align__(16) unsigned short kg[64 * 64];

  const size_t base = (size_t)b * 16384 * 256;

  f32x4 acc[4][4];
  for (int m = 0; m < 4; ++m)
    for (int n = 0; n < 4; ++n)
      for (int r = 0; r < 4; ++r) acc[m][n][r] = 0.f;

  for (int st = 0; st < 8; ++st) {
    int sp = qc * 8 + st;
    int ohi = sp >> 3, owi = sp & 7;
    __syncthreads();
#pragma unroll
    for (int r = 0; r < 8; ++r) {
      int task = tid + r * 256;
      int cg = task & 7, s = task >> 3;
      int p = (ohi * 16 + (s >> 4)) * 128 + owi * 16 + (s & 15);
      uint4 v = *(const uint4*)(Qn + base + (size_t)p * 256 + 192 + ((cg ^ (p & 7)) << 3));
      *(uint4*)(qg + s * 64 + ((cg ^ (s & 7)) << 3)) = v;
    }
#pragma unroll
    for (int r = 0; r < 2; ++r) {
      int task = tid + r * 256;
      int cg = task & 7, tl = task >> 3;
      int p = (ohi * 16 + tq * 4 + (tl >> 4)) * 128 + owi * 16 + (tl & 15);
      uint4 v = *(const uint4*)(Kn + base + (size_t)p * 256 + 192 + ((cg ^ (p & 7)) << 3));
      *(uint4*)(kg + tl * 64 + ((cg ^ (tl & 7)) << 3)) = v;
    }
    __syncthreads();
#pragma unroll
    for (int kk = 0; kk < 2; ++kk) {
      int kgid = kk * 4 + lk;
      bf8 a[4], bb[4];
#pragma unroll
      for (int m = 0; m < 4; ++m) {
        int row = wave * 64 + m * 16 + lr;
        a[m] = *(const bf8*)(qg + row * 64 + ((kgid ^ (row & 7)) << 3));
      }
#pragma unroll
      for (int n = 0; n < 4; ++n) {
        int rowb = n * 16 + lr;
        bb[n] = *(const bf8*)(kg + rowb * 64 + ((kgid ^ (rowb & 7)) << 3));
      }
#pragma unroll
      for (int m = 0; m < 4; ++m)
#pragma unroll
        for (int n = 0; n < 4; ++n)
          acc[m][n] = __builtin_amdgcn_mfma_f32_16x16x32_bf16(a[m], bb[n], acc[m][n], 0, 0, 0);
    }
  }

  float* pb = part3 + (((size_t)qc * 8 + b) * 65536);
#pragma unroll
  for (int m = 0; m < 4; ++m)
#pragma unroll
    for (int r = 0; r < 4; ++r) {
      int srow = wave * 64 + m * 16 + lk * 4 + r;
#pragma unroll
      for (int n = 0; n < 4; ++n)
        pb[srow * 256 + tq * 64 + n * 16 + lr] = acc[m][n][r];
    }
}

// ---------------- softmax idx0-2 (fp32 scores -> bf16 probs) ----------------
__global__ __launch_bounds__(256) void k_softmax(const float* __restrict__ scores,
                                                 unsigned short* __restrict__ prb) {
  const int idx = blockIdx.x, b = blockIdx.y;
  const int S = 4 << (2 * idx);
  const int off = (idx == 0 ? 0 : idx == 1 ? 128 : 2176) + b * S * S;
  const int s = threadIdx.x;
  if (s >= S) return;
  const float scale = rsqrtf(64.0f * (float)(4096 >> (2 * idx)));
  const float* row = scores + off + s * S;
  float m = -1e30f;
  for (int t = 0; t < S; ++t) m = fmaxf(m, row[t]);
  m *= scale;
  float sum = 0.f;
  for (int t = 0; t < S; ++t) sum += __expf(row[t] * scale - m);
  float inv = 1.0f / sum;
  unsigned short* prow = prb + off + s * S;
  for (int t = 0; t < S; ++t) prow[t] = f2bf(__expf(row[t] * scale - m) * inv);
}

// ---------------- softmax idx3: sum 8 partials + softmax ----------------
__global__ __launch_bounds__(256) void k_softmax3(const float* __restrict__ part3,
                                                  unsigned short* __restrict__ prb) {
  const int sc_ = blockIdx.x, b = blockIdx.y;
  const int tid = threadIdx.x;
  const int s = sc_ * 32 + (tid >> 3);
  const int t0 = (tid & 7) * 32;
  float v[32];
#pragma unroll
  for (int k = 0; k < 32; ++k) v[k] = 0.f;
  for (int q = 0; q < 8; ++q) {
    const float4* pp = (const float4*)(part3 + (((size_t)q * 8 + b) * 256 + s) * 256 + t0);
#pragma unroll
    for (int k = 0; k < 8; ++k) {
      float4 u = pp[k];
      v[k * 4 + 0] += u.x; v[k * 4 + 1] += u.y; v[k * 4 + 2] += u.z; v[k * 4 + 3] += u.w;
    }
  }
  const float scale = 1.0f / 64.0f;
  float m = -1e30f;
#pragma unroll
  for (int k = 0; k < 32; ++k) { v[k] *= scale; m = fmaxf(m, v[k]); }
  m = fmaxf(m, __shfl_xor(m, 1));
  m = fmaxf(m, __shfl_xor(m, 2));
  m = fmaxf(m, __shfl_xor(m, 4));
  float sum = 0.f;
#pragma unroll
  for (int k = 0; k < 32; ++k) { v[k] = __expf(v[k] - m); sum += v[k]; }
  sum += __shfl_xor(sum, 1);
  sum += __shfl_xor(sum, 2);
  sum += __shfl_xor(sum, 4);
  float inv = 1.0f / sum;
  unsigned short* prw = prb + 34944 + (size_t)b * 65536 + s * 256 + t0;
#pragma unroll
  for (int k8 = 0; k8 < 4; ++k8) {
    unsigned short tmp[8];
#pragma unroll
    for (int e = 0; e < 8; ++e) tmp[e] = f2bf(v[k8 * 8 + e] * inv);
    *(uint4*)(prw + k8 * 8) = *(const uint4*)tmp;
  }
}

// ---------------- PV small S (idx 0,1,2): per-head, NHWC in/out ----------------
template <int IDX>
__global__ __launch_bounds__(256) void k_pv(
    const unsigned short* __restrict__ Vn, const unsigned short* __restrict__ prb,
    unsigned short* __restrict__ Yn) {
  constexpr int HS = 2 << IDX, S = HS * HS, OH = 64 >> IDX;
  constexpr int IT = (IDX == 0) ? 8 : (IDX == 1) ? 4 : 1;
  constexpr int POFF = (IDX == 0) ? 0 : (IDX == 1) ? 128 : 2176;
  const int bx = blockIdx.x, b = blockIdx.y;
  const int c = threadIdx.x & 63, spg = threadIdx.x >> 6;
  __shared__ __align__(16) float pl[S * S];
  const unsigned short* pr = prb + POFF + (size_t)b * S * S;
  for (int i = threadIdx.x; i < S * S; i += 256) pl[i] = bf2f(pr[i]);
  __syncthreads();
  const int hc = IDX * 64;
  const unsigned short* vb = Vn + (size_t)b * 16384 * 256;
  unsigned short* yb = Yn + (size_t)b * 16384 * 256;
  for (int it = 0; it < IT; ++it) {
    int sp = bx * (4 * IT) + it * 4 + spg;
    int ohi = sp >> (6 - IDX), owi = sp & (OH - 1);
    float v[S];
#pragma unroll
    for (int t = 0; t < S; ++t) {
      int po = (ohi * HS + t / HS) * 128 + owi * HS + (t % HS);
      v[t] = bf2f(vb[(size_t)po * 256 + ((hc + c) ^ ((po & 7) << 3))]);
    }
    for (int s = 0; s < S; ++s) {
      const float4* p4 = (const float4*)(pl + s * S);
      float a = 0.f;
#pragma unroll
      for (int t4 = 0; t4 < S / 4; ++t4) {
        float4 pp = p4[t4];
        a += pp.x * v[t4 * 4] + pp.y * v[t4 * 4 + 1] + pp.z * v[t4 * 4 + 2] + pp.w * v[t4 * 4 + 3];
      }
      int po = ((s >> (IDX + 1)) * OH + ohi) * 128 + (s & (HS - 1)) * OH + owi;
      yb[(size_t)po * 256 + ((hc + c) ^ ((po & 7) << 3))] = f2bf(a);
    }
  }
}

// ---------------- PV idx3 (S=256): MFMA GEMM per (b, sp) ----------------
__global__ __launch_bounds__(256) void k_pv3(
    const unsigned short* __restrict__ Vn, const unsigned short* __restrict__ prb,
    unsigned short* __restrict__ Yn) {
  const int sp = blockIdx.x, b = blockIdx.y;
  const int ohi = sp >> 3, owi = sp & 7;
  const int tid = threadIdx.x;
  __shared__ __align__(16) unsigned short vl[64 * 256];
  const unsigned short* vb = Vn + (size_t)b * 16384 * 256;
  {
    int t = tid;
    int po = (ohi * 16 + (t >> 4)) * 128 + owi * 16 + (t & 15);
    const unsigned short* src = vb + (size_t)po * 256;
    int xv = (po & 7) << 3;
#pragma unroll
    for (int g = 0; g < 8; ++g) {
      ushort4 lo = *(const ushort4*)(src + ((192 + g * 8) ^ xv));
      ushort4 hi = *(const ushort4*)(src + ((192 + g * 8) ^ xv) + 4);
      unsigned short vv[8] = {lo.x, lo.y, lo.z, lo.w, hi.x, hi.y, hi.z, hi.w};
#pragma unroll
      for (int e = 0; e < 8; ++e) {
        int cc = g * 8 + e;
        vl[cc * 256 + (t ^ ((cc & 7) << 3))] = vv[e];
      }
    }
  }
  __syncthreads();

  const int wave = tid >> 6, lane = tid & 63;
  const int lr = lane & 15, lk = lane >> 4;
  const int sb = wave * 64;
  const unsigned short* pr = prb + 34944 + (size_t)b * 65536;

  f32x4 acc[4][4];
  for (int m = 0; m < 4; ++m)
    for (int n = 0; n < 4; ++n)
      for (int r = 0; r < 4; ++r) acc[m][n][r] = 0.f;

  for (int kk = 0; kk < 8; ++kk) {
    int t0 = kk * 32 + lk * 8;
    bf8 a[4], bb[4];
#pragma unroll
    for (int m = 0; m < 4; ++m)
      a[m] = *(const bf8*)(pr + (size_t)(sb + m * 16 + lr) * 256 + t0);
#pragma unroll
    for (int n = 0; n < 4; ++n) {
      int cc = n * 16 + lr;
      bb[n] = *(const bf8*)(&vl[cc * 256 + (t0 ^ ((cc & 7) << 3))]);
    }
#pragma unroll
    for (int m = 0; m < 4; ++m)
#pragma unroll
      for (int n = 0; n < 4; ++n)
        acc[m][n] = __builtin_amdgcn_mfma_f32_16x16x32_bf16(a[m], bb[n], acc[m][n], 0, 0, 0);
  }

  unsigned short* yb = Yn + (size_t)b * 16384 * 256;
#pragma unroll
  for (int m = 0; m < 4; ++m) {
#pragma unroll
    for (int r = 0; r < 4; ++r) {
      int s = sb + m * 16 + lk * 4 + r;
      int si = s >> 4, sj = s & 15;
      int po = (si * 8 + ohi) * 128 + sj * 8 + owi;
#pragma unroll
      for (int n = 0; n < 4; ++n) {
        int cc = 192 + n * 16 + lr;
        yb[(size_t)po * 256 + (cc ^ (owi << 3))] = f2bf(acc[m][n][r]);
      }
    }
  }
}

// ---------------- 3x3 conv: 256x256x2304 GEMM, 8-phase half-tile ring ----------------
// grid 512 = (b, 16x16 px tile); 512 threads = 8 waves (2M x 4N), per-wave C 128x64.
// Half-tile = 16KB (A-quarterpair or B-quarterpair of one K-tile). Ring of 8 slots.
// Phase P (4/K-tile, mh-major quadrants): stage H(P+5), vmcnt(6), barrier,
// ds_read quadrant frags, 16 MFMA (setprio), barrier.  Race-free (d=5 proof in notes).
__global__ __launch_bounds__(512, 2) void k_conv(
    const unsigned short* __restrict__ Yn, const unsigned short* __restrict__ Wob,
    const float* __restrict__ bo, const unsigned short* __restrict__ zp,
    float* __restrict__ out, float* __restrict__ bnp) {
  __shared__ __align__(16) unsigned short lds[8][8192];  // 8 x 16KB half-tile slots

  const int bid = blockIdx.x;
  const int swz = (bid & 7) * 64 + (bid >> 3);   // XCD-chunked, bijective (512=8*64)
  const int b = swz >> 6, tile = swz & 63;
  const int y0 = (tile >> 3) * 16, x0 = (tile & 7) * 16;
  const int tid = threadIdx.x;
  const int wave = tid >> 6, lane = tid & 63;
  const int lr = lane & 15, lk = lane >> 4;
  const int wm = wave >> 2, wn = wave & 3;
  const int cg = lane & 7;

  const unsigned short* yb = Yn + (size_t)b * 16384 * 256;

  // stage one half-tile (type w: 0/1 = A half mh, 2/3 = B half nh) of K-tile KT -> slot
  auto STAGE = [&](int slot, int w, int KT) {
    if (w < 2) {
      const unsigned short* wsrc = Wob + (KT >> 2) * 256 + (KT & 3) * 64;
#pragma unroll
      for (int j = 0; j < 2; ++j) {
        int rp = (wave * 2 + j) * 8 + (lane >> 3);   // LDS row 0..127
        int o = ((rp >> 6) & 1) * 128 + w * 64 + (rp & 63);
        int kg = cg ^ (rp & 7);
        gload16(wsrc + o * 2304 + (kg << 3), &lds[slot][(wave * 2 + j) * 512]);
      }
    } else {
      int e = KT >> 2;
      int dy = e / 3 - 1, dx = e % 3 - 1, c8 = (KT & 3) * 8;
#pragma unroll
      for (int j = 0; j < 2; ++j) {
        int rp = (wave * 2 + j) * 8 + (lane >> 3);
        int n = ((rp >> 5) & 3) * 64 + (w - 2) * 32 + (rp & 31);
        int kg = cg ^ (rp & 7);
        int h = y0 + (n >> 4) + dy, ww = x0 + (n & 15) + dx;
        const unsigned short* src = zp;
        if (h >= 0 && h < 128 && ww >= 0 && ww < 128) {
          int pp = h * 128 + ww;
          src = yb + (size_t)pp * 256 + ((c8 + (kg ^ (pp & 7))) << 3);
        }
        gload16(src, &lds[slot][(wave * 2 + j) * 512]);
      }
    }
  };

  f32x4 acc[8][4];
#pragma unroll
  for (int m = 0; m < 8; ++m)
#pragma unroll
    for (int n = 0; n < 4; ++n)
#pragma unroll
      for (int r = 0; r < 4; ++r) acc[m][n][r] = 0.f;

  // prologue: H0..H4
  STAGE(0, 0, 0); STAGE(1, 1, 0); STAGE(2, 2, 0); STAGE(3, 3, 0); STAGE(4, 0, 1);

  for (int gg = 0; gg < 18; ++gg) {
#pragma unroll
    for (int sub = 0; sub < 8; ++sub) {
      const int g = sub >> 2;            // K-tile parity (buffer group)
      const int r = sub & 3;
      const int P = gg * 8 + sub;
      if (P <= 138) {
        STAGE((sub + 5) & 7, (sub + 5) & 3, gg * 2 + ((sub + 5) >> 2));
        asm volatile("s_waitcnt vmcnt(6)" ::: "memory");
      } else if (P == 140) {
        asm volatile("s_waitcnt vmcnt(0)" ::: "memory");
      }
      __builtin_amdgcn_s_barrier();
      asm volatile("" ::: "memory");
      const int mh = r >> 1, nh = r & 1;
      const int sA = g * 4 + mh, sB = g * 4 + 2 + nh;
      bf8 a[4][2], bq2[2][2];
#pragma unroll
      for (int m2 = 0; m2 < 4; ++m2) {
        int row = wm * 64 + m2 * 16 + lr;
#pragma unroll
        for (int kk = 0; kk < 2; ++kk)
          a[m2][kk] = *(const bf8*)(&lds[sA][row * 64 + (((kk * 4 + lk) ^ (row & 7)) << 3)]);
      }
#pragma unroll
      for (int n2 = 0; n2 < 2; ++n2) {
        int row = wn * 32 + n2 * 16 + lr;
#pragma unroll
        for (int kk = 0; kk < 2; ++kk)
          bq2[n2][kk] = *(const bf8*)(&lds[sB][row * 64 + (((kk * 4 + lk) ^ (row & 7)) << 3)]);
      }
      __builtin_amdgcn_s_setprio(1);
#pragma unroll
      for (int kk = 0; kk < 2; ++kk)
#pragma unroll
        for (int m2 = 0; m2 < 4; ++m2)
#pragma unroll
          for (int n2 = 0; n2 < 2; ++n2)
            acc[mh * 4 + m2][nh * 2 + n2] = __builtin_amdgcn_mfma_f32_16x16x32_bf16(
                a[m2][kk], bq2[n2][kk], acc[mh * 4 + m2][nh * 2 + n2], 0, 0, 0);
      __builtin_amdgcn_s_setprio(0);
      asm volatile("" ::: "memory");
      __builtin_amdgcn_s_barrier();
    }
  }

  __syncthreads();
  // epilogue: bias + out write (planar f32) + BN partials
  float* ob = out + (size_t)b * 256 * 16384;
  float* red1 = (float*)&lds[0][0];     // [8][128]
  float* red2 = red1 + 1024;
#pragma unroll
  for (int m = 0; m < 8; ++m) {
#pragma unroll
    for (int r = 0; r < 4; ++r) {
      int o = wm * 128 + m * 16 + lk * 4 + r;
      float bvv = bo[o];
      float s1 = 0.f, s2 = 0.f;
#pragma unroll
      for (int n = 0; n < 4; ++n) {
        int pix = wn * 64 + n * 16 + lr;
        int py = pix >> 4, px = pix & 15;
        float v = acc[m][n][r] + bvv;
        ob[(size_t)o * 16384 + (y0 + py) * 128 + x0 + px] = v;
        s1 += v;
        s2 += v * v;
      }
      for (int off = 1; off < 16; off <<= 1) {
        s1 += __shfl_xor(s1, off, 64);
        s2 += __shfl_xor(s2, off, 64);
      }
      if (lr == 0) {
        int ol = m * 16 + lk * 4 + r;
        red1[wave * 128 + ol] = s1;
        red2[wave * 128 + ol] = s2;
      }
    }
  }
  __syncthreads();
  {
    int o = tid & 255, stat = tid >> 8;
    int wm2 = o >> 7, ol = o & 127;
    const float* rd = stat ? red2 : red1;
    float s = rd[(wm2 * 4 + 0) * 128 + ol] + rd[(wm2 * 4 + 1) * 128 + ol] +
              rd[(wm2 * 4 + 2) * 128 + ol] + rd[(wm2 * 4 + 3) * 128 + ol];
    bnp[((size_t)(b * 64 + tile) * 256 + o) * 2 + stat] = s;
  }
}

// ---------------- BN reduce + apply ----------------
__global__ __launch_bounds__(256) void k_bnred(
    const float* __restrict__ bnp, const float* __restrict__ gamma,
    const float* __restrict__ beta, float* __restrict__ bns) {
  const int o = blockIdx.x;
  const int tid = threadIdx.x;
  float s1 = 0.f, s2 = 0.f;
  for (int k = tid; k < 512; k += 256) {
    s1 += bnp[((size_t)k * 256 + o) * 2 + 0];
    s2 += bnp[((size_t)k * 256 + o) * 2 + 1];
  }
  __shared__ float r1[256], r2[256];
  r1[tid] = s1; r2[tid] = s2;
  __syncthreads();
  for (int off = 128; off > 0; off >>= 1) {
    if (tid < off) { r1[tid] += r1[tid + off]; r2[tid] += r2[tid + off]; }
    __syncthreads();
  }
  if (tid == 0) {
    const float cnt = 8.0f * 16384.0f;
    float mean = r1[0] / cnt;
    float var = r2[0] / cnt - mean * mean;
    float sc = gamma[o] * rsqrtf(var + 1e-5f);
    bns[o] = sc;
    bns[256 + o] = beta[o] - mean * sc;
  }
}

__global__ void k_bnapply(float* __restrict__ out, const float* __restrict__ bns) {
  size_t i = ((size_t)blockIdx.x * 256 + threadIdx.x) * 4;
  const size_t total = 33554432;
  const size_t stride = (size_t)gridDim.x * 256 * 4;
  for (; i < total; i += stride) {
    float4 v = *(float4*)(out + i);
    int o = (int)((i >> 14) & 255);
    float sc = bns[o], shv = bns[256 + o];
    v.x = v.x * sc + shv; v.x = v.x > 0.f ? v.x : 0.2f * v.x;
    v.y = v.y * sc + shv; v.y = v.y > 0.f ? v.y : 0.2f * v.y;
    v.z = v.z * sc + shv; v.z = v.z > 0.f ? v.z : 0.2f * v.z;
    v.w = v.w * sc + shv; v.w = v.w > 0.f ? v.w : 0.2f * v.w;
    *(float4*)(out + i) = v;
  }
}

// ---------------- launcher ----------------
extern "C" void kernel_launch(void* const* d_in, const int* in_sizes, int n_in,
                              void* d_out, int out_size, void* d_ws, size_t ws_size,
                              hipStream_t stream) {
  if (ws_size < WS_NEED) return;

  const float* x     = (const float*)d_in[0];
  const float* wq    = (const float*)d_in[1];
  const float* bq    = (const float*)d_in[2];
  const float* wk    = (const float*)d_in[3];
  const float* bk    = (const float*)d_in[4];
  const float* wv    = (const float*)d_in[5];
  const float* bv    = (const float*)d_in[6];
  const float* wo    = (const float*)d_in[7];
  const float* bo    = (const float*)d_in[8];
  const float* gamma = (const float*)d_in[9];
  const float* beta  = (const float*)d_in[10];
  float* out = (float*)d_out;
  char* ws = (char*)d_ws;

  unsigned short* Wb  = (unsigned short*)(ws + WB_OFF);
  unsigned short* Wob = (unsigned short*)(ws + WOB_OFF);
  unsigned short* Qn  = (unsigned short*)(ws + QN_OFF);
  unsigned short* Kn  = (unsigned short*)(ws + KN_OFF);
  unsigned short* Vn  = (unsigned short*)(ws + VN_OFF);
  unsigned short* Yn  = (unsigned short*)(ws + YN_OFF);
  float* part3 = (float*)(ws + YN_OFF);          // overlay: used before Yn is written
  float* scores = (float*)(ws + SC_OFF);
  unsigned short* prb = (unsigned short*)(ws + PRB_OFF);
  float* bnp    = (float*)(ws + BNP_OFF);
  float* bns    = (float*)(ws + BNS_OFF);
  unsigned short* zp = (unsigned short*)(ws + ZP_OFF);

  k_prep<<<dim3(3072), dim3(256), 0, stream>>>(wq, wk, wv, wo, Wb, Wob);
  k_zero<<<dim3(137), dim3(256), 0, stream>>>(scores, 34944);
  k_zero<<<dim3(1), dim3(64), 0, stream>>>((float*)zp, 64);
  k_qkv<<<dim3(256, 8), dim3(256), 0, stream>>>(x, Wb, bq, bk, bv, Qn, Kn, Vn);
  k_gram<0><<<dim3(32, 8), dim3(256), 0, stream>>>(Qn, Kn, scores);
  k_gram<1><<<dim3(32, 8), dim3(256), 0, stream>>>(Qn, Kn, scores);
  k_gram<2><<<dim3(32, 8), dim3(256), 0, stream>>>(Qn, Kn, scores);
  k_gram3<<<dim3(8, 4, 8), dim3(256), 0, stream>>>(Qn, Kn, part3);
  k_softmax<<<dim3(3, 8), dim3(256), 0, stream>>>(scores, prb);
  k_softmax3<<<dim3(8, 8), dim3(256), 0, stream>>>(part3, prb);
  k_pv<0><<<dim3(128, 8), dim3(256), 0, stream>>>(Vn, prb, Yn);
  k_pv<1><<<dim3(64, 8), dim3(256), 0, stream>>>(Vn, prb, Yn);
  k_pv<2><<<dim3(64, 8), dim3(256), 0, stream>>>(Vn, prb, Yn);
  k_pv3<<<dim3(64, 8), dim3(256), 0, stream>>>(Vn, prb, Yn);
  k_conv<<<dim3(512), dim3(512), 0, stream>>>(Yn, Wob, bo, zp, out, bnp);
  k_bnred<<<dim3(256), dim3(256), 0, stream>>>(bnp, gamma, beta, bns);
  k_bnapply<<<dim3(4096), dim3(256), 0, stream>>>(out, bns);
}

// Round 6
// 571.100 us; speedup vs baseline: 3.8531x; 1.0361x over previous
//
#include <hip/hip_runtime.h>
#include <stdint.h>

// ---------------- geometry ----------------
// B=8, C=256, H=W=128, HW=16384, 4 heads of d_k=64
// idx: HS=WS=2<<idx, S=HS*HS, OH=OW=64>>idx, NSP=OH*OW
// gather:  q[s=(i,j)][d=(c,ohi,owi)] = Q[lo+c][ohi*HS+i][owi*WS+j], s=i*WS+j
// scatter: Y[lo+c][i*OH+ohi][j*OW+owi] = y[s][d]   (transposed vs gather!)
// NHWC buffers (Qn,Kn,Vn,Yn): element (p, c) at [p*256 + (c ^ ((p&7)<<3))]
// granule rule: 8-ch granule g of pixel p sits at granule slot (g ^ (p&7)).

#define DEVI static __device__ __forceinline__

typedef short bf8 __attribute__((ext_vector_type(8)));   // 8 bf16 (4 VGPRs)
typedef float f32x4 __attribute__((ext_vector_type(4)));

DEVI unsigned short f2bf(float f) {
  unsigned u = __builtin_bit_cast(unsigned, f);
  u = (u + 0x7fffu + ((u >> 16) & 1u)) >> 16;
  return (unsigned short)u;
}
DEVI float bf2f(unsigned short h) {
  unsigned u = ((unsigned)h) << 16;
  return __builtin_bit_cast(float, u);
}

DEVI void gload16(const void* g, void* l) {
  __builtin_amdgcn_global_load_lds(
      (const __attribute__((address_space(1))) unsigned int*)g,
      (__attribute__((address_space(3))) unsigned int*)l, 16, 0, 0);
}

// ---------------- ws layout (bytes) ----------------
static const size_t WB_OFF  = 0;                        // bf16 [3][256][256]
static const size_t WOB_OFF = 393216;                   // bf16 [256][2304] k=(e*256+c)
static const size_t QN_OFF  = 1572864;                  // bf16 NHWC-swz [8][16384][256]; co overlay after grams
static const size_t KN_OFF  = QN_OFF + 67108864;
static const size_t VN_OFF  = KN_OFF + 67108864;
static const size_t YN_OFF  = VN_OFF + 67108864;        // bf16 NHWC-swz (also part3 overlay)
static const size_t SC_OFF  = YN_OFF + 67108864;        // f32 scores idx0-2 (34944 floats used)
static const size_t PRB_OFF = SC_OFF + 2236928;         // bf16 probs (559232)
static const size_t BNP_OFF = PRB_OFF + 1118464;        // f32 [512][256][2]
static const size_t BNS_OFF = BNP_OFF + 4194304;        // f32 [2][256]
static const size_t ZP_OFF  = BNS_OFF + 2048;           // 256B zero page for OOB gloads
static const size_t WS_NEED = ZP_OFF + 256;

// ---------------- prep: convert weights to bf16 (wo reordered) ----------------
__global__ void k_prep(const float* __restrict__ wq, const float* __restrict__ wk,
                       const float* __restrict__ wv, const float* __restrict__ wo,
                       unsigned short* __restrict__ Wb, unsigned short* __restrict__ Wob) {
  int i = blockIdx.x * 256 + threadIdx.x;        // grid covers 786432 exactly
  if (i < 196608) {
    int z = i >> 16, r = i & 65535;
    const float* w = (z == 0) ? wq : (z == 1) ? wk : wv;
    Wb[i] = f2bf(w[r]);
  } else {
    int j = i - 196608;
    int o = j / 2304, k = j - o * 2304;
    int e = k >> 8, c = k & 255;
    Wob[j] = f2bf(wo[(o * 256 + c) * 9 + e]);    // Wob[o][e*256+c] = wo[o][c][e]
  }
}

__global__ void k_zero(float* __restrict__ p, int n) {
  int i = blockIdx.x * 256 + threadIdx.x;
  for (; i < n; i += gridDim.x * 256) p[i] = 0.f;
}

// ---------------- fused QKV projection, all outputs NHWC-swizzled ----------------
__global__ __launch_bounds__(256) void k_qkv(
    const float* __restrict__ x, const unsigned short* __restrict__ Wb,
    const float* __restrict__ bq, const float* __restrict__ bk, const float* __restrict__ bv,
    unsigned short* __restrict__ Qn, unsigned short* __restrict__ Kn,
    unsigned short* __restrict__ Vn) {
  const int pt = blockIdx.x, b = blockIdx.y;
  const int p0 = pt * 64;
  const int tid = threadIdx.x;

  __shared__ __align__(16) unsigned short xt[64 * 256];  // input tile [p][c'] swizzled
  __shared__ __align__(16) unsigned short ot[64 * 256];  // output transpose buffer

  const float* xb = x + (size_t)b * 256 * 16384;
  for (int k = 0; k < 16; ++k) {
    int i = tid + k * 256;
    int c = i >> 4, p4 = (i & 15) * 4;
    float4 v = *(const float4*)(xb + (size_t)c * 16384 + p0 + p4);
    xt[(p4 + 0) * 256 + (c ^ (((p4 + 0) & 7) << 3))] = f2bf(v.x);
    xt[(p4 + 1) * 256 + (c ^ (((p4 + 1) & 7) << 3))] = f2bf(v.y);
    xt[(p4 + 2) * 256 + (c ^ (((p4 + 2) & 7) << 3))] = f2bf(v.z);
    xt[(p4 + 3) * 256 + (c ^ (((p4 + 3) & 7) << 3))] = f2bf(v.w);
  }
  __syncthreads();

  const int wave = tid >> 6, lane = tid & 63;
  const int lr = lane & 15, lk = lane >> 4;
  const int obase = wave * 64;

  for (int z = 0; z < 3; ++z) {
    const unsigned short* Wz = Wb + (size_t)z * 65536;
    f32x4 acc[4][4];
    for (int m = 0; m < 4; ++m)
      for (int n = 0; n < 4; ++n)
        for (int r = 0; r < 4; ++r) acc[m][n][r] = 0.f;

    for (int ks = 0; ks < 8; ++ks) {
      int c0 = ks * 32 + lk * 8;
      bf8 a[4], bb[4];
#pragma unroll
      for (int m = 0; m < 4; ++m)
        a[m] = *(const bf8*)(Wz + (size_t)(obase + m * 16 + lr) * 256 + c0);
#pragma unroll
      for (int n = 0; n < 4; ++n) {
        int p = n * 16 + lr;
        bb[n] = *(const bf8*)(&xt[p * 256 + (c0 ^ ((p & 7) << 3))]);
      }
#pragma unroll
      for (int m = 0; m < 4; ++m)
#pragma unroll
        for (int n = 0; n < 4; ++n)
          acc[m][n] = __builtin_amdgcn_mfma_f32_16x16x32_bf16(a[m], bb[n], acc[m][n], 0, 0, 0);
    }

    const float* bias = (z == 0) ? bq : (z == 1) ? bk : bv;
    unsigned short* On = (z == 0) ? Qn : (z == 1) ? Kn : Vn;
    __syncthreads();   // prior ot consumers done
#pragma unroll
    for (int m = 0; m < 4; ++m) {
      int ob4 = obase + m * 16 + lk * 4;
      float4 b4 = *(const float4*)(bias + ob4);
#pragma unroll
      for (int n = 0; n < 4; ++n) {
        int p = n * 16 + lr;
        ushort4 v4;
        v4.x = f2bf(acc[m][n][0] + b4.x);
        v4.y = f2bf(acc[m][n][1] + b4.y);
        v4.z = f2bf(acc[m][n][2] + b4.z);
        v4.w = f2bf(acc[m][n][3] + b4.w);
        *(ushort4*)(&ot[p * 256 + (ob4 ^ ((p & 7) << 3))]) = v4;
      }
    }
    __syncthreads();
    unsigned short* gb = On + ((size_t)b * 16384 + p0) * 256;
#pragma unroll
    for (int i = 0; i < 8; ++i) {
      int ch = tid + i * 256;
      *(uint4*)(gb + ch * 8) = *(const uint4*)(&ot[ch * 8]);
    }
  }
}

// ---------------- Gram via MFMA, idx 0..2 ----------------
template <int IDX>
__global__ __launch_bounds__(256) void k_gram(
    const unsigned short* __restrict__ Qn, const unsigned short* __restrict__ Kn,
    float* __restrict__ scores) {
  constexpr int HS = 2 << IDX, S = HS * HS, OH = 64 >> IDX, NSP = OH * OH;
  constexpr int SPW = (IDX == 2) ? 2 : 8;
  constexpr int DSUB = SPW * 64;
  constexpr int SPB = NSP / 32;
  constexpr int STEPS = SPB / SPW;
  constexpr int ROWS = S;
  constexpr int TPT = S * SPW * 8 / 256;
  constexpr int SCOFF = (IDX == 0) ? 0 : (IDX == 1) ? 128 : 2176;
  constexpr int HC = IDX * 64;
  constexpr int MT = (IDX == 2) ? 4 : 1;

  const int chk = blockIdx.x, b = blockIdx.y;
  const int tid = threadIdx.x;
  const int wave = tid >> 6, lane = tid & 63, lr = lane & 15, lk = lane >> 4;

  __shared__ __align__(16) unsigned short qg[ROWS * DSUB];
  __shared__ __align__(16) unsigned short kg[ROWS * DSUB];
  __shared__ float red[S * S];

  const size_t base = (size_t)b * 16384 * 256;

  f32x4 acc[MT][MT];
  for (int m = 0; m < MT; ++m)
    for (int n = 0; n < MT; ++n)
      for (int r = 0; r < 4; ++r) acc[m][n][r] = 0.f;

  for (int st = 0; st < STEPS; ++st) {
    const int sp0 = chk * SPB + st * SPW;
    __syncthreads();
#pragma unroll
    for (int r = 0; r < TPT; ++r) {
      int task = tid + r * 256;
      int cg = task & 7, pl = task >> 3;
      int spl = pl >> (2 * (IDX + 1)), s = pl & (S - 1);
      int sp = sp0 + spl;
      int ohi = sp >> (6 - IDX), owi = sp & (OH - 1);
      int ii = s >> (IDX + 1), jj = s & (HS - 1);
      int p = (ohi * HS + ii) * 128 + owi * HS + jj;
      size_t gaddr = base + (size_t)p * 256 + HC + ((cg ^ (p & 7)) << 3);
      int laddr = s * DSUB + (((spl * 8 + cg) ^ (s & 7)) << 3);
      *(uint4*)(qg + laddr) = *(const uint4*)(Qn + gaddr);
      *(uint4*)(kg + laddr) = *(const uint4*)(Kn + gaddr);
    }
    __syncthreads();
    if (IDX == 2) {
      int kgid = wave * 4 + lk;
      bf8 a[4], bb[4];
#pragma unroll
      for (int m = 0; m < 4; ++m) {
        int row = m * 16 + lr;
        int off = row * DSUB + ((kgid ^ (row & 7)) << 3);
        a[m] = *(const bf8*)(qg + off);
        bb[m] = *(const bf8*)(kg + off);
      }
#pragma unroll
      for (int m = 0; m < 4; ++m)
#pragma unroll
        for (int n = 0; n < 4; ++n)
          acc[m][n] = __builtin_amdgcn_mfma_f32_16x16x32_bf16(a[m], bb[n], acc[m][n], 0, 0, 0);
    } else {
      int row = lr & (ROWS - 1);
#pragma unroll
      for (int kk = 0; kk < 4; ++kk) {
        int kgid = (wave * 4 + kk) * 4 + lk;
        int off = row * DSUB + ((kgid ^ (row & 7)) << 3);
        bf8 a = *(const bf8*)(qg + off);
        bf8 bb = *(const bf8*)(kg + off);
        acc[0][0] = __builtin_amdgcn_mfma_f32_16x16x32_bf16(a, bb, acc[0][0], 0, 0, 0);
      }
    }
  }

  __syncthreads();
  for (int i2 = tid; i2 < S * S; i2 += 256) red[i2] = 0.f;
  __syncthreads();
  if (IDX == 2) {
#pragma unroll
    for (int m = 0; m < 4; ++m)
#pragma unroll
      for (int n = 0; n < 4; ++n)
#pragma unroll
        for (int r = 0; r < 4; ++r)
          atomicAdd(&red[(m * 16 + lk * 4 + r) * 64 + n * 16 + lr], acc[m][n][r]);
  } else if (IDX == 1) {
#pragma unroll
    for (int r = 0; r < 4; ++r)
      atomicAdd(&red[(lk * 4 + r) * 16 + lr], acc[0][0][r]);
  } else {
    if (lk == 0 && lr < 4) {
#pragma unroll
      for (int r = 0; r < 4; ++r)
        atomicAdd(&red[r * 4 + lr], acc[0][0][r]);
    }
  }
  __syncthreads();
  float* sc = scores + SCOFF + (size_t)b * S * S;
  for (int i2 = tid; i2 < S * S; i2 += 256) atomicAdd(sc + i2, red[i2]);
}

// ---------------- Gram idx3: 256x256x4096 GEMM, partials ----------------
__global__ __launch_bounds__(256) void k_gram3(
    const unsigned short* __restrict__ Qn, const unsigned short* __restrict__ Kn,
    float* __restrict__ part3) {
  const int qc = blockIdx.x, tq = blockIdx.y, b = blockIdx.z;
  const int tid = threadIdx.x;
  const int wave = tid >> 6, lane = tid & 63, lr = lane & 15, lk = lane >> 4;

  __shared__ __align__(16) unsigned short qg[256 * 64];
  __shared__ __align__(16) unsigned short kg[64 * 64];

  const size_t base = (size_t)b * 16384 * 256;

  f32x4 acc[4][4];
  for (int m = 0; m < 4; ++m)
    for (int n = 0; n < 4; ++n)
      for (int r = 0; r < 4; ++r) acc[m][n][r] = 0.f;

  for (int st = 0; st < 8; ++st) {
    int sp = qc * 8 + st;
    int ohi = sp >> 3, owi = sp & 7;
    __syncthreads();
#pragma unroll
    for (int r = 0; r < 8; ++r) {
      int task = tid + r * 256;
      int cg = task & 7, s = task >> 3;
      int p = (ohi * 16 + (s >> 4)) * 128 + owi * 16 + (s & 15);
      uint4 v = *(const uint4*)(Qn + base + (size_t)p * 256 + 192 + ((cg ^ (p & 7)) << 3));
      *(uint4*)(qg + s * 64 + ((cg ^ (s & 7)) << 3)) = v;
    }
#pragma unroll
    for (int r = 0; r < 2; ++r) {
      int task = tid + r * 256;
      int cg = task & 7, tl = task >> 3;
      int p = (ohi * 16 + tq * 4 + (tl >> 4)) * 128 + owi * 16 + (tl & 15);
      uint4 v = *(const uint4*)(Kn + base + (size_t)p * 256 + 192 + ((cg ^ (p & 7)) << 3));
      *(uint4*)(kg + tl * 64 + ((cg ^ (tl & 7)) << 3)) = v;
    }
    __syncthreads();
#pragma unroll
    for (int kk = 0; kk < 2; ++kk) {
      int kgid = kk * 4 + lk;
      bf8 a[4], bb[4];
#pragma unroll
      for (int m = 0; m < 4; ++m) {
        int row = wave * 64 + m * 16 + lr;
        a[m] = *(const bf8*)(qg + row * 64 + ((kgid ^ (row & 7)) << 3));
      }
#pragma unroll
      for (int n = 0; n < 4; ++n) {
        int rowb = n * 16 + lr;
        bb[n] = *(const bf8*)(kg + rowb * 64 + ((kgid ^ (rowb & 7)) << 3));
      }
#pragma unroll
      for (int m = 0; m < 4; ++m)
#pragma unroll
        for (int n = 0; n < 4; ++n)
          acc[m][n] = __builtin_amdgcn_mfma_f32_16x16x32_bf16(a[m], bb[n], acc[m][n], 0, 0, 0);
    }
  }

  float* pb = part3 + (((size_t)qc * 8 + b) * 65536);
#pragma unroll
  for (int m = 0; m < 4; ++m)
#pragma unroll
    for (int r = 0; r < 4; ++r) {
      int srow = wave * 64 + m * 16 + lk * 4 + r;
#pragma unroll
      for (int n = 0; n < 4; ++n)
        pb[srow * 256 + tq * 64 + n * 16 + lr] = acc[m][n][r];
    }
}

// ---------------- softmax idx0-2 (fp32 scores -> bf16 probs) ----------------
__global__ __launch_bounds__(256) void k_softmax(const float* __restrict__ scores,
                                                 unsigned short* __restrict__ prb) {
  const int idx = blockIdx.x, b = blockIdx.y;
  const int S = 4 << (2 * idx);
  const int off = (idx == 0 ? 0 : idx == 1 ? 128 : 2176) + b * S * S;
  const int s = threadIdx.x;
  if (s >= S) return;
  const float scale = rsqrtf(64.0f * (float)(4096 >> (2 * idx)));
  const float* row = scores + off + s * S;
  float m = -1e30f;
  for (int t = 0; t < S; ++t) m = fmaxf(m, row[t]);
  m *= scale;
  float sum = 0.f;
  for (int t = 0; t < S; ++t) sum += __expf(row[t] * scale - m);
  float inv = 1.0f / sum;
  unsigned short* prow = prb + off + s * S;
  for (int t = 0; t < S; ++t) prow[t] = f2bf(__expf(row[t] * scale - m) * inv);
}

// ---------------- softmax idx3: sum 8 partials + softmax ----------------
__global__ __launch_bounds__(256) void k_softmax3(const float* __restrict__ part3,
                                                  unsigned short* __restrict__ prb) {
  const int sc_ = blockIdx.x, b = blockIdx.y;
  const int tid = threadIdx.x;
  const int s = sc_ * 32 + (tid >> 3);
  const int t0 = (tid & 7) * 32;
  float v[32];
#pragma unroll
  for (int k = 0; k < 32; ++k) v[k] = 0.f;
  for (int q = 0; q < 8; ++q) {
    const float4* pp = (const float4*)(part3 + (((size_t)q * 8 + b) * 256 + s) * 256 + t0);
#pragma unroll
    for (int k = 0; k < 8; ++k) {
      float4 u = pp[k];
      v[k * 4 + 0] += u.x; v[k * 4 + 1] += u.y; v[k * 4 + 2] += u.z; v[k * 4 + 3] += u.w;
    }
  }
  const float scale = 1.0f / 64.0f;
  float m = -1e30f;
#pragma unroll
  for (int k = 0; k < 32; ++k) { v[k] *= scale; m = fmaxf(m, v[k]); }
  m = fmaxf(m, __shfl_xor(m, 1));
  m = fmaxf(m, __shfl_xor(m, 2));
  m = fmaxf(m, __shfl_xor(m, 4));
  float sum = 0.f;
#pragma unroll
  for (int k = 0; k < 32; ++k) { v[k] = __expf(v[k] - m); sum += v[k]; }
  sum += __shfl_xor(sum, 1);
  sum += __shfl_xor(sum, 2);
  sum += __shfl_xor(sum, 4);
  float inv = 1.0f / sum;
  unsigned short* prw = prb + 34944 + (size_t)b * 65536 + s * 256 + t0;
#pragma unroll
  for (int k8 = 0; k8 < 4; ++k8) {
    unsigned short tmp[8];
#pragma unroll
    for (int e = 0; e < 8; ++e) tmp[e] = f2bf(v[k8 * 8 + e] * inv);
    *(uint4*)(prw + k8 * 8) = *(const uint4*)tmp;
  }
}

// ---------------- PV small S (idx 0,1,2): per-head, NHWC in/out ----------------
template <int IDX>
__global__ __launch_bounds__(256) void k_pv(
    const unsigned short* __restrict__ Vn, const unsigned short* __restrict__ prb,
    unsigned short* __restrict__ Yn) {
  constexpr int HS = 2 << IDX, S = HS * HS, OH = 64 >> IDX;
  constexpr int IT = (IDX == 0) ? 8 : (IDX == 1) ? 4 : 1;
  constexpr int POFF = (IDX == 0) ? 0 : (IDX == 1) ? 128 : 2176;
  const int bx = blockIdx.x, b = blockIdx.y;
  const int c = threadIdx.x & 63, spg = threadIdx.x >> 6;
  __shared__ __align__(16) float pl[S * S];
  const unsigned short* pr = prb + POFF + (size_t)b * S * S;
  for (int i = threadIdx.x; i < S * S; i += 256) pl[i] = bf2f(pr[i]);
  __syncthreads();
  const int hc = IDX * 64;
  const unsigned short* vb = Vn + (size_t)b * 16384 * 256;
  unsigned short* yb = Yn + (size_t)b * 16384 * 256;
  for (int it = 0; it < IT; ++it) {
    int sp = bx * (4 * IT) + it * 4 + spg;
    int ohi = sp >> (6 - IDX), owi = sp & (OH - 1);
    float v[S];
#pragma unroll
    for (int t = 0; t < S; ++t) {
      int po = (ohi * HS + t / HS) * 128 + owi * HS + (t % HS);
      v[t] = bf2f(vb[(size_t)po * 256 + ((hc + c) ^ ((po & 7) << 3))]);
    }
    for (int s = 0; s < S; ++s) {
      const float4* p4 = (const float4*)(pl + s * S);
      float a = 0.f;
#pragma unroll
      for (int t4 = 0; t4 < S / 4; ++t4) {
        float4 pp = p4[t4];
        a += pp.x * v[t4 * 4] + pp.y * v[t4 * 4 + 1] + pp.z * v[t4 * 4 + 2] + pp.w * v[t4 * 4 + 3];
      }
      int po = ((s >> (IDX + 1)) * OH + ohi) * 128 + (s & (HS - 1)) * OH + owi;
      yb[(size_t)po * 256 + ((hc + c) ^ ((po & 7) << 3))] = f2bf(a);
    }
  }
}

// ---------------- PV idx3 (S=256): MFMA GEMM per (b, sp) ----------------
__global__ __launch_bounds__(256) void k_pv3(
    const unsigned short* __restrict__ Vn, const unsigned short* __restrict__ prb,
    unsigned short* __restrict__ Yn) {
  const int sp = blockIdx.x, b = blockIdx.y;
  const int ohi = sp >> 3, owi = sp & 7;
  const int tid = threadIdx.x;
  __shared__ __align__(16) unsigned short vl[64 * 256];
  const unsigned short* vb = Vn + (size_t)b * 16384 * 256;
  {
    int t = tid;
    int po = (ohi * 16 + (t >> 4)) * 128 + owi * 16 + (t & 15);
    const unsigned short* src = vb + (size_t)po * 256;
    int xv = (po & 7) << 3;
#pragma unroll
    for (int g = 0; g < 8; ++g) {
      ushort4 lo = *(const ushort4*)(src + ((192 + g * 8) ^ xv));
      ushort4 hi = *(const ushort4*)(src + ((192 + g * 8) ^ xv) + 4);
      unsigned short vv[8] = {lo.x, lo.y, lo.z, lo.w, hi.x, hi.y, hi.z, hi.w};
#pragma unroll
      for (int e = 0; e < 8; ++e) {
        int cc = g * 8 + e;
        vl[cc * 256 + (t ^ ((cc & 7) << 3))] = vv[e];
      }
    }
  }
  __syncthreads();

  const int wave = tid >> 6, lane = tid & 63;
  const int lr = lane & 15, lk = lane >> 4;
  const int sb = wave * 64;
  const unsigned short* pr = prb + 34944 + (size_t)b * 65536;

  f32x4 acc[4][4];
  for (int m = 0; m < 4; ++m)
    for (int n = 0; n < 4; ++n)
      for (int r = 0; r < 4; ++r) acc[m][n][r] = 0.f;

  for (int kk = 0; kk < 8; ++kk) {
    int t0 = kk * 32 + lk * 8;
    bf8 a[4], bb[4];
#pragma unroll
    for (int m = 0; m < 4; ++m)
      a[m] = *(const bf8*)(pr + (size_t)(sb + m * 16 + lr) * 256 + t0);
#pragma unroll
    for (int n = 0; n < 4; ++n) {
      int cc = n * 16 + lr;
      bb[n] = *(const bf8*)(&vl[cc * 256 + (t0 ^ ((cc & 7) << 3))]);
    }
#pragma unroll
    for (int m = 0; m < 4; ++m)
#pragma unroll
      for (int n = 0; n < 4; ++n)
        acc[m][n] = __builtin_amdgcn_mfma_f32_16x16x32_bf16(a[m], bb[n], acc[m][n], 0, 0, 0);
  }

  unsigned short* yb = Yn + (size_t)b * 16384 * 256;
#pragma unroll
  for (int m = 0; m < 4; ++m) {
#pragma unroll
    for (int r = 0; r < 4; ++r) {
      int s = sb + m * 16 + lk * 4 + r;
      int si = s >> 4, sj = s & 15;
      int po = (si * 8 + ohi) * 128 + sj * 8 + owi;
#pragma unroll
      for (int n = 0; n < 4; ++n) {
        int cc = 192 + n * 16 + lr;
        yb[(size_t)po * 256 + (cc ^ (owi << 3))] = f2bf(acc[m][n][r]);
      }
    }
  }
}

// ---------------- 3x3 conv: 256x256x2304 GEMM, 8-slot ring, safe schedule ----------------
// grid 512; 512 threads = 8 waves (2M x 4N), per-wave C 128x64.
// Per K-tile KT (parity pk=KT&1) slots pk*4+{0:A0,1:B0,2:B1,3:A1}.
// Phase P=4KT+r stages half r' of KT+1 in order [A0,B0,B1,A1] -> uniform
// first-use distance 3-4 phases; vmcnt(6) leaves stages P-2..P outstanding,
// forcing everything staged <=P-3 (all data needed at P) complete. A-frags
// register-reused across the two nh phases of each mh. One barrier/phase
// (stage-vs-read slot disjointness holds for every transition).
#define CONV_PHASE(KT_, R_, PK_, DOSTAGE_, WAITMODE_)                            \
  do {                                                                           \
    if (DOSTAGE_) {                                                              \
      constexpr int type_ = (R_ == 0) ? 0 : (R_ == 1) ? 2 : (R_ == 2) ? 3 : 1;   \
      STAGE((1 - (PK_)) * 4 + (R_), type_, (KT_) + 1);                           \
    }                                                                            \
    if ((WAITMODE_) == 0) { asm volatile("s_waitcnt vmcnt(6)" ::: "memory"); }   \
    else if ((WAITMODE_) == 1) { asm volatile("s_waitcnt vmcnt(0)" ::: "memory"); } \
    __builtin_amdgcn_s_barrier();                                                \
    asm volatile("" ::: "memory");                                               \
    {                                                                            \
      constexpr int mh_ = (R_) >> 1, nh_ = (R_) & 1;                             \
      constexpr int sA_ = (PK_) * 4 + (mh_ ? 3 : 0);                             \
      constexpr int sB_ = (PK_) * 4 + (nh_ ? 2 : 1);                             \
      if (nh_ == 0) {                                                            \
        _Pragma("unroll") for (int m2 = 0; m2 < 4; ++m2) {                       \
          int row = wm * 64 + m2 * 16 + lr;                                      \
          _Pragma("unroll") for (int kk = 0; kk < 2; ++kk)                       \
            areg[m2][kk] = *(const bf8*)(&lds[sA_][row * 64 +                    \
                (((kk * 4 + lk) ^ (row & 7)) << 3)]);                            \
        }                                                                        \
      }                                                                          \
      bf8 breg[2][2];                                                            \
      _Pragma("unroll") for (int n2 = 0; n2 < 2; ++n2) {                         \
        int row = wn * 32 + n2 * 16 + lr;                                        \
        _Pragma("unroll") for (int kk = 0; kk < 2; ++kk)                         \
          breg[n2][kk] = *(const bf8*)(&lds[sB_][row * 64 +                      \
              (((kk * 4 + lk) ^ (row & 7)) << 3)]);                              \
      }                                                                          \
      __builtin_amdgcn_s_setprio(1);                                             \
      _Pragma("unroll") for (int kk = 0; kk < 2; ++kk)                           \
        _Pragma("unroll") for (int m2 = 0; m2 < 4; ++m2)                         \
          _Pragma("unroll") for (int n2 = 0; n2 < 2; ++n2)                       \
            acc[mh_ * 4 + m2][nh_ * 2 + n2] =                                    \
                __builtin_amdgcn_mfma_f32_16x16x32_bf16(                         \
                    areg[m2][kk], breg[n2][kk],                                  \
                    acc[mh_ * 4 + m2][nh_ * 2 + n2], 0, 0, 0);                   \
      __builtin_amdgcn_s_setprio(0);                                             \
      asm volatile("" ::: "memory");                                             \
    }                                                                            \
  } while (0)

__global__ __launch_bounds__(512, 2) void k_conv(
    const unsigned short* __restrict__ Yn, const unsigned short* __restrict__ Wob,
    const float* __restrict__ bo, const unsigned short* __restrict__ zp,
    unsigned short* __restrict__ co, float* __restrict__ bnp) {
  __shared__ __align__(16) unsigned short lds[8][8192];  // 8 x 16KB half-tile slots

  const int bid = blockIdx.x;
  const int swz = (bid & 7) * 64 + (bid >> 3);   // XCD-chunked, bijective (512=8*64)
  const int b = swz >> 6, tile = swz & 63;
  const int y0 = (tile >> 3) * 16, x0 = (tile & 7) * 16;
  const int tid = threadIdx.x;
  const int wave = tid >> 6, lane = tid & 63;
  const int lr = lane & 15, lk = lane >> 4;
  const int wm = wave >> 2, wn = wave & 3;
  const int cg = lane & 7;

  const unsigned short* yb = Yn + (size_t)b * 16384 * 256;

  // type: 0 = A o-bit6=0, 1 = A o-bit6=1, 2 = B px-bit5=0, 3 = B px-bit5=1
  auto STAGE = [&](int slot, int type, int KT) {
    if (type < 2) {
      const unsigned short* wsrc = Wob + (KT >> 2) * 256 + (KT & 3) * 64;
#pragma unroll
      for (int j = 0; j < 2; ++j) {
        int rp = (wave * 2 + j) * 8 + (lane >> 3);   // LDS row 0..127
        int o = ((rp >> 6) & 1) * 128 + type * 64 + (rp & 63);
        int kg = cg ^ (rp & 7);
        gload16(wsrc + o * 2304 + (kg << 3), &lds[slot][(wave * 2 + j) * 512]);
      }
    } else {
      int e = KT >> 2;
      int dy = e / 3 - 1, dx = e % 3 - 1, c8 = (KT & 3) * 8;
#pragma unroll
      for (int j = 0; j < 2; ++j) {
        int rp = (wave * 2 + j) * 8 + (lane >> 3);
        int n = ((rp >> 5) & 3) * 64 + (type - 2) * 32 + (rp & 31);
        int kg = cg ^ (rp & 7);
        int h = y0 + (n >> 4) + dy, ww = x0 + (n & 15) + dx;
        const unsigned short* src = zp;
        if (h >= 0 && h < 128 && ww >= 0 && ww < 128) {
          int pp = h * 128 + ww;
          src = yb + (size_t)pp * 256 + ((c8 + (kg ^ (pp & 7))) << 3);
        }
        gload16(src, &lds[slot][(wave * 2 + j) * 512]);
      }
    }
  };

  f32x4 acc[8][4];
#pragma unroll
  for (int m = 0; m < 8; ++m)
#pragma unroll
    for (int n = 0; n < 4; ++n)
#pragma unroll
      for (int r = 0; r < 4; ++r) acc[m][n][r] = 0.f;

  bf8 areg[4][2];

  // prologue: all 4 halves of KT0 (parity 0), then drain once
  STAGE(0, 0, 0); STAGE(1, 2, 0); STAGE(2, 3, 0); STAGE(3, 1, 0);
  asm volatile("s_waitcnt vmcnt(0)" ::: "memory");

  for (int gg = 0; gg < 17; ++gg) {
    const int k0 = gg * 2;
    CONV_PHASE(k0, 0, 0, true, 0);
    CONV_PHASE(k0, 1, 0, true, 0);
    CONV_PHASE(k0, 2, 0, true, 0);
    CONV_PHASE(k0, 3, 0, true, 0);
    CONV_PHASE(k0 + 1, 0, 1, true, 0);
    CONV_PHASE(k0 + 1, 1, 1, true, 0);
    CONV_PHASE(k0 + 1, 2, 1, true, 0);
    CONV_PHASE(k0 + 1, 3, 1, true, 0);
  }
  // tail: KT=34 stages KT35; KT=35 drains then computes
  CONV_PHASE(34, 0, 0, true, 0);
  CONV_PHASE(34, 1, 0, true, 0);
  CONV_PHASE(34, 2, 0, true, 0);
  CONV_PHASE(34, 3, 0, true, 0);
  CONV_PHASE(35, 0, 1, false, 1);
  CONV_PHASE(35, 1, 1, false, 2);
  CONV_PHASE(35, 2, 1, false, 2);
  CONV_PHASE(35, 3, 1, false, 2);

  __syncthreads();
  // epilogue: bias + bf16 out write (planar) + BN partials (exact f32 stats)
  unsigned short* cb = co + (size_t)b * 256 * 16384;
  float* red1 = (float*)&lds[0][0];     // [8][128]
  float* red2 = red1 + 1024;
#pragma unroll
  for (int m = 0; m < 8; ++m) {
#pragma unroll
    for (int r = 0; r < 4; ++r) {
      int o = wm * 128 + m * 16 + lk * 4 + r;
      float bvv = bo[o];
      float s1 = 0.f, s2 = 0.f;
#pragma unroll
      for (int n = 0; n < 4; ++n) {
        int pix = wn * 64 + n * 16 + lr;
        int py = pix >> 4, px = pix & 15;
        float v = acc[m][n][r] + bvv;
        cb[(size_t)o * 16384 + (y0 + py) * 128 + x0 + px] = f2bf(v);
        s1 += v;
        s2 += v * v;
      }
      for (int off = 1; off < 16; off <<= 1) {
        s1 += __shfl_xor(s1, off, 64);
        s2 += __shfl_xor(s2, off, 64);
      }
      if (lr == 0) {
        int ol = m * 16 + lk * 4 + r;
        red1[wave * 128 + ol] = s1;
        red2[wave * 128 + ol] = s2;
      }
    }
  }
  __syncthreads();
  {
    int o = tid & 255, stat = tid >> 8;
    int wm2 = o >> 7, ol = o & 127;
    const float* rd = stat ? red2 : red1;
    float s = rd[(wm2 * 4 + 0) * 128 + ol] + rd[(wm2 * 4 + 1) * 128 + ol] +
              rd[(wm2 * 4 + 2) * 128 + ol] + rd[(wm2 * 4 + 3) * 128 + ol];
    bnp[((size_t)(b * 64 + tile) * 256 + o) * 2 + stat] = s;
  }
}

// ---------------- BN reduce + apply ----------------
__global__ __launch_bounds__(256) void k_bnred(
    const float* __restrict__ bnp, const float* __restrict__ gamma,
    const float* __restrict__ beta, float* __restrict__ bns) {
  const int o = blockIdx.x;
  const int tid = threadIdx.x;
  float s1 = 0.f, s2 = 0.f;
  for (int k = tid; k < 512; k += 256) {
    s1 += bnp[((size_t)k * 256 + o) * 2 + 0];
    s2 += bnp[((size_t)k * 256 + o) * 2 + 1];
  }
  __shared__ float r1[256], r2[256];
  r1[tid] = s1; r2[tid] = s2;
  __syncthreads();
  for (int off = 128; off > 0; off >>= 1) {
    if (tid < off) { r1[tid] += r1[tid + off]; r2[tid] += r2[tid + off]; }
    __syncthreads();
  }
  if (tid == 0) {
    const float cnt = 8.0f * 16384.0f;
    float mean = r1[0] / cnt;
    float var = r2[0] / cnt - mean * mean;
    float sc = gamma[o] * rsqrtf(var + 1e-5f);
    bns[o] = sc;
    bns[256 + o] = beta[o] - mean * sc;
  }
}

__global__ void k_bnapply(const unsigned short* __restrict__ co, float* __restrict__ out,
                          const float* __restrict__ bns) {
  size_t i = ((size_t)blockIdx.x * 256 + threadIdx.x) * 8;
  const size_t total = 33554432;
  const size_t stride = (size_t)gridDim.x * 256 * 8;
  for (; i < total; i += stride) {
    uint4 v = *(const uint4*)(co + i);
    int o = (int)((i >> 14) & 255);
    float sc = bns[o], shv = bns[256 + o];
    const unsigned short* pv = (const unsigned short*)&v;
    float r[8];
#pragma unroll
    for (int e = 0; e < 8; ++e) {
      float f = bf2f(pv[e]) * sc + shv;
      r[e] = f > 0.f ? f : 0.2f * f;
    }
    *(float4*)(out + i) = *(const float4*)&r[0];
    *(float4*)(out + i + 4) = *(const float4*)&r[4];
  }
}

// ---------------- launcher ----------------
extern "C" void kernel_launch(void* const* d_in, const int* in_sizes, int n_in,
                              void* d_out, int out_size, void* d_ws, size_t ws_size,
                              hipStream_t stream) {
  if (ws_size < WS_NEED) return;

  const float* x     = (const float*)d_in[0];
  const float* wq    = (const float*)d_in[1];
  const float* bq    = (const float*)d_in[2];
  const float* wk    = (const float*)d_in[3];
  const float* bk    = (const float*)d_in[4];
  const float* wv    = (const float*)d_in[5];
  const float* bv    = (const float*)d_in[6];
  const float* wo    = (const float*)d_in[7];
  const float* bo    = (const float*)d_in[8];
  const float* gamma = (const float*)d_in[9];
  const float* beta  = (const float*)d_in[10];
  float* out = (float*)d_out;
  char* ws = (char*)d_ws;

  unsigned short* Wb  = (unsigned short*)(ws + WB_OFF);
  unsigned short* Wob = (unsigned short*)(ws + WOB_OFF);
  unsigned short* Qn  = (unsigned short*)(ws + QN_OFF);
  unsigned short* Kn  = (unsigned short*)(ws + KN_OFF);
  unsigned short* Vn  = (unsigned short*)(ws + VN_OFF);
  unsigned short* Yn  = (unsigned short*)(ws + YN_OFF);
  float* part3 = (float*)(ws + YN_OFF);          // overlay: used before Yn is written
  unsigned short* co = (unsigned short*)(ws + QN_OFF);  // overlay: Qn dead after grams
  float* scores = (float*)(ws + SC_OFF);
  unsigned short* prb = (unsigned short*)(ws + PRB_OFF);
  float* bnp    = (float*)(ws + BNP_OFF);
  float* bns    = (float*)(ws + BNS_OFF);
  unsigned short* zp = (unsigned short*)(ws + ZP_OFF);

  k_prep<<<dim3(3072), dim3(256), 0, stream>>>(wq, wk, wv, wo, Wb, Wob);
  k_zero<<<dim3(137), dim3(256), 0, stream>>>(scores, 34944);
  k_zero<<<dim3(1), dim3(64), 0, stream>>>((float*)zp, 64);
  k_qkv<<<dim3(256, 8), dim3(256), 0, stream>>>(x, Wb, bq, bk, bv, Qn, Kn, Vn);
  k_gram<0><<<dim3(32, 8), dim3(256), 0, stream>>>(Qn, Kn, scores);
  k_gram<1><<<dim3(32, 8), dim3(256), 0, stream>>>(Qn, Kn, scores);
  k_gram<2><<<dim3(32, 8), dim3(256), 0, stream>>>(Qn, Kn, scores);
  k_gram3<<<dim3(8, 4, 8), dim3(256), 0, stream>>>(Qn, Kn, part3);
  k_softmax<<<dim3(3, 8), dim3(256), 0, stream>>>(scores, prb);
  k_softmax3<<<dim3(8, 8), dim3(256), 0, stream>>>(part3, prb);
  k_pv<0><<<dim3(128, 8), dim3(256), 0, stream>>>(Vn, prb, Yn);
  k_pv<1><<<dim3(64, 8), dim3(256), 0, stream>>>(Vn, prb, Yn);
  k_pv<2><<<dim3(64, 8), dim3(256), 0, stream>>>(Vn, prb, Yn);
  k_pv3<<<dim3(64, 8), dim3(256), 0, stream>>>(Vn, prb, Yn);
  k_conv<<<dim3(512), dim3(512), 0, stream>>>(Yn, Wob, bo, zp, co, bnp);
  k_bnred<<<dim3(256), dim3(256), 0, stream>>>(bnp, gamma, beta, bns);
  k_bnapply<<<dim3(4096), dim3(256), 0, stream>>>(co, out, bns);
}